// Round 5
// baseline (762.899 us; speedup 1.0000x reference)
//
#include <hip/hip_runtime.h>
#include <hip/hip_bf16.h>
#include <math.h>

#define D_FEAT 128
#define NLAYER 3
#define BN_EPS 1e-5f
#define INV_SQRT_C 0.17677669529663687f  // 1/sqrt(32)
#define SORT_NPB 1024                    // nodes per sort block
#define LDSS 72                          // shorts per LDS row (64 data + 8 pad)
#define HALF_SHORTS (128 * LDSS)         // 9216 shorts per K-half

typedef __bf16 bf16x8 __attribute__((ext_vector_type(8)));
typedef float f32x4 __attribute__((ext_vector_type(4)));

static __device__ __forceinline__ unsigned short f2bf(float f) {
    return __builtin_bit_cast(unsigned short, __float2bfloat16(f));
}
static __device__ __forceinline__ float bfl(unsigned u) { return __uint_as_float(u << 16); }
static __device__ __forceinline__ float bfh(unsigned u) { return __uint_as_float(u & 0xffff0000u); }

// ---------------- conversions / init ----------------

// dst[l][n][k] = bf16(src[l][k][n])
__global__ void transp_cvt_kernel(const float* __restrict__ src, unsigned short* __restrict__ dst,
                                  int L, int lsrc, int ldst, int K, int Ncols) {
    int total = L * K * Ncols;
    for (int i = blockIdx.x * blockDim.x + threadIdx.x; i < total;
         i += gridDim.x * blockDim.x) {
        int l = i / (K * Ncols);
        int rem = i - l * (K * Ncols);
        int k = rem / Ncols;
        int nn = rem - k * Ncols;
        dst[(size_t)l * ldst + (size_t)nn * K + k] =
            f2bf(src[(size_t)l * lsrc + (size_t)k * Ncols + nn]);
    }
}

__global__ void init_ustats_kernel(float* __restrict__ u) {
    int t = threadIdx.x;
    if (t < 128) { u[256 + t] = 1.f; u[768 + t] = 0.f; }
}

// ---------------- CSR build ----------------

__global__ void hist_kernel(const int* __restrict__ dst, int E, int* __restrict__ deg) {
    int e = blockIdx.x * blockDim.x + threadIdx.x;
    if (e < E) atomicAdd(&deg[dst[e]], 1);
}

__global__ __launch_bounds__(256) void scan1_kernel(const int* __restrict__ deg, int n,
                                                    int* __restrict__ rowptr,
                                                    int* __restrict__ partials) {
    int b = blockIdx.x, tid = threadIdx.x;
    int base = b * 1024 + tid * 4;
    int4 d = {0, 0, 0, 0};
    if (base + 3 < n) d = *(const int4*)(deg + base);
    else {
        if (base + 0 < n) d.x = deg[base + 0];
        if (base + 1 < n) d.y = deg[base + 1];
        if (base + 2 < n) d.z = deg[base + 2];
        if (base + 3 < n) d.w = deg[base + 3];
    }
    int p0 = d.x, p1 = p0 + d.y, p2 = p1 + d.z, p3 = p2 + d.w;
    int v = p3;
    int lane = tid & 63;
    #pragma unroll
    for (int off = 1; off < 64; off <<= 1) {
        int t = __shfl_up(v, off);
        if (lane >= off) v += t;
    }
    __shared__ int wsum[4];
    int w = tid >> 6;
    if (lane == 63) wsum[w] = v;
    __syncthreads();
    int woff = 0;
    #pragma unroll
    for (int j = 0; j < 4; ++j) if (j < w) woff += wsum[j];
    int excl = woff + v - p3;
    if (base + 0 < n) rowptr[base + 1] = excl + p0;
    if (base + 1 < n) rowptr[base + 2] = excl + p1;
    if (base + 2 < n) rowptr[base + 3] = excl + p2;
    if (base + 3 < n) rowptr[base + 4] = excl + p3;
    if (tid == 255) partials[b] = excl + p3;
    if (b == 0 && tid == 0) rowptr[0] = 0;
}

__global__ void scan2_kernel(int* __restrict__ partials, int nb) {
    int lane = threadIdx.x;
    int v = (lane < nb) ? partials[lane] : 0;
    #pragma unroll
    for (int off = 1; off < 64; off <<= 1) {
        int t = __shfl_up(v, off);
        if (lane >= off) v += t;
    }
    if (lane < nb) partials[lane] = v;  // inclusive
}

__global__ __launch_bounds__(256) void scan3_kernel(int* __restrict__ rowptr, int n,
                                                    const int* __restrict__ partials) {
    int b = blockIdx.x, tid = threadIdx.x;
    if (b == 0) return;
    int off = partials[b - 1];
    int base = b * 1024 + tid * 4;
    #pragma unroll
    for (int j = 0; j < 4; ++j) {
        int i = base + j;
        if (i < n) rowptr[i + 1] += off;
    }
}

__global__ void scatter_kernel(const int* __restrict__ src, const int* __restrict__ dst, int E,
                               const int* __restrict__ rowptr, int* __restrict__ cursor,
                               int* __restrict__ csrsrc) {
    int e = blockIdx.x * blockDim.x + threadIdx.x;
    if (e < E) {
        int d = dst[e];
        int p = atomicAdd(&cursor[d], 1);
        csrsrc[rowptr[d] + p] = src[e];
    }
}

// ---------------- degree binning: contention-free counting sort ----------------

__global__ __launch_bounds__(256) void bin_blockhist_kernel(
    const int* __restrict__ rowptr, int n, int B, int* __restrict__ bhist)
{
    __shared__ int h[256];
    int b = blockIdx.x, tid = threadIdx.x;
    h[tid] = 0;
    __syncthreads();
    #pragma unroll
    for (int j = 0; j < SORT_NPB / 256; ++j) {
        int i = b * SORT_NPB + j * 256 + tid;
        if (i < n) {
            int d = rowptr[i + 1] - rowptr[i];
            if (d > 255) d = 255;
            atomicAdd(&h[d], 1);
        }
    }
    __syncthreads();
    bhist[tid * B + b] = h[tid];
}

__global__ __launch_bounds__(256) void bin_colscan_kernel(
    int* __restrict__ bhist, int B, int* __restrict__ binoff)
{
    int d = threadIdx.x;
    int run = 0;
    for (int b = 0; b < B; ++b) {
        int c = bhist[d * B + b];
        bhist[d * B + b] = run;
        run += c;
    }
    __shared__ int sd[256];
    sd[d] = run;
    __syncthreads();
    int v = run;
    for (int s = 1; s < 256; s <<= 1) {
        int t = (d >= s) ? sd[d - s] : 0;
        __syncthreads();
        sd[d] += t;
        __syncthreads();
    }
    binoff[d] = sd[d] - v;  // exclusive
}

__global__ __launch_bounds__(256) void bin_order_kernel(
    const int* __restrict__ rowptr, int n, int B,
    const int* __restrict__ bhist, const int* __restrict__ binoff,
    int* __restrict__ order)
{
    __shared__ int cur[256];
    int b = blockIdx.x, tid = threadIdx.x;
    cur[tid] = binoff[tid] + bhist[tid * B + b];
    __syncthreads();
    #pragma unroll
    for (int j = 0; j < SORT_NPB / 256; ++j) {
        int i = b * SORT_NPB + j * 256 + tid;
        if (i < n) {
            int d = rowptr[i + 1] - rowptr[i];
            if (d > 255) d = 255;
            int pos = atomicAdd(&cur[d], 1);
            order[pos] = i;
        }
    }
}

// ---------------- Fused per-layer GEMM ----------------
// A: f32 [M][128] (raw x or pre-BN hnext). BN scale/shift from stats (+ReLU if relu!=0)
// applied during LDS staging, cast to bf16. All 4 weight matmuls computed by the same
// block: A staged once, a-frags held in registers, LDS arena reused for each W tile.

__global__ __launch_bounds__(256) void gemm_layer_kernel(
    const float* __restrict__ A, const float* __restrict__ stats, int relu, int M,
    const unsigned short* __restrict__ Wt,
    const float* __restrict__ b0, const float* __restrict__ b1,
    const float* __restrict__ b2, const float* __restrict__ b3,
    float* __restrict__ q, unsigned short* __restrict__ kv, float* __restrict__ s)
{
    __shared__ unsigned short arena[2 * HALF_SHORTS];
    int r0 = blockIdx.x * 128;
    int tid = threadIdx.x;
    int wid = tid >> 6, lane = tid & 63;
    int wm = wid >> 1, wn = wid & 1;
    int lr = lane & 15, lk = lane >> 4;
    const float* scale = stats + 256;
    const float* shift = stats + 768;

    // Stage A (128x128 f32 -> BN -> bf16)
    #pragma unroll
    for (int it = 0; it < 16; ++it) {
        int idx = (it * 256 + tid) * 4;
        int row = idx >> 7, col = idx & 127;
        int gr = r0 + row;
        float4 v = (gr < M) ? *(const float4*)(A + (size_t)gr * 128 + col)
                            : make_float4(0.f, 0.f, 0.f, 0.f);
        float4 scv = *(const float4*)(scale + col);
        float4 shv = *(const float4*)(shift + col);
        float t0 = v.x * scv.x + shv.x;
        float t1 = v.y * scv.y + shv.y;
        float t2 = v.z * scv.z + shv.z;
        float t3 = v.w * scv.w + shv.w;
        if (relu) {
            t0 = fmaxf(t0, 0.f); t1 = fmaxf(t1, 0.f);
            t2 = fmaxf(t2, 0.f); t3 = fmaxf(t3, 0.f);
        }
        ushort4 u;
        u.x = f2bf(t0); u.y = f2bf(t1); u.z = f2bf(t2); u.w = f2bf(t3);
        *(ushort4*)&arena[(col >> 6) * HALF_SHORTS + row * LDSS + (col & 63)] = u;
    }
    __syncthreads();

    // Hoist a-frags to registers (K=128 across 4 k-steps of 32)
    bf16x8 a[4][4];
    #pragma unroll
    for (int mi = 0; mi < 4; ++mi)
        #pragma unroll
        for (int ks = 0; ks < 4; ++ks)
            a[mi][ks] = *(const bf16x8*)&arena[(ks >> 1) * HALF_SHORTS +
                                               (wm * 64 + mi * 16 + lr) * LDSS +
                                               (ks & 1) * 32 + lk * 8];
    __syncthreads();

    #pragma unroll 1
    for (int ct = 0; ct < 4; ++ct) {
        const unsigned short* W = Wt + (size_t)ct * 16384;
        #pragma unroll
        for (int it = 0; it < 8; ++it) {
            int sidx = (it * 256 + tid) * 8;
            int row = sidx >> 7, col = sidx & 127;
            int4 val = *(const int4*)(W + row * 128 + col);
            *(int4*)&arena[(col >> 6) * HALF_SHORTS + row * LDSS + (col & 63)] = val;
        }
        __syncthreads();

        f32x4 acc[4][4] = {};
        #pragma unroll
        for (int ks = 0; ks < 4; ++ks) {
            bf16x8 b[4];
            #pragma unroll
            for (int nj = 0; nj < 4; ++nj)
                b[nj] = *(const bf16x8*)&arena[(ks >> 1) * HALF_SHORTS +
                                               (wn * 64 + nj * 16 + lr) * LDSS +
                                               (ks & 1) * 32 + lk * 8];
            #pragma unroll
            for (int mi = 0; mi < 4; ++mi)
                #pragma unroll
                for (int nj = 0; nj < 4; ++nj)
                    acc[mi][nj] = __builtin_amdgcn_mfma_f32_16x16x32_bf16(
                        a[mi][ks], b[nj], acc[mi][nj], 0, 0, 0);
        }

        const float* bias = (ct == 0) ? b0 : (ct == 1) ? b1 : (ct == 2) ? b2 : b3;
        #pragma unroll
        for (int mi = 0; mi < 4; ++mi) {
            #pragma unroll
            for (int nj = 0; nj < 4; ++nj) {
                int col = wn * 64 + nj * 16 + lr;
                float bv = bias[col];
                #pragma unroll
                for (int reg = 0; reg < 4; ++reg) {
                    int rw = r0 + wm * 64 + mi * 16 + lk * 4 + reg;
                    if (rw < M) {
                        float val = acc[mi][nj][reg] + bv;
                        if (ct == 0) q[(size_t)rw * 128 + col] = val;
                        else if (ct == 1) kv[(size_t)rw * 256 + col] = f2bf(val);
                        else if (ct == 2) kv[(size_t)rw * 256 + 128 + col] = f2bf(val);
                        else s[(size_t)rw * 128 + col] = val;
                    }
                }
            }
        }
        __syncthreads();
    }
}

// Final projection fused with BN+ReLU of last layer: out[M x 64] = BNrelu(A) @ Wo + bo
__global__ __launch_bounds__(256) void gemm_final_kernel(
    const float* __restrict__ A, const float* __restrict__ stats, int M,
    const unsigned short* __restrict__ Wot, const float* __restrict__ bias,
    float* __restrict__ out)
{
    __shared__ unsigned short arena[2 * HALF_SHORTS];
    int r0 = blockIdx.x * 128;
    int tid = threadIdx.x;
    int wid = tid >> 6, lane = tid & 63;
    int wm = wid >> 1, wn = wid & 1;
    int lr = lane & 15, lk = lane >> 4;
    const float* scale = stats + 256;
    const float* shift = stats + 768;

    #pragma unroll
    for (int it = 0; it < 16; ++it) {
        int idx = (it * 256 + tid) * 4;
        int row = idx >> 7, col = idx & 127;
        int gr = r0 + row;
        float4 v = (gr < M) ? *(const float4*)(A + (size_t)gr * 128 + col)
                            : make_float4(0.f, 0.f, 0.f, 0.f);
        float4 scv = *(const float4*)(scale + col);
        float4 shv = *(const float4*)(shift + col);
        ushort4 u;
        u.x = f2bf(fmaxf(v.x * scv.x + shv.x, 0.f));
        u.y = f2bf(fmaxf(v.y * scv.y + shv.y, 0.f));
        u.z = f2bf(fmaxf(v.z * scv.z + shv.z, 0.f));
        u.w = f2bf(fmaxf(v.w * scv.w + shv.w, 0.f));
        *(ushort4*)&arena[(col >> 6) * HALF_SHORTS + row * LDSS + (col & 63)] = u;
    }
    __syncthreads();

    bf16x8 a[4][4];
    #pragma unroll
    for (int mi = 0; mi < 4; ++mi)
        #pragma unroll
        for (int ks = 0; ks < 4; ++ks)
            a[mi][ks] = *(const bf16x8*)&arena[(ks >> 1) * HALF_SHORTS +
                                               (wm * 64 + mi * 16 + lr) * LDSS +
                                               (ks & 1) * 32 + lk * 8];
    __syncthreads();

    // Stage Wot: 64 rows x 128 k
    #pragma unroll
    for (int it = 0; it < 4; ++it) {
        int sidx = (it * 256 + tid) * 8;
        int row = sidx >> 7, col = sidx & 127;
        int4 val = *(const int4*)(Wot + row * 128 + col);
        *(int4*)&arena[(col >> 6) * HALF_SHORTS + row * LDSS + (col & 63)] = val;
    }
    __syncthreads();

    f32x4 acc[4][2] = {};
    #pragma unroll
    for (int ks = 0; ks < 4; ++ks) {
        bf16x8 b[2];
        #pragma unroll
        for (int nj = 0; nj < 2; ++nj)
            b[nj] = *(const bf16x8*)&arena[(ks >> 1) * HALF_SHORTS +
                                           (wn * 32 + nj * 16 + lr) * LDSS +
                                           (ks & 1) * 32 + lk * 8];
        #pragma unroll
        for (int mi = 0; mi < 4; ++mi)
            #pragma unroll
            for (int nj = 0; nj < 2; ++nj)
                acc[mi][nj] = __builtin_amdgcn_mfma_f32_16x16x32_bf16(
                    a[mi][ks], b[nj], acc[mi][nj], 0, 0, 0);
    }

    #pragma unroll
    for (int mi = 0; mi < 4; ++mi) {
        #pragma unroll
        for (int nj = 0; nj < 2; ++nj) {
            int col = wn * 32 + nj * 16 + lr;
            float bv = bias[col];
            #pragma unroll
            for (int reg = 0; reg < 4; ++reg) {
                int rw = r0 + wm * 64 + mi * 16 + lk * 4 + reg;
                if (rw < M) out[(size_t)rw * 64 + col] = acc[mi][nj][reg] + bv;
            }
        }
    }
}

// ---------------- Fused flash-style attention: 4 nodes/wave, unroll 8 ----------------

__global__ __launch_bounds__(256) void attn_kernel(
    const float* __restrict__ q, const unsigned short* __restrict__ kv,
    const float* __restrict__ sk,
    const int* __restrict__ rowptr, const int* __restrict__ csrsrc,
    const int* __restrict__ order,
    float* __restrict__ hnext, int N)
{
    int wave = (blockIdx.x * blockDim.x + threadIdx.x) >> 6;
    int lane = threadIdx.x & 63;
    int gl = lane & 15;
    int slot = wave * 4 + (lane >> 4);
    bool nv = slot < N;
    int n = nv ? order[slot] : 0;

    int r0 = rowptr[n], r1 = rowptr[n + 1];
    int deg = nv ? (r1 - r0) : 0;
    int dmax = deg;
    dmax = max(dmax, __shfl_xor(dmax, 16));
    dmax = max(dmax, __shfl_xor(dmax, 32));

    const float* qp = q + (size_t)n * 128 + gl * 8;
    float4 qa = *(const float4*)(qp);
    float4 qb = *(const float4*)(qp + 4);

    float m = -INFINITY, ssum = 0.f;
    float acc[8] = {};

    for (int i = 0; i < dmax; i += 8) {
        int eidx[8];
        bool av[8];
        #pragma unroll
        for (int j = 0; j < 8; ++j) {
            av[j] = (i + j) < deg;
            int e = csrsrc[r0 + i + j];   // csrsrc padded; OOB reads masked below
            eidx[j] = av[j] ? e : 0;
        }
        int4 K[8], V[8];
        #pragma unroll
        for (int j = 0; j < 8; ++j) {
            const unsigned short* row = kv + (size_t)eidx[j] * 256 + gl * 8;
            K[j] = *(const int4*)(row);
            V[j] = *(const int4*)(row + 128);
        }
        float sc[8];
        #pragma unroll
        for (int j = 0; j < 8; ++j) {
            float p = qa.x * bfl(K[j].x) + qa.y * bfh(K[j].x)
                    + qa.z * bfl(K[j].y) + qa.w * bfh(K[j].y)
                    + qb.x * bfl(K[j].z) + qb.y * bfh(K[j].z)
                    + qb.z * bfl(K[j].w) + qb.w * bfh(K[j].w);
            p += __shfl_xor(p, 1);
            p += __shfl_xor(p, 2);
            sc[j] = av[j] ? p * INV_SQRT_C : -INFINITY;
        }
        float mn = m;
        #pragma unroll
        for (int j = 0; j < 8; ++j) mn = fmaxf(mn, sc[j]);
        if (mn > m) {
            float scale = __expf(m - mn);
            ssum *= scale;
            #pragma unroll
            for (int c = 0; c < 8; ++c) acc[c] *= scale;
            m = mn;
        }
        #pragma unroll
        for (int j = 0; j < 8; ++j) {
            float ej = av[j] ? __expf(sc[j] - m) : 0.f;
            ssum += ej;
            acc[0] += ej * bfl(V[j].x); acc[1] += ej * bfh(V[j].x);
            acc[2] += ej * bfl(V[j].y); acc[3] += ej * bfh(V[j].y);
            acc[4] += ej * bfl(V[j].z); acc[5] += ej * bfh(V[j].z);
            acc[6] += ej * bfl(V[j].w); acc[7] += ej * bfh(V[j].w);
        }
    }

    if (nv) {
        float inv = (ssum > 0.f) ? 1.0f / ssum : 0.f;
        const float* skp = sk + (size_t)n * 128 + gl * 8;
        float4 s0 = *(const float4*)(skp);
        float4 s1 = *(const float4*)(skp + 4);
        float4 o0, o1;
        o0.x = acc[0] * inv + s0.x; o0.y = acc[1] * inv + s0.y;
        o0.z = acc[2] * inv + s0.z; o0.w = acc[3] * inv + s0.w;
        o1.x = acc[4] * inv + s1.x; o1.y = acc[5] * inv + s1.y;
        o1.z = acc[6] * inv + s1.z; o1.w = acc[7] * inv + s1.w;
        float* op = hnext + (size_t)n * 128 + gl * 8;
        *(float4*)(op) = o0;
        *(float4*)(op + 4) = o1;
    }
}

// ---------------- BatchNorm stats ----------------

__global__ __launch_bounds__(256) void bn_stats_kernel(const float* __restrict__ x, int N, int F,
                                                       float* __restrict__ stats) {
    int tid = threadIdx.x;
    int F4 = F >> 2;
    int c4 = tid & (F4 - 1);
    int rpi = 256 / F4;
    int r = blockIdx.x * rpi + (tid / F4);
    int rstep = gridDim.x * rpi;
    float sx = 0, sy = 0, sz = 0, sw = 0, qx = 0, qy = 0, qz = 0, qw = 0;
    for (; r < N; r += rstep) {
        float4 v = *(const float4*)(x + (size_t)r * F + c4 * 4);
        sx += v.x; sy += v.y; sz += v.z; sw += v.w;
        qx += v.x * v.x; qy += v.y * v.y; qz += v.z * v.z; qw += v.w * v.w;
    }
    __shared__ float4 ls[256], lq[256];
    ls[tid] = make_float4(sx, sy, sz, sw);
    lq[tid] = make_float4(qx, qy, qz, qw);
    __syncthreads();
    if (tid < F4) {
        for (int c = F4; c < 256; c += F4) {
            float4 a = ls[tid + c], b = lq[tid + c];
            sx += a.x; sy += a.y; sz += a.z; sw += a.w;
            qx += b.x; qy += b.y; qz += b.z; qw += b.w;
        }
        atomicAdd(&stats[tid * 4 + 0], sx);
        atomicAdd(&stats[tid * 4 + 1], sy);
        atomicAdd(&stats[tid * 4 + 2], sz);
        atomicAdd(&stats[tid * 4 + 3], sw);
        atomicAdd(&stats[512 + tid * 4 + 0], qx);
        atomicAdd(&stats[512 + tid * 4 + 1], qy);
        atomicAdd(&stats[512 + tid * 4 + 2], qz);
        atomicAdd(&stats[512 + tid * 4 + 3], qw);
    }
}

__global__ void bn_finalize_kernel(float* __restrict__ stats, const float* __restrict__ g,
                                   const float* __restrict__ b, int N, int F) {
    int f = threadIdx.x;
    if (f < F) {
        float invN = 1.0f / (float)N;
        float mu = stats[f] * invN;
        float var = stats[512 + f] * invN - mu * mu;
        float sc = rsqrtf(var + BN_EPS) * g[f];
        stats[256 + f] = sc;
        stats[768 + f] = b[f] - mu * sc;
    }
}

__global__ void bn_apply_f32_kernel(const float* __restrict__ x, float* __restrict__ y,
                                    const float* __restrict__ stats, int N, int F) {
    const float* scale = stats + 256;
    const float* shift = stats + 768;
    size_t total4 = (size_t)N * F >> 2;
    int Fm = F - 1;
    for (size_t t = (size_t)blockIdx.x * blockDim.x + threadIdx.x; t < total4;
         t += (size_t)gridDim.x * blockDim.x) {
        size_t i = t * 4;
        int f = (int)(i & (size_t)Fm);
        float4 v = *(const float4*)(x + i);
        float4 o;
        o.x = fmaxf(v.x * scale[f + 0] + shift[f + 0], 0.f);
        o.y = fmaxf(v.y * scale[f + 1] + shift[f + 1], 0.f);
        o.z = fmaxf(v.z * scale[f + 2] + shift[f + 2], 0.f);
        o.w = fmaxf(v.w * scale[f + 3] + shift[f + 3], 0.f);
        *(float4*)(y + i) = o;
    }
}

// ---------------- launch ----------------

static inline size_t al16(size_t x) { return (x + 15) & ~(size_t)15; }

extern "C" void kernel_launch(void* const* d_in, const int* in_sizes, int n_in,
                              void* d_out, int out_size, void* d_ws, size_t ws_size,
                              hipStream_t stream) {
    const float* x    = (const float*)d_in[0];
    const int*   edge = (const int*)d_in[1];
    const float* Wq   = (const float*)d_in[2];
    const float* bq   = (const float*)d_in[3];
    const float* Wk   = (const float*)d_in[4];
    const float* bk   = (const float*)d_in[5];
    const float* Wv   = (const float*)d_in[6];
    const float* bv   = (const float*)d_in[7];
    const float* Wsk  = (const float*)d_in[8];
    const float* bsk  = (const float*)d_in[9];
    const float* bng  = (const float*)d_in[10];
    const float* bnb  = (const float*)d_in[11];
    const float* Wo   = (const float*)d_in[12];
    const float* bo   = (const float*)d_in[13];
    const float* bnog = (const float*)d_in[14];
    const float* bnob = (const float*)d_in[15];

    const int N = in_sizes[0] / D_FEAT;
    const int E = in_sizes[1] / 2;
    const int* esrc = edge;
    const int* edst = edge + E;

    const int SB = (N + SORT_NPB - 1) / SORT_NPB;

    char* wsb = (char*)d_ws;
    unsigned short* kv = (unsigned short*)wsb; wsb += al16((size_t)N * 256 * 2);
    float* q      = (float*)wsb; wsb += al16((size_t)N * 128 * 4);
    float* s      = (float*)wsb; wsb += al16((size_t)N * 128 * 4);
    float* hnext  = (float*)wsb; wsb += al16((size_t)N * 128 * 4);
    float* outpre = (float*)wsb; wsb += al16((size_t)N * 64 * 4);
    unsigned short* Wt  = (unsigned short*)wsb; wsb += al16((size_t)NLAYER * 4 * 16384 * 2);
    unsigned short* Wot = (unsigned short*)wsb; wsb += al16((size_t)64 * 128 * 2);
    float* stats  = (float*)wsb; wsb += al16(1024 * 4);
    float* ustats = (float*)wsb; wsb += al16(1024 * 4);
    int* rowptr   = (int*)wsb;   wsb += al16((size_t)(N + 1) * 4);
    int* deg      = (int*)wsb;   wsb += al16((size_t)N * 4);
    int* csrsrc   = (int*)wsb;   wsb += al16((size_t)(E + 64) * 4);  // +pad for unroll-8 overread
    int* partials = (int*)wsb;   wsb += al16(256 * 4);
    int* bhist    = (int*)wsb;   wsb += al16((size_t)256 * SB * 4);
    int* binoff   = (int*)wsb;   wsb += al16(256 * 4);
    int* order    = (int*)wsb;   wsb += al16((size_t)N * 4);

    // weight prep + unit stats
    transp_cvt_kernel<<<256, 256, 0, stream>>>(Wq,  Wt + 0 * 16384, NLAYER, 16384, 4 * 16384, 128, 128);
    transp_cvt_kernel<<<256, 256, 0, stream>>>(Wk,  Wt + 1 * 16384, NLAYER, 16384, 4 * 16384, 128, 128);
    transp_cvt_kernel<<<256, 256, 0, stream>>>(Wv,  Wt + 2 * 16384, NLAYER, 16384, 4 * 16384, 128, 128);
    transp_cvt_kernel<<<256, 256, 0, stream>>>(Wsk, Wt + 3 * 16384, NLAYER, 16384, 4 * 16384, 128, 128);
    transp_cvt_kernel<<<64, 256, 0, stream>>>(Wo, Wot, 1, 8192, 8192, 128, 64);
    init_ustats_kernel<<<1, 128, 0, stream>>>(ustats);

    // CSR build
    const int nb1 = (N + 1023) / 1024;
    hipMemsetAsync(deg, 0, (size_t)N * 4, stream);
    hist_kernel<<<(E + 255) / 256, 256, 0, stream>>>(edst, E, deg);
    scan1_kernel<<<nb1, 256, 0, stream>>>(deg, N, rowptr, partials);
    scan2_kernel<<<1, 64, 0, stream>>>(partials, nb1);
    scan3_kernel<<<nb1, 256, 0, stream>>>(rowptr, N, partials);
    hipMemsetAsync(deg, 0, (size_t)N * 4, stream);
    scatter_kernel<<<(E + 255) / 256, 256, 0, stream>>>(esrc, edst, E, rowptr, deg, csrsrc);

    // degree-binned node order
    bin_blockhist_kernel<<<SB, 256, 0, stream>>>(rowptr, N, SB, bhist);
    bin_colscan_kernel<<<1, 256, 0, stream>>>(bhist, SB, binoff);
    bin_order_kernel<<<SB, 256, 0, stream>>>(rowptr, N, SB, bhist, binoff, order);

    const int gemm_rb = (N + 127) / 128;
    const int attn_blocks = (N + 15) / 16;
    const float* hin = x;
    const float* statsIn = ustats;
    for (int l = 0; l < NLAYER; ++l) {
        gemm_layer_kernel<<<gemm_rb, 256, 0, stream>>>(
            hin, statsIn, (l == 0) ? 0 : 1, N, Wt + (size_t)l * 4 * 16384,
            bq + l * 128, bk + l * 128, bv + l * 128, bsk + l * 128,
            q, kv, s);
        attn_kernel<<<attn_blocks, 256, 0, stream>>>(q, kv, s, rowptr, csrsrc, order, hnext, N);
        hipMemsetAsync(stats, 0, 1024 * 4, stream);
        bn_stats_kernel<<<256, 256, 0, stream>>>(hnext, N, 128, stats);
        bn_finalize_kernel<<<1, 128, 0, stream>>>(stats, bng + l * 128, bnb + l * 128, N, 128);
        hin = hnext;
        statsIn = stats;
    }

    gemm_final_kernel<<<gemm_rb, 256, 0, stream>>>(hnext, stats, N, Wot, bo, outpre);
    hipMemsetAsync(stats, 0, 1024 * 4, stream);
    bn_stats_kernel<<<256, 256, 0, stream>>>(outpre, N, 64, stats);
    bn_finalize_kernel<<<1, 128, 0, stream>>>(stats, bnog, bnob, N, 64);
    bn_apply_f32_kernel<<<2048, 256, 0, stream>>>(outpre, (float*)d_out, stats, N, 64);
}

// Round 6
// 700.299 us; speedup vs baseline: 1.0894x; 1.0894x over previous
//
#include <hip/hip_runtime.h>
#include <hip/hip_bf16.h>
#include <math.h>

#define D_FEAT 128
#define NLAYER 3
#define BN_EPS 1e-5f
#define INV_SQRT_C 0.17677669529663687f  // 1/sqrt(32)
#define SORT_NPB 1024                    // nodes per sort block
#define LDSS 72                          // shorts per LDS row (64 data + 8 pad)
#define HALF_SHORTS (128 * LDSS)         // 9216 shorts per K-half

typedef __bf16 bf16x8 __attribute__((ext_vector_type(8)));
typedef float f32x4 __attribute__((ext_vector_type(4)));

static __device__ __forceinline__ unsigned short f2bf(float f) {
    return __builtin_bit_cast(unsigned short, __float2bfloat16(f));
}
static __device__ __forceinline__ float bfl(unsigned u) { return __uint_as_float(u << 16); }
static __device__ __forceinline__ float bfh(unsigned u) { return __uint_as_float(u & 0xffff0000u); }

// ---------------- conversions / init ----------------

// dst[l][n][k] = bf16(src[l][k][n])
__global__ void transp_cvt_kernel(const float* __restrict__ src, unsigned short* __restrict__ dst,
                                  int L, int lsrc, int ldst, int K, int Ncols) {
    int total = L * K * Ncols;
    for (int i = blockIdx.x * blockDim.x + threadIdx.x; i < total;
         i += gridDim.x * blockDim.x) {
        int l = i / (K * Ncols);
        int rem = i - l * (K * Ncols);
        int k = rem / Ncols;
        int nn = rem - k * Ncols;
        dst[(size_t)l * ldst + (size_t)nn * K + k] =
            f2bf(src[(size_t)l * lsrc + (size_t)k * Ncols + nn]);
    }
}

__global__ void init_ustats_kernel(float* __restrict__ u) {
    int t = threadIdx.x;
    if (t < 128) { u[256 + t] = 1.f; u[768 + t] = 0.f; }
}

// ---------------- CSR build ----------------

__global__ void hist_kernel(const int* __restrict__ dst, int E, int* __restrict__ deg) {
    int e = blockIdx.x * blockDim.x + threadIdx.x;
    if (e < E) atomicAdd(&deg[dst[e]], 1);
}

__global__ __launch_bounds__(256) void scan1_kernel(const int* __restrict__ deg, int n,
                                                    int* __restrict__ rowptr,
                                                    int* __restrict__ partials) {
    int b = blockIdx.x, tid = threadIdx.x;
    int base = b * 1024 + tid * 4;
    int4 d = {0, 0, 0, 0};
    if (base + 3 < n) d = *(const int4*)(deg + base);
    else {
        if (base + 0 < n) d.x = deg[base + 0];
        if (base + 1 < n) d.y = deg[base + 1];
        if (base + 2 < n) d.z = deg[base + 2];
        if (base + 3 < n) d.w = deg[base + 3];
    }
    int p0 = d.x, p1 = p0 + d.y, p2 = p1 + d.z, p3 = p2 + d.w;
    int v = p3;
    int lane = tid & 63;
    #pragma unroll
    for (int off = 1; off < 64; off <<= 1) {
        int t = __shfl_up(v, off);
        if (lane >= off) v += t;
    }
    __shared__ int wsum[4];
    int w = tid >> 6;
    if (lane == 63) wsum[w] = v;
    __syncthreads();
    int woff = 0;
    #pragma unroll
    for (int j = 0; j < 4; ++j) if (j < w) woff += wsum[j];
    int excl = woff + v - p3;
    if (base + 0 < n) rowptr[base + 1] = excl + p0;
    if (base + 1 < n) rowptr[base + 2] = excl + p1;
    if (base + 2 < n) rowptr[base + 3] = excl + p2;
    if (base + 3 < n) rowptr[base + 4] = excl + p3;
    if (tid == 255) partials[b] = excl + p3;
    if (b == 0 && tid == 0) rowptr[0] = 0;
}

__global__ void scan2_kernel(int* __restrict__ partials, int nb) {
    int lane = threadIdx.x;
    int v = (lane < nb) ? partials[lane] : 0;
    #pragma unroll
    for (int off = 1; off < 64; off <<= 1) {
        int t = __shfl_up(v, off);
        if (lane >= off) v += t;
    }
    if (lane < nb) partials[lane] = v;  // inclusive
}

__global__ __launch_bounds__(256) void scan3_kernel(int* __restrict__ rowptr, int n,
                                                    const int* __restrict__ partials) {
    int b = blockIdx.x, tid = threadIdx.x;
    if (b == 0) return;
    int off = partials[b - 1];
    int base = b * 1024 + tid * 4;
    #pragma unroll
    for (int j = 0; j < 4; ++j) {
        int i = base + j;
        if (i < n) rowptr[i + 1] += off;
    }
}

__global__ void scatter_kernel(const int* __restrict__ src, const int* __restrict__ dst, int E,
                               const int* __restrict__ rowptr, int* __restrict__ cursor,
                               int* __restrict__ csrsrc) {
    int e = blockIdx.x * blockDim.x + threadIdx.x;
    if (e < E) {
        int d = dst[e];
        int p = atomicAdd(&cursor[d], 1);
        csrsrc[rowptr[d] + p] = src[e];
    }
}

// ---------------- degree binning: contention-free counting sort ----------------

__global__ __launch_bounds__(256) void bin_blockhist_kernel(
    const int* __restrict__ rowptr, int n, int B, int* __restrict__ bhist)
{
    __shared__ int h[256];
    int b = blockIdx.x, tid = threadIdx.x;
    h[tid] = 0;
    __syncthreads();
    #pragma unroll
    for (int j = 0; j < SORT_NPB / 256; ++j) {
        int i = b * SORT_NPB + j * 256 + tid;
        if (i < n) {
            int d = rowptr[i + 1] - rowptr[i];
            if (d > 255) d = 255;
            atomicAdd(&h[d], 1);
        }
    }
    __syncthreads();
    bhist[tid * B + b] = h[tid];
}

__global__ __launch_bounds__(256) void bin_colscan_kernel(
    int* __restrict__ bhist, int B, int* __restrict__ binoff)
{
    int d = threadIdx.x;
    int run = 0;
    for (int b = 0; b < B; ++b) {
        int c = bhist[d * B + b];
        bhist[d * B + b] = run;
        run += c;
    }
    __shared__ int sd[256];
    sd[d] = run;
    __syncthreads();
    int v = run;
    for (int s = 1; s < 256; s <<= 1) {
        int t = (d >= s) ? sd[d - s] : 0;
        __syncthreads();
        sd[d] += t;
        __syncthreads();
    }
    binoff[d] = sd[d] - v;  // exclusive
}

__global__ __launch_bounds__(256) void bin_order_kernel(
    const int* __restrict__ rowptr, int n, int B,
    const int* __restrict__ bhist, const int* __restrict__ binoff,
    int* __restrict__ order)
{
    __shared__ int cur[256];
    int b = blockIdx.x, tid = threadIdx.x;
    cur[tid] = binoff[tid] + bhist[tid * B + b];
    __syncthreads();
    #pragma unroll
    for (int j = 0; j < SORT_NPB / 256; ++j) {
        int i = b * SORT_NPB + j * 256 + tid;
        if (i < n) {
            int d = rowptr[i + 1] - rowptr[i];
            if (d > 255) d = 255;
            int pos = atomicAdd(&cur[d], 1);
            order[pos] = i;
        }
    }
}

// ---------------- MFMA GEMM: one (row-tile, weight) block ----------------
// A: f32 [M][128]; BN scale/shift (+optional ReLU) applied during LDS staging, cast bf16.
// ct = blockIdx.y picks W/bias/output. Block tile 128x128, 4 waves (2x2).

__global__ __launch_bounds__(256) void gemm_qkvs_kernel(
    const float* __restrict__ A, const float* __restrict__ stats, int relu, int M,
    const unsigned short* __restrict__ Wt,
    const float* __restrict__ b0, const float* __restrict__ b1,
    const float* __restrict__ b2, const float* __restrict__ b3,
    float* __restrict__ q, unsigned short* __restrict__ kv, float* __restrict__ s)
{
    __shared__ unsigned short arena[2 * HALF_SHORTS];
    int r0 = blockIdx.x * 128;
    int ct = blockIdx.y;
    int tid = threadIdx.x;
    int wid = tid >> 6, lane = tid & 63;
    int wm = wid >> 1, wn = wid & 1;
    int lr = lane & 15, lk = lane >> 4;
    const float* scale = stats + 256;
    const float* shift = stats + 768;

    // Stage A (128x128 f32 -> BN(+ReLU) -> bf16)
    #pragma unroll
    for (int it = 0; it < 16; ++it) {
        int idx = (it * 256 + tid) * 4;
        int row = idx >> 7, col = idx & 127;
        int gr = r0 + row;
        float4 v = (gr < M) ? *(const float4*)(A + (size_t)gr * 128 + col)
                            : make_float4(0.f, 0.f, 0.f, 0.f);
        float4 scv = *(const float4*)(scale + col);
        float4 shv = *(const float4*)(shift + col);
        float t0 = v.x * scv.x + shv.x;
        float t1 = v.y * scv.y + shv.y;
        float t2 = v.z * scv.z + shv.z;
        float t3 = v.w * scv.w + shv.w;
        if (relu) {
            t0 = fmaxf(t0, 0.f); t1 = fmaxf(t1, 0.f);
            t2 = fmaxf(t2, 0.f); t3 = fmaxf(t3, 0.f);
        }
        ushort4 u;
        u.x = f2bf(t0); u.y = f2bf(t1); u.z = f2bf(t2); u.w = f2bf(t3);
        *(ushort4*)&arena[(col >> 6) * HALF_SHORTS + row * LDSS + (col & 63)] = u;
    }
    __syncthreads();

    // Hoist a-frags to registers (K=128 across 4 k-steps of 32)
    bf16x8 a[4][4];
    #pragma unroll
    for (int mi = 0; mi < 4; ++mi)
        #pragma unroll
        for (int ks = 0; ks < 4; ++ks)
            a[mi][ks] = *(const bf16x8*)&arena[(ks >> 1) * HALF_SHORTS +
                                               (wm * 64 + mi * 16 + lr) * LDSS +
                                               (ks & 1) * 32 + lk * 8];
    __syncthreads();

    // Stage W (this ct only)
    const unsigned short* W = Wt + (size_t)ct * 16384;
    #pragma unroll
    for (int it = 0; it < 8; ++it) {
        int sidx = (it * 256 + tid) * 8;
        int row = sidx >> 7, col = sidx & 127;
        int4 val = *(const int4*)(W + row * 128 + col);
        *(int4*)&arena[(col >> 6) * HALF_SHORTS + row * LDSS + (col & 63)] = val;
    }
    __syncthreads();

    f32x4 acc[4][4] = {};
    #pragma unroll
    for (int ks = 0; ks < 4; ++ks) {
        bf16x8 b[4];
        #pragma unroll
        for (int nj = 0; nj < 4; ++nj)
            b[nj] = *(const bf16x8*)&arena[(ks >> 1) * HALF_SHORTS +
                                           (wn * 64 + nj * 16 + lr) * LDSS +
                                           (ks & 1) * 32 + lk * 8];
        #pragma unroll
        for (int mi = 0; mi < 4; ++mi)
            #pragma unroll
            for (int nj = 0; nj < 4; ++nj)
                acc[mi][nj] = __builtin_amdgcn_mfma_f32_16x16x32_bf16(
                    a[mi][ks], b[nj], acc[mi][nj], 0, 0, 0);
    }

    const float* bias = (ct == 0) ? b0 : (ct == 1) ? b1 : (ct == 2) ? b2 : b3;
    #pragma unroll
    for (int mi = 0; mi < 4; ++mi) {
        #pragma unroll
        for (int nj = 0; nj < 4; ++nj) {
            int col = wn * 64 + nj * 16 + lr;
            float bv = bias[col];
            #pragma unroll
            for (int reg = 0; reg < 4; ++reg) {
                int rw = r0 + wm * 64 + mi * 16 + lk * 4 + reg;
                if (rw < M) {
                    float val = acc[mi][nj][reg] + bv;
                    if (ct == 0) q[(size_t)rw * 128 + col] = val;
                    else if (ct == 1) kv[(size_t)rw * 256 + col] = f2bf(val);
                    else if (ct == 2) kv[(size_t)rw * 256 + 128 + col] = f2bf(val);
                    else s[(size_t)rw * 128 + col] = val;
                }
            }
        }
    }
}

// Final projection fused with BN+ReLU of last layer: out[M x 64] = BNrelu(A) @ Wo + bo
__global__ __launch_bounds__(256) void gemm_final_kernel(
    const float* __restrict__ A, const float* __restrict__ stats, int M,
    const unsigned short* __restrict__ Wot, const float* __restrict__ bias,
    float* __restrict__ out)
{
    __shared__ unsigned short arena[2 * HALF_SHORTS];
    int r0 = blockIdx.x * 128;
    int tid = threadIdx.x;
    int wid = tid >> 6, lane = tid & 63;
    int wm = wid >> 1, wn = wid & 1;
    int lr = lane & 15, lk = lane >> 4;
    const float* scale = stats + 256;
    const float* shift = stats + 768;

    #pragma unroll
    for (int it = 0; it < 16; ++it) {
        int idx = (it * 256 + tid) * 4;
        int row = idx >> 7, col = idx & 127;
        int gr = r0 + row;
        float4 v = (gr < M) ? *(const float4*)(A + (size_t)gr * 128 + col)
                            : make_float4(0.f, 0.f, 0.f, 0.f);
        float4 scv = *(const float4*)(scale + col);
        float4 shv = *(const float4*)(shift + col);
        ushort4 u;
        u.x = f2bf(fmaxf(v.x * scv.x + shv.x, 0.f));
        u.y = f2bf(fmaxf(v.y * scv.y + shv.y, 0.f));
        u.z = f2bf(fmaxf(v.z * scv.z + shv.z, 0.f));
        u.w = f2bf(fmaxf(v.w * scv.w + shv.w, 0.f));
        *(ushort4*)&arena[(col >> 6) * HALF_SHORTS + row * LDSS + (col & 63)] = u;
    }
    __syncthreads();

    bf16x8 a[4][4];
    #pragma unroll
    for (int mi = 0; mi < 4; ++mi)
        #pragma unroll
        for (int ks = 0; ks < 4; ++ks)
            a[mi][ks] = *(const bf16x8*)&arena[(ks >> 1) * HALF_SHORTS +
                                               (wm * 64 + mi * 16 + lr) * LDSS +
                                               (ks & 1) * 32 + lk * 8];
    __syncthreads();

    #pragma unroll
    for (int it = 0; it < 4; ++it) {
        int sidx = (it * 256 + tid) * 8;
        int row = sidx >> 7, col = sidx & 127;
        int4 val = *(const int4*)(Wot + row * 128 + col);
        *(int4*)&arena[(col >> 6) * HALF_SHORTS + row * LDSS + (col & 63)] = val;
    }
    __syncthreads();

    f32x4 acc[4][2] = {};
    #pragma unroll
    for (int ks = 0; ks < 4; ++ks) {
        bf16x8 b[2];
        #pragma unroll
        for (int nj = 0; nj < 2; ++nj)
            b[nj] = *(const bf16x8*)&arena[(ks >> 1) * HALF_SHORTS +
                                           (wn * 32 + nj * 16 + lr) * LDSS +
                                           (ks & 1) * 32 + lk * 8];
        #pragma unroll
        for (int mi = 0; mi < 4; ++mi)
            #pragma unroll
            for (int nj = 0; nj < 2; ++nj)
                acc[mi][nj] = __builtin_amdgcn_mfma_f32_16x16x32_bf16(
                    a[mi][ks], b[nj], acc[mi][nj], 0, 0, 0);
    }

    #pragma unroll
    for (int mi = 0; mi < 4; ++mi) {
        #pragma unroll
        for (int nj = 0; nj < 2; ++nj) {
            int col = wn * 32 + nj * 16 + lr;
            float bv = bias[col];
            #pragma unroll
            for (int reg = 0; reg < 4; ++reg) {
                int rw = r0 + wm * 64 + mi * 16 + lk * 4 + reg;
                if (rw < M) out[(size_t)rw * 64 + col] = acc[mi][nj][reg] + bv;
            }
        }
    }
}

// ---------------- Fused flash-style attention: 4 nodes/wave, unroll 8 ----------------

__global__ __launch_bounds__(256) void attn_kernel(
    const float* __restrict__ q, const unsigned short* __restrict__ kv,
    const float* __restrict__ sk,
    const int* __restrict__ rowptr, const int* __restrict__ csrsrc,
    const int* __restrict__ order,
    float* __restrict__ hnext, int N)
{
    int wave = (blockIdx.x * blockDim.x + threadIdx.x) >> 6;
    int lane = threadIdx.x & 63;
    int gl = lane & 15;
    int slot = wave * 4 + (lane >> 4);
    bool nv = slot < N;
    int n = nv ? order[slot] : 0;

    int r0 = rowptr[n], r1 = rowptr[n + 1];
    int deg = nv ? (r1 - r0) : 0;
    int dmax = deg;
    dmax = max(dmax, __shfl_xor(dmax, 16));
    dmax = max(dmax, __shfl_xor(dmax, 32));

    const float* qp = q + (size_t)n * 128 + gl * 8;
    float4 qa = *(const float4*)(qp);
    float4 qb = *(const float4*)(qp + 4);

    float m = -INFINITY, ssum = 0.f;
    float acc[8] = {};

    for (int i = 0; i < dmax; i += 8) {
        int eidx[8];
        bool av[8];
        #pragma unroll
        for (int j = 0; j < 8; ++j) {
            av[j] = (i + j) < deg;
            int e = csrsrc[r0 + i + j];   // csrsrc padded; OOB reads masked below
            eidx[j] = av[j] ? e : 0;
        }
        int4 K[8], V[8];
        #pragma unroll
        for (int j = 0; j < 8; ++j) {
            const unsigned short* row = kv + (size_t)eidx[j] * 256 + gl * 8;
            K[j] = *(const int4*)(row);
            V[j] = *(const int4*)(row + 128);
        }
        float sc[8];
        #pragma unroll
        for (int j = 0; j < 8; ++j) {
            float p = qa.x * bfl(K[j].x) + qa.y * bfh(K[j].x)
                    + qa.z * bfl(K[j].y) + qa.w * bfh(K[j].y)
                    + qb.x * bfl(K[j].z) + qb.y * bfh(K[j].z)
                    + qb.z * bfl(K[j].w) + qb.w * bfh(K[j].w);
            p += __shfl_xor(p, 1);
            p += __shfl_xor(p, 2);
            sc[j] = av[j] ? p * INV_SQRT_C : -INFINITY;
        }
        float mn = m;
        #pragma unroll
        for (int j = 0; j < 8; ++j) mn = fmaxf(mn, sc[j]);
        if (mn > m) {
            float scale = __expf(m - mn);
            ssum *= scale;
            #pragma unroll
            for (int c = 0; c < 8; ++c) acc[c] *= scale;
            m = mn;
        }
        #pragma unroll
        for (int j = 0; j < 8; ++j) {
            float ej = av[j] ? __expf(sc[j] - m) : 0.f;
            ssum += ej;
            acc[0] += ej * bfl(V[j].x); acc[1] += ej * bfh(V[j].x);
            acc[2] += ej * bfl(V[j].y); acc[3] += ej * bfh(V[j].y);
            acc[4] += ej * bfl(V[j].z); acc[5] += ej * bfh(V[j].z);
            acc[6] += ej * bfl(V[j].w); acc[7] += ej * bfh(V[j].w);
        }
    }

    if (nv) {
        float inv = (ssum > 0.f) ? 1.0f / ssum : 0.f;
        const float* skp = sk + (size_t)n * 128 + gl * 8;
        float4 s0 = *(const float4*)(skp);
        float4 s1 = *(const float4*)(skp + 4);
        float4 o0, o1;
        o0.x = acc[0] * inv + s0.x; o0.y = acc[1] * inv + s0.y;
        o0.z = acc[2] * inv + s0.z; o0.w = acc[3] * inv + s0.w;
        o1.x = acc[4] * inv + s1.x; o1.y = acc[5] * inv + s1.y;
        o1.z = acc[6] * inv + s1.z; o1.w = acc[7] * inv + s1.w;
        float* op = hnext + (size_t)n * 128 + gl * 8;
        *(float4*)(op) = o0;
        *(float4*)(op + 4) = o1;
    }
}

// ---------------- BatchNorm stats ----------------

__global__ __launch_bounds__(256) void bn_stats_kernel(const float* __restrict__ x, int N, int F,
                                                       float* __restrict__ stats) {
    int tid = threadIdx.x;
    int F4 = F >> 2;
    int c4 = tid & (F4 - 1);
    int rpi = 256 / F4;
    int r = blockIdx.x * rpi + (tid / F4);
    int rstep = gridDim.x * rpi;
    float sx = 0, sy = 0, sz = 0, sw = 0, qx = 0, qy = 0, qz = 0, qw = 0;
    for (; r < N; r += rstep) {
        float4 v = *(const float4*)(x + (size_t)r * F + c4 * 4);
        sx += v.x; sy += v.y; sz += v.z; sw += v.w;
        qx += v.x * v.x; qy += v.y * v.y; qz += v.z * v.z; qw += v.w * v.w;
    }
    __shared__ float4 ls[256], lq[256];
    ls[tid] = make_float4(sx, sy, sz, sw);
    lq[tid] = make_float4(qx, qy, qz, qw);
    __syncthreads();
    if (tid < F4) {
        for (int c = F4; c < 256; c += F4) {
            float4 a = ls[tid + c], b = lq[tid + c];
            sx += a.x; sy += a.y; sz += a.z; sw += a.w;
            qx += b.x; qy += b.y; qz += b.z; qw += b.w;
        }
        atomicAdd(&stats[tid * 4 + 0], sx);
        atomicAdd(&stats[tid * 4 + 1], sy);
        atomicAdd(&stats[tid * 4 + 2], sz);
        atomicAdd(&stats[tid * 4 + 3], sw);
        atomicAdd(&stats[512 + tid * 4 + 0], qx);
        atomicAdd(&stats[512 + tid * 4 + 1], qy);
        atomicAdd(&stats[512 + tid * 4 + 2], qz);
        atomicAdd(&stats[512 + tid * 4 + 3], qw);
    }
}

__global__ void bn_finalize_kernel(float* __restrict__ stats, const float* __restrict__ g,
                                   const float* __restrict__ b, int N, int F) {
    int f = threadIdx.x;
    if (f < F) {
        float invN = 1.0f / (float)N;
        float mu = stats[f] * invN;
        float var = stats[512 + f] * invN - mu * mu;
        float sc = rsqrtf(var + BN_EPS) * g[f];
        stats[256 + f] = sc;
        stats[768 + f] = b[f] - mu * sc;
    }
}

__global__ void bn_apply_f32_kernel(const float* __restrict__ x, float* __restrict__ y,
                                    const float* __restrict__ stats, int N, int F) {
    const float* scale = stats + 256;
    const float* shift = stats + 768;
    size_t total4 = (size_t)N * F >> 2;
    int Fm = F - 1;
    for (size_t t = (size_t)blockIdx.x * blockDim.x + threadIdx.x; t < total4;
         t += (size_t)gridDim.x * blockDim.x) {
        size_t i = t * 4;
        int f = (int)(i & (size_t)Fm);
        float4 v = *(const float4*)(x + i);
        float4 o;
        o.x = fmaxf(v.x * scale[f + 0] + shift[f + 0], 0.f);
        o.y = fmaxf(v.y * scale[f + 1] + shift[f + 1], 0.f);
        o.z = fmaxf(v.z * scale[f + 2] + shift[f + 2], 0.f);
        o.w = fmaxf(v.w * scale[f + 3] + shift[f + 3], 0.f);
        *(float4*)(y + i) = o;
    }
}

// ---------------- launch ----------------

static inline size_t al16(size_t x) { return (x + 15) & ~(size_t)15; }

extern "C" void kernel_launch(void* const* d_in, const int* in_sizes, int n_in,
                              void* d_out, int out_size, void* d_ws, size_t ws_size,
                              hipStream_t stream) {
    const float* x    = (const float*)d_in[0];
    const int*   edge = (const int*)d_in[1];
    const float* Wq   = (const float*)d_in[2];
    const float* bq   = (const float*)d_in[3];
    const float* Wk   = (const float*)d_in[4];
    const float* bk   = (const float*)d_in[5];
    const float* Wv   = (const float*)d_in[6];
    const float* bv   = (const float*)d_in[7];
    const float* Wsk  = (const float*)d_in[8];
    const float* bsk  = (const float*)d_in[9];
    const float* bng  = (const float*)d_in[10];
    const float* bnb  = (const float*)d_in[11];
    const float* Wo   = (const float*)d_in[12];
    const float* bo   = (const float*)d_in[13];
    const float* bnog = (const float*)d_in[14];
    const float* bnob = (const float*)d_in[15];

    const int N = in_sizes[0] / D_FEAT;
    const int E = in_sizes[1] / 2;
    const int* esrc = edge;
    const int* edst = edge + E;

    const int SB = (N + SORT_NPB - 1) / SORT_NPB;

    char* wsb = (char*)d_ws;
    unsigned short* kv = (unsigned short*)wsb; wsb += al16((size_t)N * 256 * 2);
    float* q      = (float*)wsb; wsb += al16((size_t)N * 128 * 4);
    float* s      = (float*)wsb; wsb += al16((size_t)N * 128 * 4);
    float* hnext  = (float*)wsb; wsb += al16((size_t)N * 128 * 4);
    float* outpre = (float*)wsb; wsb += al16((size_t)N * 64 * 4);
    unsigned short* Wt  = (unsigned short*)wsb; wsb += al16((size_t)NLAYER * 4 * 16384 * 2);
    unsigned short* Wot = (unsigned short*)wsb; wsb += al16((size_t)64 * 128 * 2);
    float* stats  = (float*)wsb; wsb += al16(1024 * 4);
    float* ustats = (float*)wsb; wsb += al16(1024 * 4);
    int* rowptr   = (int*)wsb;   wsb += al16((size_t)(N + 1) * 4);
    int* deg      = (int*)wsb;   wsb += al16((size_t)N * 4);
    int* csrsrc   = (int*)wsb;   wsb += al16((size_t)(E + 64) * 4);  // +pad for unroll-8 overread
    int* partials = (int*)wsb;   wsb += al16(256 * 4);
    int* bhist    = (int*)wsb;   wsb += al16((size_t)256 * SB * 4);
    int* binoff   = (int*)wsb;   wsb += al16(256 * 4);
    int* order    = (int*)wsb;   wsb += al16((size_t)N * 4);

    // weight prep + unit stats
    transp_cvt_kernel<<<256, 256, 0, stream>>>(Wq,  Wt + 0 * 16384, NLAYER, 16384, 4 * 16384, 128, 128);
    transp_cvt_kernel<<<256, 256, 0, stream>>>(Wk,  Wt + 1 * 16384, NLAYER, 16384, 4 * 16384, 128, 128);
    transp_cvt_kernel<<<256, 256, 0, stream>>>(Wv,  Wt + 2 * 16384, NLAYER, 16384, 4 * 16384, 128, 128);
    transp_cvt_kernel<<<256, 256, 0, stream>>>(Wsk, Wt + 3 * 16384, NLAYER, 16384, 4 * 16384, 128, 128);
    transp_cvt_kernel<<<64, 256, 0, stream>>>(Wo, Wot, 1, 8192, 8192, 128, 64);
    init_ustats_kernel<<<1, 128, 0, stream>>>(ustats);

    // CSR build
    const int nb1 = (N + 1023) / 1024;
    hipMemsetAsync(deg, 0, (size_t)N * 4, stream);
    hist_kernel<<<(E + 255) / 256, 256, 0, stream>>>(edst, E, deg);
    scan1_kernel<<<nb1, 256, 0, stream>>>(deg, N, rowptr, partials);
    scan2_kernel<<<1, 64, 0, stream>>>(partials, nb1);
    scan3_kernel<<<nb1, 256, 0, stream>>>(rowptr, N, partials);
    hipMemsetAsync(deg, 0, (size_t)N * 4, stream);
    scatter_kernel<<<(E + 255) / 256, 256, 0, stream>>>(esrc, edst, E, rowptr, deg, csrsrc);

    // degree-binned node order
    bin_blockhist_kernel<<<SB, 256, 0, stream>>>(rowptr, N, SB, bhist);
    bin_colscan_kernel<<<1, 256, 0, stream>>>(bhist, SB, binoff);
    bin_order_kernel<<<SB, 256, 0, stream>>>(rowptr, N, SB, bhist, binoff, order);

    const int gemm_rb = (N + 127) / 128;
    const int attn_blocks = (N + 15) / 16;
    const float* hin = x;
    const float* statsIn = ustats;
    for (int l = 0; l < NLAYER; ++l) {
        gemm_qkvs_kernel<<<dim3(gemm_rb, 4), 256, 0, stream>>>(
            hin, statsIn, (l == 0) ? 0 : 1, N, Wt + (size_t)l * 4 * 16384,
            bq + l * 128, bk + l * 128, bv + l * 128, bsk + l * 128,
            q, kv, s);
        attn_kernel<<<attn_blocks, 256, 0, stream>>>(q, kv, s, rowptr, csrsrc, order, hnext, N);
        hipMemsetAsync(stats, 0, 1024 * 4, stream);
        bn_stats_kernel<<<256, 256, 0, stream>>>(hnext, N, 128, stats);
        bn_finalize_kernel<<<1, 128, 0, stream>>>(stats, bng + l * 128, bnb + l * 128, N, 128);
        hin = hnext;
        statsIn = stats;
    }

    gemm_final_kernel<<<gemm_rb, 256, 0, stream>>>(hnext, stats, N, Wot, bo, outpre);
    hipMemsetAsync(stats, 0, 1024 * 4, stream);
    bn_stats_kernel<<<256, 256, 0, stream>>>(outpre, N, 64, stats);
    bn_finalize_kernel<<<1, 128, 0, stream>>>(stats, bnog, bnob, N, 64);
    bn_apply_f32_kernel<<<2048, 256, 0, stream>>>(outpre, (float*)d_out, stats, N, 64);
}

// Round 7
// 656.813 us; speedup vs baseline: 1.1615x; 1.0662x over previous
//
#include <hip/hip_runtime.h>
#include <hip/hip_bf16.h>
#include <math.h>

#define D_FEAT 128
#define NLAYER 3
#define BN_EPS 1e-5f
#define INV_SQRT_C 0.17677669529663687f  // 1/sqrt(32)
#define SORT_NPB 1024                    // nodes per sort block

typedef __bf16 bf16x8 __attribute__((ext_vector_type(8)));
typedef float f32x4 __attribute__((ext_vector_type(4)));

static __device__ __forceinline__ unsigned short f2bf(float f) {
    return __builtin_bit_cast(unsigned short, __float2bfloat16(f));
}
static __device__ __forceinline__ float bfl(unsigned u) { return __uint_as_float(u << 16); }
static __device__ __forceinline__ float bfh(unsigned u) { return __uint_as_float(u & 0xffff0000u); }

// ---------------- conversions ----------------

__global__ void cvt_bf16_kernel(const float* __restrict__ src, unsigned short* __restrict__ dst,
                                size_t n4) {
    for (size_t t = (size_t)blockIdx.x * blockDim.x + threadIdx.x; t < n4;
         t += (size_t)gridDim.x * blockDim.x) {
        size_t i = t * 4;
        float4 v = *(const float4*)(src + i);
        ushort4 u;
        u.x = f2bf(v.x); u.y = f2bf(v.y); u.z = f2bf(v.z); u.w = f2bf(v.w);
        *(ushort4*)(dst + i) = u;
    }
}

// dst[l][n][k] = bf16(src[l][k][n])
__global__ void transp_cvt_kernel(const float* __restrict__ src, unsigned short* __restrict__ dst,
                                  int L, int lsrc, int ldst, int K, int Ncols) {
    int total = L * K * Ncols;
    for (int i = blockIdx.x * blockDim.x + threadIdx.x; i < total;
         i += gridDim.x * blockDim.x) {
        int l = i / (K * Ncols);
        int rem = i - l * (K * Ncols);
        int k = rem / Ncols;
        int nn = rem - k * Ncols;
        dst[(size_t)l * ldst + (size_t)nn * K + k] =
            f2bf(src[(size_t)l * lsrc + (size_t)k * Ncols + nn]);
    }
}

// ---------------- CSR build ----------------

__global__ void hist_kernel(const int* __restrict__ dst, int E, int* __restrict__ deg) {
    int e = blockIdx.x * blockDim.x + threadIdx.x;
    if (e < E) atomicAdd(&deg[dst[e]], 1);
}

__global__ __launch_bounds__(256) void scan1_kernel(const int* __restrict__ deg, int n,
                                                    int* __restrict__ rowptr,
                                                    int* __restrict__ partials) {
    int b = blockIdx.x, tid = threadIdx.x;
    int base = b * 1024 + tid * 4;
    int4 d = {0, 0, 0, 0};
    if (base + 3 < n) d = *(const int4*)(deg + base);
    else {
        if (base + 0 < n) d.x = deg[base + 0];
        if (base + 1 < n) d.y = deg[base + 1];
        if (base + 2 < n) d.z = deg[base + 2];
        if (base + 3 < n) d.w = deg[base + 3];
    }
    int p0 = d.x, p1 = p0 + d.y, p2 = p1 + d.z, p3 = p2 + d.w;
    int v = p3;
    int lane = tid & 63;
    #pragma unroll
    for (int off = 1; off < 64; off <<= 1) {
        int t = __shfl_up(v, off);
        if (lane >= off) v += t;
    }
    __shared__ int wsum[4];
    int w = tid >> 6;
    if (lane == 63) wsum[w] = v;
    __syncthreads();
    int woff = 0;
    #pragma unroll
    for (int j = 0; j < 4; ++j) if (j < w) woff += wsum[j];
    int excl = woff + v - p3;
    if (base + 0 < n) rowptr[base + 1] = excl + p0;
    if (base + 1 < n) rowptr[base + 2] = excl + p1;
    if (base + 2 < n) rowptr[base + 3] = excl + p2;
    if (base + 3 < n) rowptr[base + 4] = excl + p3;
    if (tid == 255) partials[b] = excl + p3;
    if (b == 0 && tid == 0) rowptr[0] = 0;
}

__global__ void scan2_kernel(int* __restrict__ partials, int nb) {
    int lane = threadIdx.x;
    int v = (lane < nb) ? partials[lane] : 0;
    #pragma unroll
    for (int off = 1; off < 64; off <<= 1) {
        int t = __shfl_up(v, off);
        if (lane >= off) v += t;
    }
    if (lane < nb) partials[lane] = v;  // inclusive
}

__global__ __launch_bounds__(256) void scan3_kernel(int* __restrict__ rowptr, int n,
                                                    const int* __restrict__ partials) {
    int b = blockIdx.x, tid = threadIdx.x;
    if (b == 0) return;
    int off = partials[b - 1];
    int base = b * 1024 + tid * 4;
    #pragma unroll
    for (int j = 0; j < 4; ++j) {
        int i = base + j;
        if (i < n) rowptr[i + 1] += off;
    }
}

__global__ void scatter_kernel(const int* __restrict__ src, const int* __restrict__ dst, int E,
                               const int* __restrict__ rowptr, int* __restrict__ cursor,
                               int* __restrict__ csrsrc) {
    int e = blockIdx.x * blockDim.x + threadIdx.x;
    if (e < E) {
        int d = dst[e];
        int p = atomicAdd(&cursor[d], 1);
        csrsrc[rowptr[d] + p] = src[e];
    }
}

// ---------------- degree binning: contention-free counting sort ----------------

__global__ __launch_bounds__(256) void bin_blockhist_kernel(
    const int* __restrict__ rowptr, int n, int B, int* __restrict__ bhist)
{
    __shared__ int h[256];
    int b = blockIdx.x, tid = threadIdx.x;
    h[tid] = 0;
    __syncthreads();
    #pragma unroll
    for (int j = 0; j < SORT_NPB / 256; ++j) {
        int i = b * SORT_NPB + j * 256 + tid;
        if (i < n) {
            int d = rowptr[i + 1] - rowptr[i];
            if (d > 255) d = 255;
            atomicAdd(&h[d], 1);
        }
    }
    __syncthreads();
    bhist[tid * B + b] = h[tid];
}

__global__ __launch_bounds__(256) void bin_colscan_kernel(
    int* __restrict__ bhist, int B, int* __restrict__ binoff)
{
    int d = threadIdx.x;
    int run = 0;
    for (int b = 0; b < B; ++b) {
        int c = bhist[d * B + b];
        bhist[d * B + b] = run;
        run += c;
    }
    __shared__ int sd[256];
    sd[d] = run;
    __syncthreads();
    int v = run;
    for (int s = 1; s < 256; s <<= 1) {
        int t = (d >= s) ? sd[d - s] : 0;
        __syncthreads();
        sd[d] += t;
        __syncthreads();
    }
    binoff[d] = sd[d] - v;  // exclusive
}

__global__ __launch_bounds__(256) void bin_order_kernel(
    const int* __restrict__ rowptr, int n, int B,
    const int* __restrict__ bhist, const int* __restrict__ binoff,
    int* __restrict__ order)
{
    __shared__ int cur[256];
    int b = blockIdx.x, tid = threadIdx.x;
    cur[tid] = binoff[tid] + bhist[tid * B + b];
    __syncthreads();
    #pragma unroll
    for (int j = 0; j < SORT_NPB / 256; ++j) {
        int i = b * SORT_NPB + j * 256 + tid;
        if (i < n) {
            int d = rowptr[i + 1] - rowptr[i];
            if (d > 255) d = 255;
            int pos = atomicAdd(&cur[d], 1);
            order[pos] = i;
        }
    }
}

// ---------------- LDS-free direct-register MFMA GEMM ----------------
// A: bf16 [M][128] (k contiguous). Wt: bf16 [4][128 n][128 k]. ct = blockIdx.y.
// Block tile 128x128, 4 waves (2x2), wave tile 64x64. All fragment loads are
// direct global int4 (16B) reads; W is L2-resident, A rows L1/L2-reused.

__global__ __launch_bounds__(256) void gemm_qkvs_kernel(
    const unsigned short* __restrict__ A, int M,
    const unsigned short* __restrict__ Wt,
    const float* __restrict__ b0, const float* __restrict__ b1,
    const float* __restrict__ b2, const float* __restrict__ b3,
    unsigned short* __restrict__ q, unsigned short* __restrict__ kv,
    unsigned short* __restrict__ s)
{
    int r0 = blockIdx.x * 128;
    int ct = blockIdx.y;
    int tid = threadIdx.x;
    int wid = tid >> 6, lane = tid & 63;
    int wm = wid >> 1, wn = wid & 1;
    int lr = lane & 15, lk = lane >> 4;
    const unsigned short* W = Wt + (size_t)ct * 16384;

    f32x4 acc[4][4] = {};
    #pragma unroll
    for (int ks = 0; ks < 4; ++ks) {
        int ko = ks * 32 + lk * 8;
        bf16x8 a[4], b[4];
        #pragma unroll
        for (int mi = 0; mi < 4; ++mi) {
            int arow = r0 + wm * 64 + mi * 16 + lr;
            int4 t = {0, 0, 0, 0};
            if (arow < M) t = *(const int4*)(A + (size_t)arow * 128 + ko);
            a[mi] = __builtin_bit_cast(bf16x8, t);
        }
        #pragma unroll
        for (int nj = 0; nj < 4; ++nj) {
            int4 t = *(const int4*)(W + (size_t)(wn * 64 + nj * 16 + lr) * 128 + ko);
            b[nj] = __builtin_bit_cast(bf16x8, t);
        }
        #pragma unroll
        for (int mi = 0; mi < 4; ++mi)
            #pragma unroll
            for (int nj = 0; nj < 4; ++nj)
                acc[mi][nj] = __builtin_amdgcn_mfma_f32_16x16x32_bf16(
                    a[mi], b[nj], acc[mi][nj], 0, 0, 0);
    }

    const float* bias = (ct == 0) ? b0 : (ct == 1) ? b1 : (ct == 2) ? b2 : b3;
    #pragma unroll
    for (int mi = 0; mi < 4; ++mi) {
        #pragma unroll
        for (int nj = 0; nj < 4; ++nj) {
            int col = wn * 64 + nj * 16 + lr;
            float bv = bias[col];
            #pragma unroll
            for (int reg = 0; reg < 4; ++reg) {
                int rw = r0 + wm * 64 + mi * 16 + lk * 4 + reg;
                if (rw < M) {
                    unsigned short val = f2bf(acc[mi][nj][reg] + bv);
                    if (ct == 0) q[(size_t)rw * 128 + col] = val;
                    else if (ct == 1) kv[(size_t)rw * 256 + col] = val;
                    else if (ct == 2) kv[(size_t)rw * 256 + 128 + col] = val;
                    else s[(size_t)rw * 128 + col] = val;
                }
            }
        }
    }
}

// Final: out[M x 64] = A@Wo + bo, f32 out. Wot: bf16 [64 n][128 k].
__global__ __launch_bounds__(256) void gemm_final_kernel(
    const unsigned short* __restrict__ A, int M,
    const unsigned short* __restrict__ Wot, const float* __restrict__ bias,
    float* __restrict__ out)
{
    int r0 = blockIdx.x * 128;
    int tid = threadIdx.x;
    int wid = tid >> 6, lane = tid & 63;
    int wm = wid >> 1, wn = wid & 1;
    int lr = lane & 15, lk = lane >> 4;

    f32x4 acc[4][2] = {};
    #pragma unroll
    for (int ks = 0; ks < 4; ++ks) {
        int ko = ks * 32 + lk * 8;
        bf16x8 a[4], b[2];
        #pragma unroll
        for (int mi = 0; mi < 4; ++mi) {
            int arow = r0 + wm * 64 + mi * 16 + lr;
            int4 t = {0, 0, 0, 0};
            if (arow < M) t = *(const int4*)(A + (size_t)arow * 128 + ko);
            a[mi] = __builtin_bit_cast(bf16x8, t);
        }
        #pragma unroll
        for (int nj = 0; nj < 2; ++nj) {
            int4 t = *(const int4*)(Wot + (size_t)(wn * 32 + nj * 16 + lr) * 128 + ko);
            b[nj] = __builtin_bit_cast(bf16x8, t);
        }
        #pragma unroll
        for (int mi = 0; mi < 4; ++mi)
            #pragma unroll
            for (int nj = 0; nj < 2; ++nj)
                acc[mi][nj] = __builtin_amdgcn_mfma_f32_16x16x32_bf16(
                    a[mi], b[nj], acc[mi][nj], 0, 0, 0);
    }

    #pragma unroll
    for (int mi = 0; mi < 4; ++mi) {
        #pragma unroll
        for (int nj = 0; nj < 2; ++nj) {
            int col = wn * 32 + nj * 16 + lr;
            float bv = bias[col];
            #pragma unroll
            for (int reg = 0; reg < 4; ++reg) {
                int rw = r0 + wm * 64 + mi * 16 + lk * 4 + reg;
                if (rw < M) out[(size_t)rw * 64 + col] = acc[mi][nj][reg] + bv;
            }
        }
    }
}

// ---------------- Fused flash-style attention: 4 nodes/wave, unroll 8 ----------------
// q, kv, sk all bf16. kv row: [k(128) | v(128)] = 512 B.

__global__ __launch_bounds__(256) void attn_kernel(
    const unsigned short* __restrict__ q, const unsigned short* __restrict__ kv,
    const unsigned short* __restrict__ sk,
    const int* __restrict__ rowptr, const int* __restrict__ csrsrc,
    const int* __restrict__ order,
    float* __restrict__ hnext, int N)
{
    int wave = (blockIdx.x * blockDim.x + threadIdx.x) >> 6;
    int lane = threadIdx.x & 63;
    int gl = lane & 15;
    int slot = wave * 4 + (lane >> 4);
    bool nv = slot < N;
    int n = nv ? order[slot] : 0;

    int r0 = rowptr[n], r1 = rowptr[n + 1];
    int deg = nv ? (r1 - r0) : 0;
    int dmax = deg;
    dmax = max(dmax, __shfl_xor(dmax, 16));
    dmax = max(dmax, __shfl_xor(dmax, 32));

    int4 qu = *(const int4*)(q + (size_t)n * 128 + gl * 8);
    float qf[8];
    qf[0] = bfl(qu.x); qf[1] = bfh(qu.x); qf[2] = bfl(qu.y); qf[3] = bfh(qu.y);
    qf[4] = bfl(qu.z); qf[5] = bfh(qu.z); qf[6] = bfl(qu.w); qf[7] = bfh(qu.w);

    float m = -INFINITY, ssum = 0.f;
    float acc[8] = {};

    for (int i = 0; i < dmax; i += 8) {
        int eidx[8];
        bool av[8];
        #pragma unroll
        for (int j = 0; j < 8; ++j) {
            av[j] = (i + j) < deg;
            int e = csrsrc[r0 + i + j];   // csrsrc padded; OOB reads masked below
            eidx[j] = av[j] ? e : 0;
        }
        int4 K[8], V[8];
        #pragma unroll
        for (int j = 0; j < 8; ++j) {
            const unsigned short* row = kv + (size_t)eidx[j] * 256 + gl * 8;
            K[j] = *(const int4*)(row);
            V[j] = *(const int4*)(row + 128);
        }
        float sc[8];
        #pragma unroll
        for (int j = 0; j < 8; ++j) {
            float p = qf[0] * bfl(K[j].x) + qf[1] * bfh(K[j].x)
                    + qf[2] * bfl(K[j].y) + qf[3] * bfh(K[j].y)
                    + qf[4] * bfl(K[j].z) + qf[5] * bfh(K[j].z)
                    + qf[6] * bfl(K[j].w) + qf[7] * bfh(K[j].w);
            p += __shfl_xor(p, 1);
            p += __shfl_xor(p, 2);
            sc[j] = av[j] ? p * INV_SQRT_C : -INFINITY;
        }
        float mn = m;
        #pragma unroll
        for (int j = 0; j < 8; ++j) mn = fmaxf(mn, sc[j]);
        if (mn > m) {
            float scale = __expf(m - mn);
            ssum *= scale;
            #pragma unroll
            for (int c = 0; c < 8; ++c) acc[c] *= scale;
            m = mn;
        }
        #pragma unroll
        for (int j = 0; j < 8; ++j) {
            float ej = av[j] ? __expf(sc[j] - m) : 0.f;
            ssum += ej;
            acc[0] += ej * bfl(V[j].x); acc[1] += ej * bfh(V[j].x);
            acc[2] += ej * bfl(V[j].y); acc[3] += ej * bfh(V[j].y);
            acc[4] += ej * bfl(V[j].z); acc[5] += ej * bfh(V[j].z);
            acc[6] += ej * bfl(V[j].w); acc[7] += ej * bfh(V[j].w);
        }
    }

    if (nv) {
        float inv = (ssum > 0.f) ? 1.0f / ssum : 0.f;
        int4 su = *(const int4*)(sk + (size_t)n * 128 + gl * 8);
        float4 o0, o1;
        o0.x = acc[0] * inv + bfl(su.x); o0.y = acc[1] * inv + bfh(su.x);
        o0.z = acc[2] * inv + bfl(su.y); o0.w = acc[3] * inv + bfh(su.y);
        o1.x = acc[4] * inv + bfl(su.z); o1.y = acc[5] * inv + bfh(su.z);
        o1.z = acc[6] * inv + bfl(su.w); o1.w = acc[7] * inv + bfh(su.w);
        float* op = hnext + (size_t)n * 128 + gl * 8;
        *(float4*)(op) = o0;
        *(float4*)(op + 4) = o1;
    }
}

// ---------------- BatchNorm ----------------

__global__ __launch_bounds__(256) void bn_stats_kernel(const float* __restrict__ x, int N, int F,
                                                       float* __restrict__ stats) {
    int tid = threadIdx.x;
    int F4 = F >> 2;
    int c4 = tid & (F4 - 1);
    int rpi = 256 / F4;
    int r = blockIdx.x * rpi + (tid / F4);
    int rstep = gridDim.x * rpi;
    float sx = 0, sy = 0, sz = 0, sw = 0, qx = 0, qy = 0, qz = 0, qw = 0;
    for (; r < N; r += rstep) {
        float4 v = *(const float4*)(x + (size_t)r * F + c4 * 4);
        sx += v.x; sy += v.y; sz += v.z; sw += v.w;
        qx += v.x * v.x; qy += v.y * v.y; qz += v.z * v.z; qw += v.w * v.w;
    }
    __shared__ float4 ls[256], lq[256];
    ls[tid] = make_float4(sx, sy, sz, sw);
    lq[tid] = make_float4(qx, qy, qz, qw);
    __syncthreads();
    if (tid < F4) {
        for (int c = F4; c < 256; c += F4) {
            float4 a = ls[tid + c], b = lq[tid + c];
            sx += a.x; sy += a.y; sz += a.z; sw += a.w;
            qx += b.x; qy += b.y; qz += b.z; qw += b.w;
        }
        atomicAdd(&stats[tid * 4 + 0], sx);
        atomicAdd(&stats[tid * 4 + 1], sy);
        atomicAdd(&stats[tid * 4 + 2], sz);
        atomicAdd(&stats[tid * 4 + 3], sw);
        atomicAdd(&stats[512 + tid * 4 + 0], qx);
        atomicAdd(&stats[512 + tid * 4 + 1], qy);
        atomicAdd(&stats[512 + tid * 4 + 2], qz);
        atomicAdd(&stats[512 + tid * 4 + 3], qw);
    }
}

__global__ void bn_finalize_kernel(float* __restrict__ stats, const float* __restrict__ g,
                                   const float* __restrict__ b, int N, int F) {
    int f = threadIdx.x;
    if (f < F) {
        float invN = 1.0f / (float)N;
        float mu = stats[f] * invN;
        float var = stats[512 + f] * invN - mu * mu;
        float sc = rsqrtf(var + BN_EPS) * g[f];
        stats[256 + f] = sc;
        stats[768 + f] = b[f] - mu * sc;
    }
}

__global__ void bn_apply_bf16_kernel(const float* __restrict__ x, unsigned short* __restrict__ y,
                                     const float* __restrict__ stats, int N, int F) {
    const float* scale = stats + 256;
    const float* shift = stats + 768;
    size_t total4 = (size_t)N * F >> 2;
    int Fm = F - 1;
    for (size_t t = (size_t)blockIdx.x * blockDim.x + threadIdx.x; t < total4;
         t += (size_t)gridDim.x * blockDim.x) {
        size_t i = t * 4;
        int f = (int)(i & (size_t)Fm);
        float4 v = *(const float4*)(x + i);
        float r0 = fmaxf(v.x * scale[f + 0] + shift[f + 0], 0.f);
        float r1 = fmaxf(v.y * scale[f + 1] + shift[f + 1], 0.f);
        float r2 = fmaxf(v.z * scale[f + 2] + shift[f + 2], 0.f);
        float r3 = fmaxf(v.w * scale[f + 3] + shift[f + 3], 0.f);
        ushort4 u;
        u.x = f2bf(r0); u.y = f2bf(r1); u.z = f2bf(r2); u.w = f2bf(r3);
        *(ushort4*)(y + i) = u;
    }
}

__global__ void bn_apply_f32_kernel(const float* __restrict__ x, float* __restrict__ y,
                                    const float* __restrict__ stats, int N, int F) {
    const float* scale = stats + 256;
    const float* shift = stats + 768;
    size_t total4 = (size_t)N * F >> 2;
    int Fm = F - 1;
    for (size_t t = (size_t)blockIdx.x * blockDim.x + threadIdx.x; t < total4;
         t += (size_t)gridDim.x * blockDim.x) {
        size_t i = t * 4;
        int f = (int)(i & (size_t)Fm);
        float4 v = *(const float4*)(x + i);
        float4 o;
        o.x = fmaxf(v.x * scale[f + 0] + shift[f + 0], 0.f);
        o.y = fmaxf(v.y * scale[f + 1] + shift[f + 1], 0.f);
        o.z = fmaxf(v.z * scale[f + 2] + shift[f + 2], 0.f);
        o.w = fmaxf(v.w * scale[f + 3] + shift[f + 3], 0.f);
        *(float4*)(y + i) = o;
    }
}

// ---------------- launch ----------------

static inline size_t al16(size_t x) { return (x + 15) & ~(size_t)15; }

extern "C" void kernel_launch(void* const* d_in, const int* in_sizes, int n_in,
                              void* d_out, int out_size, void* d_ws, size_t ws_size,
                              hipStream_t stream) {
    const float* x    = (const float*)d_in[0];
    const int*   edge = (const int*)d_in[1];
    const float* Wq   = (const float*)d_in[2];
    const float* bq   = (const float*)d_in[3];
    const float* Wk   = (const float*)d_in[4];
    const float* bk   = (const float*)d_in[5];
    const float* Wv   = (const float*)d_in[6];
    const float* bv   = (const float*)d_in[7];
    const float* Wsk  = (const float*)d_in[8];
    const float* bsk  = (const float*)d_in[9];
    const float* bng  = (const float*)d_in[10];
    const float* bnb  = (const float*)d_in[11];
    const float* Wo   = (const float*)d_in[12];
    const float* bo   = (const float*)d_in[13];
    const float* bnog = (const float*)d_in[14];
    const float* bnob = (const float*)d_in[15];

    const int N = in_sizes[0] / D_FEAT;
    const int E = in_sizes[1] / 2;
    const int* esrc = edge;
    const int* edst = edge + E;

    const int SB = (N + SORT_NPB - 1) / SORT_NPB;

    char* wsb = (char*)d_ws;
    unsigned short* xb = (unsigned short*)wsb; wsb += al16((size_t)N * 128 * 2);
    unsigned short* hb = (unsigned short*)wsb; wsb += al16((size_t)N * 128 * 2);
    unsigned short* kv = (unsigned short*)wsb; wsb += al16((size_t)N * 256 * 2);
    unsigned short* q  = (unsigned short*)wsb; wsb += al16((size_t)N * 128 * 2);
    unsigned short* s  = (unsigned short*)wsb; wsb += al16((size_t)N * 128 * 2);
    float* hnext  = (float*)wsb; wsb += al16((size_t)N * 128 * 4);
    float* outpre = (float*)wsb; wsb += al16((size_t)N * 64 * 4);
    unsigned short* Wt  = (unsigned short*)wsb; wsb += al16((size_t)NLAYER * 4 * 16384 * 2);
    unsigned short* Wot = (unsigned short*)wsb; wsb += al16((size_t)64 * 128 * 2);
    float* stats  = (float*)wsb; wsb += al16(1024 * 4);
    int* rowptr   = (int*)wsb;   wsb += al16((size_t)(N + 1) * 4);
    int* deg      = (int*)wsb;   wsb += al16((size_t)N * 4);
    int* csrsrc   = (int*)wsb;   wsb += al16((size_t)(E + 64) * 4);  // +pad for unroll-8 overread
    int* partials = (int*)wsb;   wsb += al16(256 * 4);
    int* bhist    = (int*)wsb;   wsb += al16((size_t)256 * SB * 4);
    int* binoff   = (int*)wsb;   wsb += al16(256 * 4);
    int* order    = (int*)wsb;   wsb += al16((size_t)N * 4);

    // conversions
    cvt_bf16_kernel<<<2048, 256, 0, stream>>>(x, xb, (size_t)N * 128 / 4);
    transp_cvt_kernel<<<256, 256, 0, stream>>>(Wq,  Wt + 0 * 16384, NLAYER, 16384, 4 * 16384, 128, 128);
    transp_cvt_kernel<<<256, 256, 0, stream>>>(Wk,  Wt + 1 * 16384, NLAYER, 16384, 4 * 16384, 128, 128);
    transp_cvt_kernel<<<256, 256, 0, stream>>>(Wv,  Wt + 2 * 16384, NLAYER, 16384, 4 * 16384, 128, 128);
    transp_cvt_kernel<<<256, 256, 0, stream>>>(Wsk, Wt + 3 * 16384, NLAYER, 16384, 4 * 16384, 128, 128);
    transp_cvt_kernel<<<64, 256, 0, stream>>>(Wo, Wot, 1, 8192, 8192, 128, 64);

    // CSR build
    const int nb1 = (N + 1023) / 1024;
    hipMemsetAsync(deg, 0, (size_t)N * 4, stream);
    hist_kernel<<<(E + 255) / 256, 256, 0, stream>>>(edst, E, deg);
    scan1_kernel<<<nb1, 256, 0, stream>>>(deg, N, rowptr, partials);
    scan2_kernel<<<1, 64, 0, stream>>>(partials, nb1);
    scan3_kernel<<<nb1, 256, 0, stream>>>(rowptr, N, partials);
    hipMemsetAsync(deg, 0, (size_t)N * 4, stream);
    scatter_kernel<<<(E + 255) / 256, 256, 0, stream>>>(esrc, edst, E, rowptr, deg, csrsrc);

    // degree-binned node order
    bin_blockhist_kernel<<<SB, 256, 0, stream>>>(rowptr, N, SB, bhist);
    bin_colscan_kernel<<<1, 256, 0, stream>>>(bhist, SB, binoff);
    bin_order_kernel<<<SB, 256, 0, stream>>>(rowptr, N, SB, bhist, binoff, order);

    const int gemm_rb = (N + 127) / 128;
    const int attn_blocks = (N + 15) / 16;
    const unsigned short* hin = xb;
    for (int l = 0; l < NLAYER; ++l) {
        gemm_qkvs_kernel<<<dim3(gemm_rb, 4), 256, 0, stream>>>(
            hin, N, Wt + (size_t)l * 4 * 16384,
            bq + l * 128, bk + l * 128, bv + l * 128, bsk + l * 128,
            q, kv, s);
        attn_kernel<<<attn_blocks, 256, 0, stream>>>(q, kv, s, rowptr, csrsrc, order, hnext, N);
        hipMemsetAsync(stats, 0, 1024 * 4, stream);
        bn_stats_kernel<<<256, 256, 0, stream>>>(hnext, N, 128, stats);
        bn_finalize_kernel<<<1, 128, 0, stream>>>(stats, bng + l * 128, bnb + l * 128, N, 128);
        bn_apply_bf16_kernel<<<2048, 256, 0, stream>>>(hnext, hb, stats, N, 128);
        hin = hb;
    }

    gemm_final_kernel<<<gemm_rb, 256, 0, stream>>>(hb, N, Wot, bo, outpre);
    hipMemsetAsync(stats, 0, 1024 * 4, stream);
    bn_stats_kernel<<<256, 256, 0, stream>>>(outpre, N, 64, stats);
    bn_finalize_kernel<<<1, 128, 0, stream>>>(stats, bnog, bnob, N, 64);
    bn_apply_f32_kernel<<<2048, 256, 0, stream>>>(outpre, (float*)d_out, stats, N, 64);
}

// Round 8
// 633.761 us; speedup vs baseline: 1.2038x; 1.0364x over previous
//
#include <hip/hip_runtime.h>
#include <hip/hip_bf16.h>
#include <math.h>

#define D_FEAT 128
#define NLAYER 3
#define BN_EPS 1e-5f
#define INV_SQRT_C 0.17677669529663687f  // 1/sqrt(32)
#define SORT_NPB 1024                    // nodes per sort block

typedef __bf16 bf16x8 __attribute__((ext_vector_type(8)));
typedef float f32x4 __attribute__((ext_vector_type(4)));

static __device__ __forceinline__ unsigned short f2bf(float f) {
    return __builtin_bit_cast(unsigned short, __float2bfloat16(f));
}
static __device__ __forceinline__ float bfl(unsigned u) { return __uint_as_float(u << 16); }
static __device__ __forceinline__ float bfh(unsigned u) { return __uint_as_float(u & 0xffff0000u); }

// ---------------- conversions ----------------

__global__ void cvt_bf16_kernel(const float* __restrict__ src, unsigned short* __restrict__ dst,
                                size_t n4) {
    for (size_t t = (size_t)blockIdx.x * blockDim.x + threadIdx.x; t < n4;
         t += (size_t)gridDim.x * blockDim.x) {
        size_t i = t * 4;
        float4 v = *(const float4*)(src + i);
        ushort4 u;
        u.x = f2bf(v.x); u.y = f2bf(v.y); u.z = f2bf(v.z); u.w = f2bf(v.w);
        *(ushort4*)(dst + i) = u;
    }
}

// One kernel: transpose+convert all 12 layer weights [128k x 128n]->[n][k] and Wo [128x64]->[64][128].
__global__ void prep_weights_kernel(
    const float* __restrict__ Wq, const float* __restrict__ Wk,
    const float* __restrict__ Wv, const float* __restrict__ Ws,
    const float* __restrict__ Wo,
    unsigned short* __restrict__ Wt, unsigned short* __restrict__ Wot)
{
    const int permat = 16384;
    const int main_total = NLAYER * 4 * permat;
    const int total = main_total + 64 * 128;
    for (int i = blockIdx.x * blockDim.x + threadIdx.x; i < total;
         i += gridDim.x * blockDim.x) {
        if (i < main_total) {
            int l = i / (4 * permat);
            int rem = i - l * (4 * permat);
            int mat = rem / permat;
            int e = rem - mat * permat;
            int nn = e >> 7;       // out col (0..127)
            int kk = e & 127;      // k index
            const float* src = (mat == 0) ? Wq : (mat == 1) ? Wk : (mat == 2) ? Wv : Ws;
            Wt[(size_t)l * 4 * permat + mat * permat + nn * 128 + kk] =
                f2bf(src[(size_t)l * permat + kk * 128 + nn]);
        } else {
            int e = i - main_total;
            int nn = e >> 7;
            int kk = e & 127;
            Wot[nn * 128 + kk] = f2bf(Wo[kk * 64 + nn]);
        }
    }
}

// ---------------- CSR build ----------------

__global__ void hist_kernel(const int* __restrict__ dst, int E, int* __restrict__ deg) {
    int e = blockIdx.x * blockDim.x + threadIdx.x;
    if (e < E) atomicAdd(&deg[dst[e]], 1);
}

__global__ __launch_bounds__(256) void scan1_kernel(const int* __restrict__ deg, int n,
                                                    int* __restrict__ rowptr,
                                                    int* __restrict__ partials) {
    int b = blockIdx.x, tid = threadIdx.x;
    int base = b * 1024 + tid * 4;
    int4 d = {0, 0, 0, 0};
    if (base + 3 < n) d = *(const int4*)(deg + base);
    else {
        if (base + 0 < n) d.x = deg[base + 0];
        if (base + 1 < n) d.y = deg[base + 1];
        if (base + 2 < n) d.z = deg[base + 2];
        if (base + 3 < n) d.w = deg[base + 3];
    }
    int p0 = d.x, p1 = p0 + d.y, p2 = p1 + d.z, p3 = p2 + d.w;
    int v = p3;
    int lane = tid & 63;
    #pragma unroll
    for (int off = 1; off < 64; off <<= 1) {
        int t = __shfl_up(v, off);
        if (lane >= off) v += t;
    }
    __shared__ int wsum[4];
    int w = tid >> 6;
    if (lane == 63) wsum[w] = v;
    __syncthreads();
    int woff = 0;
    #pragma unroll
    for (int j = 0; j < 4; ++j) if (j < w) woff += wsum[j];
    int excl = woff + v - p3;
    if (base + 0 < n) rowptr[base + 1] = excl + p0;
    if (base + 1 < n) rowptr[base + 2] = excl + p1;
    if (base + 2 < n) rowptr[base + 3] = excl + p2;
    if (base + 3 < n) rowptr[base + 4] = excl + p3;
    if (tid == 255) partials[b] = excl + p3;
    if (b == 0 && tid == 0) rowptr[0] = 0;
}

__global__ void scan2_kernel(int* __restrict__ partials, int nb) {
    int lane = threadIdx.x;
    int v = (lane < nb) ? partials[lane] : 0;
    #pragma unroll
    for (int off = 1; off < 64; off <<= 1) {
        int t = __shfl_up(v, off);
        if (lane >= off) v += t;
    }
    if (lane < nb) partials[lane] = v;  // inclusive
}

__global__ __launch_bounds__(256) void scan3_kernel(int* __restrict__ rowptr, int n,
                                                    const int* __restrict__ partials) {
    int b = blockIdx.x, tid = threadIdx.x;
    if (b == 0) return;
    int off = partials[b - 1];
    int base = b * 1024 + tid * 4;
    #pragma unroll
    for (int j = 0; j < 4; ++j) {
        int i = base + j;
        if (i < n) rowptr[i + 1] += off;
    }
}

__global__ void scatter_kernel(const int* __restrict__ src, const int* __restrict__ dst, int E,
                               const int* __restrict__ rowptr, int* __restrict__ cursor,
                               int* __restrict__ csrsrc) {
    int e = blockIdx.x * blockDim.x + threadIdx.x;
    if (e < E) {
        int d = dst[e];
        int p = atomicAdd(&cursor[d], 1);
        csrsrc[rowptr[d] + p] = src[e];
    }
}

// ---------------- degree binning: contention-free counting sort ----------------

__global__ __launch_bounds__(256) void bin_blockhist_kernel(
    const int* __restrict__ rowptr, int n, int B, int* __restrict__ bhist)
{
    __shared__ int h[256];
    int b = blockIdx.x, tid = threadIdx.x;
    h[tid] = 0;
    __syncthreads();
    #pragma unroll
    for (int j = 0; j < SORT_NPB / 256; ++j) {
        int i = b * SORT_NPB + j * 256 + tid;
        if (i < n) {
            int d = rowptr[i + 1] - rowptr[i];
            if (d > 255) d = 255;
            atomicAdd(&h[d], 1);
        }
    }
    __syncthreads();
    bhist[tid * B + b] = h[tid];
}

__global__ __launch_bounds__(256) void bin_colscan_kernel(
    int* __restrict__ bhist, int B, int* __restrict__ binoff)
{
    int d = threadIdx.x;
    int run = 0;
    for (int b = 0; b < B; ++b) {
        int c = bhist[d * B + b];
        bhist[d * B + b] = run;
        run += c;
    }
    __shared__ int sd[256];
    sd[d] = run;
    __syncthreads();
    int v = run;
    for (int s = 1; s < 256; s <<= 1) {
        int t = (d >= s) ? sd[d - s] : 0;
        __syncthreads();
        sd[d] += t;
        __syncthreads();
    }
    binoff[d] = sd[d] - v;  // exclusive
}

__global__ __launch_bounds__(256) void bin_order_kernel(
    const int* __restrict__ rowptr, int n, int B,
    const int* __restrict__ bhist, const int* __restrict__ binoff,
    int* __restrict__ order)
{
    __shared__ int cur[256];
    int b = blockIdx.x, tid = threadIdx.x;
    cur[tid] = binoff[tid] + bhist[tid * B + b];
    __syncthreads();
    #pragma unroll
    for (int j = 0; j < SORT_NPB / 256; ++j) {
        int i = b * SORT_NPB + j * 256 + tid;
        if (i < n) {
            int d = rowptr[i + 1] - rowptr[i];
            if (d > 255) d = 255;
            int pos = atomicAdd(&cur[d], 1);
            order[pos] = i;
        }
    }
}

// ---------------- LDS-free direct-register MFMA GEMM ----------------

__global__ __launch_bounds__(256) void gemm_qkvs_kernel(
    const unsigned short* __restrict__ A, int M,
    const unsigned short* __restrict__ Wt,
    const float* __restrict__ b0, const float* __restrict__ b1,
    const float* __restrict__ b2, const float* __restrict__ b3,
    unsigned short* __restrict__ q, unsigned short* __restrict__ kv,
    unsigned short* __restrict__ s)
{
    int r0 = blockIdx.x * 128;
    int ct = blockIdx.y;
    int tid = threadIdx.x;
    int wid = tid >> 6, lane = tid & 63;
    int wm = wid >> 1, wn = wid & 1;
    int lr = lane & 15, lk = lane >> 4;
    const unsigned short* W = Wt + (size_t)ct * 16384;

    f32x4 acc[4][4] = {};
    #pragma unroll
    for (int ks = 0; ks < 4; ++ks) {
        int ko = ks * 32 + lk * 8;
        bf16x8 a[4], b[4];
        #pragma unroll
        for (int mi = 0; mi < 4; ++mi) {
            int arow = r0 + wm * 64 + mi * 16 + lr;
            int4 t = {0, 0, 0, 0};
            if (arow < M) t = *(const int4*)(A + (size_t)arow * 128 + ko);
            a[mi] = __builtin_bit_cast(bf16x8, t);
        }
        #pragma unroll
        for (int nj = 0; nj < 4; ++nj) {
            int4 t = *(const int4*)(W + (size_t)(wn * 64 + nj * 16 + lr) * 128 + ko);
            b[nj] = __builtin_bit_cast(bf16x8, t);
        }
        #pragma unroll
        for (int mi = 0; mi < 4; ++mi)
            #pragma unroll
            for (int nj = 0; nj < 4; ++nj)
                acc[mi][nj] = __builtin_amdgcn_mfma_f32_16x16x32_bf16(
                    a[mi], b[nj], acc[mi][nj], 0, 0, 0);
    }

    const float* bias = (ct == 0) ? b0 : (ct == 1) ? b1 : (ct == 2) ? b2 : b3;
    #pragma unroll
    for (int mi = 0; mi < 4; ++mi) {
        #pragma unroll
        for (int nj = 0; nj < 4; ++nj) {
            int col = wn * 64 + nj * 16 + lr;
            float bv = bias[col];
            #pragma unroll
            for (int reg = 0; reg < 4; ++reg) {
                int rw = r0 + wm * 64 + mi * 16 + lk * 4 + reg;
                if (rw < M) {
                    unsigned short val = f2bf(acc[mi][nj][reg] + bv);
                    if (ct == 0) q[(size_t)rw * 128 + col] = val;
                    else if (ct == 1) kv[(size_t)rw * 256 + col] = val;
                    else if (ct == 2) kv[(size_t)rw * 256 + 128 + col] = val;
                    else s[(size_t)rw * 128 + col] = val;
                }
            }
        }
    }
}

__global__ __launch_bounds__(256) void gemm_final_kernel(
    const unsigned short* __restrict__ A, int M,
    const unsigned short* __restrict__ Wot, const float* __restrict__ bias,
    float* __restrict__ out)
{
    int r0 = blockIdx.x * 128;
    int tid = threadIdx.x;
    int wid = tid >> 6, lane = tid & 63;
    int wm = wid >> 1, wn = wid & 1;
    int lr = lane & 15, lk = lane >> 4;

    f32x4 acc[4][2] = {};
    #pragma unroll
    for (int ks = 0; ks < 4; ++ks) {
        int ko = ks * 32 + lk * 8;
        bf16x8 a[4], b[2];
        #pragma unroll
        for (int mi = 0; mi < 4; ++mi) {
            int arow = r0 + wm * 64 + mi * 16 + lr;
            int4 t = {0, 0, 0, 0};
            if (arow < M) t = *(const int4*)(A + (size_t)arow * 128 + ko);
            a[mi] = __builtin_bit_cast(bf16x8, t);
        }
        #pragma unroll
        for (int nj = 0; nj < 2; ++nj) {
            int4 t = *(const int4*)(Wot + (size_t)(wn * 32 + nj * 16 + lr) * 128 + ko);
            b[nj] = __builtin_bit_cast(bf16x8, t);
        }
        #pragma unroll
        for (int mi = 0; mi < 4; ++mi)
            #pragma unroll
            for (int nj = 0; nj < 2; ++nj)
                acc[mi][nj] = __builtin_amdgcn_mfma_f32_16x16x32_bf16(
                    a[mi], b[nj], acc[mi][nj], 0, 0, 0);
    }

    #pragma unroll
    for (int mi = 0; mi < 4; ++mi) {
        #pragma unroll
        for (int nj = 0; nj < 2; ++nj) {
            int col = wn * 32 + nj * 16 + lr;
            float bv = bias[col];
            #pragma unroll
            for (int reg = 0; reg < 4; ++reg) {
                int rw = r0 + wm * 64 + mi * 16 + lk * 4 + reg;
                if (rw < M) out[(size_t)rw * 64 + col] = acc[mi][nj][reg] + bv;
            }
        }
    }
}

// ---------------- Fused flash-style attention: 4 nodes/wave, unroll 8 ----------------
// launch_bounds(256,2): allow ~256 VGPR so all 16 gathers stay in flight.

__global__ __launch_bounds__(256, 2) void attn_kernel(
    const unsigned short* __restrict__ q, const unsigned short* __restrict__ kv,
    const unsigned short* __restrict__ sk,
    const int* __restrict__ rowptr, const int* __restrict__ csrsrc,
    const int* __restrict__ order,
    float* __restrict__ hnext, int N)
{
    int wave = (blockIdx.x * blockDim.x + threadIdx.x) >> 6;
    int lane = threadIdx.x & 63;
    int gl = lane & 15;
    int slot = wave * 4 + (lane >> 4);
    bool nv = slot < N;
    int n = nv ? order[slot] : 0;

    int r0 = rowptr[n], r1 = rowptr[n + 1];
    int deg = nv ? (r1 - r0) : 0;
    int dmax = deg;
    dmax = max(dmax, __shfl_xor(dmax, 16));
    dmax = max(dmax, __shfl_xor(dmax, 32));

    int4 qu = *(const int4*)(q + (size_t)n * 128 + gl * 8);
    float qf[8];
    qf[0] = bfl(qu.x); qf[1] = bfh(qu.x); qf[2] = bfl(qu.y); qf[3] = bfh(qu.y);
    qf[4] = bfl(qu.z); qf[5] = bfh(qu.z); qf[6] = bfl(qu.w); qf[7] = bfh(qu.w);

    float m = -INFINITY, ssum = 0.f;
    float acc[8] = {};

    for (int i = 0; i < dmax; i += 8) {
        int eidx[8];
        bool av[8];
        #pragma unroll
        for (int j = 0; j < 8; ++j) {
            av[j] = (i + j) < deg;
            int e = csrsrc[r0 + i + j];   // csrsrc padded; OOB reads masked below
            eidx[j] = av[j] ? e : 0;
        }
        int4 K[8], V[8];
        #pragma unroll
        for (int j = 0; j < 8; ++j) {
            const unsigned short* row = kv + (size_t)eidx[j] * 256 + gl * 8;
            K[j] = *(const int4*)(row);
            V[j] = *(const int4*)(row + 128);
        }
        float sc[8];
        #pragma unroll
        for (int j = 0; j < 8; ++j) {
            float p = qf[0] * bfl(K[j].x) + qf[1] * bfh(K[j].x)
                    + qf[2] * bfl(K[j].y) + qf[3] * bfh(K[j].y)
                    + qf[4] * bfl(K[j].z) + qf[5] * bfh(K[j].z)
                    + qf[6] * bfl(K[j].w) + qf[7] * bfh(K[j].w);
            p += __shfl_xor(p, 1);
            p += __shfl_xor(p, 2);
            sc[j] = av[j] ? p * INV_SQRT_C : -INFINITY;
        }
        float mn = m;
        #pragma unroll
        for (int j = 0; j < 8; ++j) mn = fmaxf(mn, sc[j]);
        if (mn > m) {
            float scale = __expf(m - mn);
            ssum *= scale;
            #pragma unroll
            for (int c = 0; c < 8; ++c) acc[c] *= scale;
            m = mn;
        }
        #pragma unroll
        for (int j = 0; j < 8; ++j) {
            float ej = av[j] ? __expf(sc[j] - m) : 0.f;
            ssum += ej;
            acc[0] += ej * bfl(V[j].x); acc[1] += ej * bfh(V[j].x);
            acc[2] += ej * bfl(V[j].y); acc[3] += ej * bfh(V[j].y);
            acc[4] += ej * bfl(V[j].z); acc[5] += ej * bfh(V[j].z);
            acc[6] += ej * bfl(V[j].w); acc[7] += ej * bfh(V[j].w);
        }
    }

    if (nv) {
        float inv = (ssum > 0.f) ? 1.0f / ssum : 0.f;
        int4 su = *(const int4*)(sk + (size_t)n * 128 + gl * 8);
        float4 o0, o1;
        o0.x = acc[0] * inv + bfl(su.x); o0.y = acc[1] * inv + bfh(su.x);
        o0.z = acc[2] * inv + bfl(su.y); o0.w = acc[3] * inv + bfh(su.y);
        o1.x = acc[4] * inv + bfl(su.z); o1.y = acc[5] * inv + bfh(su.z);
        o1.z = acc[6] * inv + bfl(su.w); o1.w = acc[7] * inv + bfh(su.w);
        float* op = hnext + (size_t)n * 128 + gl * 8;
        *(float4*)(op) = o0;
        *(float4*)(op + 4) = o1;
    }
}

// ---------------- BatchNorm ----------------

__global__ __launch_bounds__(256) void bn_stats_kernel(const float* __restrict__ x, int N, int F,
                                                       float* __restrict__ stats) {
    int tid = threadIdx.x;
    int F4 = F >> 2;
    int c4 = tid & (F4 - 1);
    int rpi = 256 / F4;
    int r = blockIdx.x * rpi + (tid / F4);
    int rstep = gridDim.x * rpi;
    float sx = 0, sy = 0, sz = 0, sw = 0, qx = 0, qy = 0, qz = 0, qw = 0;
    for (; r < N; r += rstep) {
        float4 v = *(const float4*)(x + (size_t)r * F + c4 * 4);
        sx += v.x; sy += v.y; sz += v.z; sw += v.w;
        qx += v.x * v.x; qy += v.y * v.y; qz += v.z * v.z; qw += v.w * v.w;
    }
    __shared__ float4 ls[256], lq[256];
    ls[tid] = make_float4(sx, sy, sz, sw);
    lq[tid] = make_float4(qx, qy, qz, qw);
    __syncthreads();
    if (tid < F4) {
        for (int c = F4; c < 256; c += F4) {
            float4 a = ls[tid + c], b = lq[tid + c];
            sx += a.x; sy += a.y; sz += a.z; sw += a.w;
            qx += b.x; qy += b.y; qz += b.z; qw += b.w;
        }
        atomicAdd(&stats[tid * 4 + 0], sx);
        atomicAdd(&stats[tid * 4 + 1], sy);
        atomicAdd(&stats[tid * 4 + 2], sz);
        atomicAdd(&stats[tid * 4 + 3], sw);
        atomicAdd(&stats[512 + tid * 4 + 0], qx);
        atomicAdd(&stats[512 + tid * 4 + 1], qy);
        atomicAdd(&stats[512 + tid * 4 + 2], qz);
        atomicAdd(&stats[512 + tid * 4 + 3], qw);
    }
}

// BN apply + ReLU + bf16 out; derives scale/shift from raw sums in LDS (no finalize pass).
__global__ __launch_bounds__(256) void bn_apply_bf16_kernel(
    const float* __restrict__ x, unsigned short* __restrict__ y,
    const float* __restrict__ stats, const float* __restrict__ g,
    const float* __restrict__ b, int N, int F)
{
    __shared__ float scale[128], shift[128];
    int tid = threadIdx.x;
    if (tid < F) {
        float invN = 1.0f / (float)N;
        float mu = stats[tid] * invN;
        float var = stats[512 + tid] * invN - mu * mu;
        float sc = rsqrtf(var + BN_EPS) * g[tid];
        scale[tid] = sc;
        shift[tid] = b[tid] - mu * sc;
    }
    __syncthreads();
    size_t total4 = (size_t)N * F >> 2;
    int Fm = F - 1;
    for (size_t t = (size_t)blockIdx.x * blockDim.x + tid; t < total4;
         t += (size_t)gridDim.x * blockDim.x) {
        size_t i = t * 4;
        int f = (int)(i & (size_t)Fm);
        float4 v = *(const float4*)(x + i);
        float r0 = fmaxf(v.x * scale[f + 0] + shift[f + 0], 0.f);
        float r1 = fmaxf(v.y * scale[f + 1] + shift[f + 1], 0.f);
        float r2 = fmaxf(v.z * scale[f + 2] + shift[f + 2], 0.f);
        float r3 = fmaxf(v.w * scale[f + 3] + shift[f + 3], 0.f);
        ushort4 u;
        u.x = f2bf(r0); u.y = f2bf(r1); u.z = f2bf(r2); u.w = f2bf(r3);
        *(ushort4*)(y + i) = u;
    }
}

__global__ __launch_bounds__(256) void bn_apply_f32_kernel(
    const float* __restrict__ x, float* __restrict__ y,
    const float* __restrict__ stats, const float* __restrict__ g,
    const float* __restrict__ b, int N, int F)
{
    __shared__ float scale[128], shift[128];
    int tid = threadIdx.x;
    if (tid < F) {
        float invN = 1.0f / (float)N;
        float mu = stats[tid] * invN;
        float var = stats[512 + tid] * invN - mu * mu;
        float sc = rsqrtf(var + BN_EPS) * g[tid];
        scale[tid] = sc;
        shift[tid] = b[tid] - mu * sc;
    }
    __syncthreads();
    size_t total4 = (size_t)N * F >> 2;
    int Fm = F - 1;
    for (size_t t = (size_t)blockIdx.x * blockDim.x + tid; t < total4;
         t += (size_t)gridDim.x * blockDim.x) {
        size_t i = t * 4;
        int f = (int)(i & (size_t)Fm);
        float4 v = *(const float4*)(x + i);
        float4 o;
        o.x = fmaxf(v.x * scale[f + 0] + shift[f + 0], 0.f);
        o.y = fmaxf(v.y * scale[f + 1] + shift[f + 1], 0.f);
        o.z = fmaxf(v.z * scale[f + 2] + shift[f + 2], 0.f);
        o.w = fmaxf(v.w * scale[f + 3] + shift[f + 3], 0.f);
        *(float4*)(y + i) = o;
    }
}

// ---------------- launch ----------------

static inline size_t al16(size_t x) { return (x + 15) & ~(size_t)15; }

extern "C" void kernel_launch(void* const* d_in, const int* in_sizes, int n_in,
                              void* d_out, int out_size, void* d_ws, size_t ws_size,
                              hipStream_t stream) {
    const float* x    = (const float*)d_in[0];
    const int*   edge = (const int*)d_in[1];
    const float* Wq   = (const float*)d_in[2];
    const float* bq   = (const float*)d_in[3];
    const float* Wk   = (const float*)d_in[4];
    const float* bk   = (const float*)d_in[5];
    const float* Wv   = (const float*)d_in[6];
    const float* bv   = (const float*)d_in[7];
    const float* Wsk  = (const float*)d_in[8];
    const float* bsk  = (const float*)d_in[9];
    const float* bng  = (const float*)d_in[10];
    const float* bnb  = (const float*)d_in[11];
    const float* Wo   = (const float*)d_in[12];
    const float* bo   = (const float*)d_in[13];
    const float* bnog = (const float*)d_in[14];
    const float* bnob = (const float*)d_in[15];

    const int N = in_sizes[0] / D_FEAT;
    const int E = in_sizes[1] / 2;
    const int* esrc = edge;
    const int* edst = edge + E;

    const int SB = (N + SORT_NPB - 1) / SORT_NPB;

    char* wsb = (char*)d_ws;
    unsigned short* xb = (unsigned short*)wsb; wsb += al16((size_t)N * 128 * 2);
    unsigned short* hb = (unsigned short*)wsb; wsb += al16((size_t)N * 128 * 2);
    unsigned short* kv = (unsigned short*)wsb; wsb += al16((size_t)N * 256 * 2);
    unsigned short* q  = (unsigned short*)wsb; wsb += al16((size_t)N * 128 * 2);
    unsigned short* s  = (unsigned short*)wsb; wsb += al16((size_t)N * 128 * 2);
    float* hnext  = (float*)wsb; wsb += al16((size_t)N * 128 * 4);
    float* outpre = (float*)wsb; wsb += al16((size_t)N * 64 * 4);
    unsigned short* Wt  = (unsigned short*)wsb; wsb += al16((size_t)NLAYER * 4 * 16384 * 2);
    unsigned short* Wot = (unsigned short*)wsb; wsb += al16((size_t)64 * 128 * 2);
    float* stats  = (float*)wsb; wsb += al16(4096 * 4);   // 4 regions of 1024
    int* rowptr   = (int*)wsb;   wsb += al16((size_t)(N + 1) * 4);
    int* deg      = (int*)wsb;   wsb += al16((size_t)N * 4);
    int* csrsrc   = (int*)wsb;   wsb += al16((size_t)(E + 64) * 4);  // +pad for unroll-8 overread
    int* partials = (int*)wsb;   wsb += al16(256 * 4);
    int* bhist    = (int*)wsb;   wsb += al16((size_t)256 * SB * 4);
    int* binoff   = (int*)wsb;   wsb += al16(256 * 4);
    int* order    = (int*)wsb;   wsb += al16((size_t)N * 4);

    // conversions + stats arena zero
    cvt_bf16_kernel<<<2048, 256, 0, stream>>>(x, xb, (size_t)N * 128 / 4);
    prep_weights_kernel<<<256, 256, 0, stream>>>(Wq, Wk, Wv, Wsk, Wo, Wt, Wot);
    hipMemsetAsync(stats, 0, 4096 * 4, stream);

    // CSR build
    const int nb1 = (N + 1023) / 1024;
    hipMemsetAsync(deg, 0, (size_t)N * 4, stream);
    hist_kernel<<<(E + 255) / 256, 256, 0, stream>>>(edst, E, deg);
    scan1_kernel<<<nb1, 256, 0, stream>>>(deg, N, rowptr, partials);
    scan2_kernel<<<1, 64, 0, stream>>>(partials, nb1);
    scan3_kernel<<<nb1, 256, 0, stream>>>(rowptr, N, partials);
    hipMemsetAsync(deg, 0, (size_t)N * 4, stream);
    scatter_kernel<<<(E + 255) / 256, 256, 0, stream>>>(esrc, edst, E, rowptr, deg, csrsrc);

    // degree-binned node order
    bin_blockhist_kernel<<<SB, 256, 0, stream>>>(rowptr, N, SB, bhist);
    bin_colscan_kernel<<<1, 256, 0, stream>>>(bhist, SB, binoff);
    bin_order_kernel<<<SB, 256, 0, stream>>>(rowptr, N, SB, bhist, binoff, order);

    const int gemm_rb = (N + 127) / 128;
    const int attn_blocks = (N + 15) / 16;
    const unsigned short* hin = xb;
    for (int l = 0; l < NLAYER; ++l) {
        float* lstats = stats + l * 1024;
        gemm_qkvs_kernel<<<dim3(gemm_rb, 4), 256, 0, stream>>>(
            hin, N, Wt + (size_t)l * 4 * 16384,
            bq + l * 128, bk + l * 128, bv + l * 128, bsk + l * 128,
            q, kv, s);
        attn_kernel<<<attn_blocks, 256, 0, stream>>>(q, kv, s, rowptr, csrsrc, order, hnext, N);
        bn_stats_kernel<<<256, 256, 0, stream>>>(hnext, N, 128, lstats);
        bn_apply_bf16_kernel<<<2048, 256, 0, stream>>>(hnext, hb, lstats,
                                                       bng + l * 128, bnb + l * 128, N, 128);
        hin = hb;
    }

    float* fstats = stats + 3 * 1024;
    gemm_final_kernel<<<gemm_rb, 256, 0, stream>>>(hb, N, Wot, bo, outpre);
    bn_stats_kernel<<<256, 256, 0, stream>>>(outpre, N, 64, fstats);
    bn_apply_f32_kernel<<<2048, 256, 0, stream>>>(outpre, (float*)d_out, fstats,
                                                  bnog, bnob, N, 64);
}

// Round 9
// 607.015 us; speedup vs baseline: 1.2568x; 1.0441x over previous
//
#include <hip/hip_runtime.h>
#include <hip/hip_bf16.h>
#include <math.h>

#define D_FEAT 128
#define NLAYER 3
#define BN_EPS 1e-5f
#define INV_SQRT_C 0.17677669529663687f  // 1/sqrt(32)
#define SORT_NPB 1024                    // nodes per sort block

typedef __bf16 bf16x8 __attribute__((ext_vector_type(8)));
typedef float f32x4 __attribute__((ext_vector_type(4)));

static __device__ __forceinline__ unsigned short f2bf(float f) {
    return __builtin_bit_cast(unsigned short, __float2bfloat16(f));
}
static __device__ __forceinline__ float bfl(unsigned u) { return __uint_as_float(u << 16); }
static __device__ __forceinline__ float bfh(unsigned u) { return __uint_as_float(u & 0xffff0000u); }
static __device__ __forceinline__ unsigned packbf(float a, float b) {
    return (unsigned)f2bf(a) | ((unsigned)f2bf(b) << 16);
}

// ---------------- conversions ----------------

__global__ void cvt_bf16_kernel(const float* __restrict__ src, unsigned short* __restrict__ dst,
                                size_t n4) {
    for (size_t t = (size_t)blockIdx.x * blockDim.x + threadIdx.x; t < n4;
         t += (size_t)gridDim.x * blockDim.x) {
        size_t i = t * 4;
        float4 v = *(const float4*)(src + i);
        ushort4 u;
        u.x = f2bf(v.x); u.y = f2bf(v.y); u.z = f2bf(v.z); u.w = f2bf(v.w);
        *(ushort4*)(dst + i) = u;
    }
}

__global__ void prep_weights_kernel(
    const float* __restrict__ Wq, const float* __restrict__ Wk,
    const float* __restrict__ Wv, const float* __restrict__ Ws,
    const float* __restrict__ Wo,
    unsigned short* __restrict__ Wt, unsigned short* __restrict__ Wot)
{
    const int permat = 16384;
    const int main_total = NLAYER * 4 * permat;
    const int total = main_total + 64 * 128;
    for (int i = blockIdx.x * blockDim.x + threadIdx.x; i < total;
         i += gridDim.x * blockDim.x) {
        if (i < main_total) {
            int l = i / (4 * permat);
            int rem = i - l * (4 * permat);
            int mat = rem / permat;
            int e = rem - mat * permat;
            int nn = e >> 7;
            int kk = e & 127;
            const float* src = (mat == 0) ? Wq : (mat == 1) ? Wk : (mat == 2) ? Wv : Ws;
            Wt[(size_t)l * 4 * permat + mat * permat + nn * 128 + kk] =
                f2bf(src[(size_t)l * permat + kk * 128 + nn]);
        } else {
            int e = i - main_total;
            int nn = e >> 7;
            int kk = e & 127;
            Wot[nn * 128 + kk] = f2bf(Wo[kk * 64 + nn]);
        }
    }
}

// ---------------- CSR build ----------------

__global__ void hist_kernel(const int* __restrict__ dst, int E, int* __restrict__ deg) {
    int e = blockIdx.x * blockDim.x + threadIdx.x;
    if (e < E) atomicAdd(&deg[dst[e]], 1);
}

__global__ __launch_bounds__(256) void scan1_kernel(const int* __restrict__ deg, int n,
                                                    int* __restrict__ rowptr,
                                                    int* __restrict__ partials) {
    int b = blockIdx.x, tid = threadIdx.x;
    int base = b * 1024 + tid * 4;
    int4 d = {0, 0, 0, 0};
    if (base + 3 < n) d = *(const int4*)(deg + base);
    else {
        if (base + 0 < n) d.x = deg[base + 0];
        if (base + 1 < n) d.y = deg[base + 1];
        if (base + 2 < n) d.z = deg[base + 2];
        if (base + 3 < n) d.w = deg[base + 3];
    }
    int p0 = d.x, p1 = p0 + d.y, p2 = p1 + d.z, p3 = p2 + d.w;
    int v = p3;
    int lane = tid & 63;
    #pragma unroll
    for (int off = 1; off < 64; off <<= 1) {
        int t = __shfl_up(v, off);
        if (lane >= off) v += t;
    }
    __shared__ int wsum[4];
    int w = tid >> 6;
    if (lane == 63) wsum[w] = v;
    __syncthreads();
    int woff = 0;
    #pragma unroll
    for (int j = 0; j < 4; ++j) if (j < w) woff += wsum[j];
    int excl = woff + v - p3;
    if (base + 0 < n) rowptr[base + 1] = excl + p0;
    if (base + 1 < n) rowptr[base + 2] = excl + p1;
    if (base + 2 < n) rowptr[base + 3] = excl + p2;
    if (base + 3 < n) rowptr[base + 4] = excl + p3;
    if (tid == 255) partials[b] = excl + p3;
    if (b == 0 && tid == 0) rowptr[0] = 0;
}

__global__ void scan2_kernel(int* __restrict__ partials, int nb) {
    int lane = threadIdx.x;
    int v = (lane < nb) ? partials[lane] : 0;
    #pragma unroll
    for (int off = 1; off < 64; off <<= 1) {
        int t = __shfl_up(v, off);
        if (lane >= off) v += t;
    }
    if (lane < nb) partials[lane] = v;  // inclusive
}

__global__ __launch_bounds__(256) void scan3_kernel(int* __restrict__ rowptr, int n,
                                                    const int* __restrict__ partials) {
    int b = blockIdx.x, tid = threadIdx.x;
    if (b == 0) return;
    int off = partials[b - 1];
    int base = b * 1024 + tid * 4;
    #pragma unroll
    for (int j = 0; j < 4; ++j) {
        int i = base + j;
        if (i < n) rowptr[i + 1] += off;
    }
}

__global__ void scatter_kernel(const int* __restrict__ src, const int* __restrict__ dst, int E,
                               const int* __restrict__ rowptr, int* __restrict__ cursor,
                               int* __restrict__ csrsrc) {
    int e = blockIdx.x * blockDim.x + threadIdx.x;
    if (e < E) {
        int d = dst[e];
        int p = atomicAdd(&cursor[d], 1);
        csrsrc[rowptr[d] + p] = src[e];
    }
}

// ---------------- degree binning: contention-free counting sort (DESCENDING) ----------------

__global__ __launch_bounds__(256) void bin_blockhist_kernel(
    const int* __restrict__ rowptr, int n, int B, int* __restrict__ bhist)
{
    __shared__ int h[256];
    int b = blockIdx.x, tid = threadIdx.x;
    h[tid] = 0;
    __syncthreads();
    #pragma unroll
    for (int j = 0; j < SORT_NPB / 256; ++j) {
        int i = b * SORT_NPB + j * 256 + tid;
        if (i < n) {
            int d = rowptr[i + 1] - rowptr[i];
            if (d > 255) d = 255;
            atomicAdd(&h[255 - d], 1);   // descending: big degrees -> low bins
        }
    }
    __syncthreads();
    bhist[tid * B + b] = h[tid];
}

__global__ __launch_bounds__(256) void bin_colscan_kernel(
    int* __restrict__ bhist, int B, int* __restrict__ binoff)
{
    int d = threadIdx.x;
    int run = 0;
    for (int b = 0; b < B; ++b) {
        int c = bhist[d * B + b];
        bhist[d * B + b] = run;
        run += c;
    }
    __shared__ int sd[256];
    sd[d] = run;
    __syncthreads();
    int v = run;
    for (int s = 1; s < 256; s <<= 1) {
        int t = (d >= s) ? sd[d - s] : 0;
        __syncthreads();
        sd[d] += t;
        __syncthreads();
    }
    binoff[d] = sd[d] - v;  // exclusive
}

__global__ __launch_bounds__(256) void bin_order_kernel(
    const int* __restrict__ rowptr, int n, int B,
    const int* __restrict__ bhist, const int* __restrict__ binoff,
    int* __restrict__ order)
{
    __shared__ int cur[256];
    int b = blockIdx.x, tid = threadIdx.x;
    cur[tid] = binoff[tid] + bhist[tid * B + b];
    __syncthreads();
    #pragma unroll
    for (int j = 0; j < SORT_NPB / 256; ++j) {
        int i = b * SORT_NPB + j * 256 + tid;
        if (i < n) {
            int d = rowptr[i + 1] - rowptr[i];
            if (d > 255) d = 255;
            int pos = atomicAdd(&cur[255 - d], 1);
            order[pos] = i;
        }
    }
}

// ---------------- LDS-free direct-register MFMA GEMM, ct-pairs, inline BN ----------------
// A: bf16 [M][128]. If mode!=0, per-channel BN scale/shift derived from raw stats
// (+ReLU) is applied to each a-frag. Each block computes 2 weight matrices
// (ct = blockIdx.y*2 + cc), reusing the BN'd a-frags.

__global__ __launch_bounds__(256, 2) void gemm_qkvs_kernel(
    const unsigned short* __restrict__ A,
    const float* __restrict__ stats, const float* __restrict__ g,
    const float* __restrict__ bb, int mode, int M,
    const unsigned short* __restrict__ Wt,
    const float* __restrict__ b0, const float* __restrict__ b1,
    const float* __restrict__ b2, const float* __restrict__ b3,
    unsigned short* __restrict__ q, unsigned short* __restrict__ kv,
    unsigned short* __restrict__ s)
{
    __shared__ float scale[128], shift[128];
    int r0 = blockIdx.x * 128;
    int tid = threadIdx.x;
    int wid = tid >> 6, lane = tid & 63;
    int wm = wid >> 1, wn = wid & 1;
    int lr = lane & 15, lk = lane >> 4;

    if (mode && tid < 128) {
        float invN = 1.0f / (float)M;
        float mu = stats[tid] * invN;
        float var = stats[512 + tid] * invN - mu * mu;
        float sc = rsqrtf(var + BN_EPS) * g[tid];
        scale[tid] = sc;
        shift[tid] = bb[tid] - mu * sc;
    }
    __syncthreads();

    // Load + BN a-frags once
    bf16x8 a[4][4];
    #pragma unroll
    for (int ks = 0; ks < 4; ++ks) {
        int ko = ks * 32 + lk * 8;
        #pragma unroll
        for (int mi = 0; mi < 4; ++mi) {
            int arow = r0 + wm * 64 + mi * 16 + lr;
            int4 t = {0, 0, 0, 0};
            if (arow < M) t = *(const int4*)(A + (size_t)arow * 128 + ko);
            if (mode) {
                float4 sc0 = *(const float4*)&scale[ko];
                float4 sc1 = *(const float4*)&scale[ko + 4];
                float4 sh0 = *(const float4*)&shift[ko];
                float4 sh1 = *(const float4*)&shift[ko + 4];
                float v0 = fmaxf(bfl(t.x) * sc0.x + sh0.x, 0.f);
                float v1 = fmaxf(bfh(t.x) * sc0.y + sh0.y, 0.f);
                float v2 = fmaxf(bfl(t.y) * sc0.z + sh0.z, 0.f);
                float v3 = fmaxf(bfh(t.y) * sc0.w + sh0.w, 0.f);
                float v4 = fmaxf(bfl(t.z) * sc1.x + sh1.x, 0.f);
                float v5 = fmaxf(bfh(t.z) * sc1.y + sh1.y, 0.f);
                float v6 = fmaxf(bfl(t.w) * sc1.z + sh1.z, 0.f);
                float v7 = fmaxf(bfh(t.w) * sc1.w + sh1.w, 0.f);
                t.x = (int)packbf(v0, v1); t.y = (int)packbf(v2, v3);
                t.z = (int)packbf(v4, v5); t.w = (int)packbf(v6, v7);
            }
            a[mi][ks] = __builtin_bit_cast(bf16x8, t);
        }
    }

    #pragma unroll
    for (int cc = 0; cc < 2; ++cc) {
        int ct = blockIdx.y * 2 + cc;
        const unsigned short* W = Wt + (size_t)ct * 16384;

        f32x4 acc[4][4] = {};
        #pragma unroll
        for (int ks = 0; ks < 4; ++ks) {
            int ko = ks * 32 + lk * 8;
            bf16x8 b[4];
            #pragma unroll
            for (int nj = 0; nj < 4; ++nj) {
                int4 t = *(const int4*)(W + (size_t)(wn * 64 + nj * 16 + lr) * 128 + ko);
                b[nj] = __builtin_bit_cast(bf16x8, t);
            }
            #pragma unroll
            for (int mi = 0; mi < 4; ++mi)
                #pragma unroll
                for (int nj = 0; nj < 4; ++nj)
                    acc[mi][nj] = __builtin_amdgcn_mfma_f32_16x16x32_bf16(
                        a[mi][ks], b[nj], acc[mi][nj], 0, 0, 0);
        }

        const float* bias = (ct == 0) ? b0 : (ct == 1) ? b1 : (ct == 2) ? b2 : b3;
        #pragma unroll
        for (int mi = 0; mi < 4; ++mi) {
            #pragma unroll
            for (int nj = 0; nj < 4; ++nj) {
                int col = wn * 64 + nj * 16 + lr;
                float bv = bias[col];
                #pragma unroll
                for (int reg = 0; reg < 4; ++reg) {
                    int rw = r0 + wm * 64 + mi * 16 + lk * 4 + reg;
                    if (rw < M) {
                        unsigned short val = f2bf(acc[mi][nj][reg] + bv);
                        if (ct == 0) q[(size_t)rw * 128 + col] = val;
                        else if (ct == 1) kv[(size_t)rw * 256 + col] = val;
                        else if (ct == 2) kv[(size_t)rw * 256 + 128 + col] = val;
                        else s[(size_t)rw * 128 + col] = val;
                    }
                }
            }
        }
    }
}

// Final: out[M x 64] = BNrelu(A) @ Wo + bo (f32), inline BN from raw stats; also
// accumulates output column stats (sum, sumsq) into statsOut for the final BN.
__global__ __launch_bounds__(256, 2) void gemm_final_kernel(
    const unsigned short* __restrict__ A,
    const float* __restrict__ stats, const float* __restrict__ g,
    const float* __restrict__ bb, int M,
    const unsigned short* __restrict__ Wot, const float* __restrict__ bias,
    float* __restrict__ out, float* __restrict__ statsOut)
{
    __shared__ float scale[128], shift[128];
    __shared__ float fs[64], fq[64];
    int r0 = blockIdx.x * 128;
    int tid = threadIdx.x;
    int wid = tid >> 6, lane = tid & 63;
    int wm = wid >> 1, wn = wid & 1;
    int lr = lane & 15, lk = lane >> 4;

    if (tid < 128) {
        float invN = 1.0f / (float)M;
        float mu = stats[tid] * invN;
        float var = stats[512 + tid] * invN - mu * mu;
        float sc = rsqrtf(var + BN_EPS) * g[tid];
        scale[tid] = sc;
        shift[tid] = bb[tid] - mu * sc;
    }
    if (tid < 64) { fs[tid] = 0.f; fq[tid] = 0.f; }
    __syncthreads();

    bf16x8 a[4][4];
    #pragma unroll
    for (int ks = 0; ks < 4; ++ks) {
        int ko = ks * 32 + lk * 8;
        #pragma unroll
        for (int mi = 0; mi < 4; ++mi) {
            int arow = r0 + wm * 64 + mi * 16 + lr;
            int4 t = {0, 0, 0, 0};
            if (arow < M) t = *(const int4*)(A + (size_t)arow * 128 + ko);
            float4 sc0 = *(const float4*)&scale[ko];
            float4 sc1 = *(const float4*)&scale[ko + 4];
            float4 sh0 = *(const float4*)&shift[ko];
            float4 sh1 = *(const float4*)&shift[ko + 4];
            float v0 = fmaxf(bfl(t.x) * sc0.x + sh0.x, 0.f);
            float v1 = fmaxf(bfh(t.x) * sc0.y + sh0.y, 0.f);
            float v2 = fmaxf(bfl(t.y) * sc0.z + sh0.z, 0.f);
            float v3 = fmaxf(bfh(t.y) * sc0.w + sh0.w, 0.f);
            float v4 = fmaxf(bfl(t.z) * sc1.x + sh1.x, 0.f);
            float v5 = fmaxf(bfh(t.z) * sc1.y + sh1.y, 0.f);
            float v6 = fmaxf(bfl(t.w) * sc1.z + sh1.z, 0.f);
            float v7 = fmaxf(bfh(t.w) * sc1.w + sh1.w, 0.f);
            t.x = (int)packbf(v0, v1); t.y = (int)packbf(v2, v3);
            t.z = (int)packbf(v4, v5); t.w = (int)packbf(v6, v7);
            a[mi][ks] = __builtin_bit_cast(bf16x8, t);
        }
    }

    f32x4 acc[4][2] = {};
    #pragma unroll
    for (int ks = 0; ks < 4; ++ks) {
        int ko = ks * 32 + lk * 8;
        bf16x8 b[2];
        #pragma unroll
        for (int nj = 0; nj < 2; ++nj) {
            int4 t = *(const int4*)(Wot + (size_t)(wn * 32 + nj * 16 + lr) * 128 + ko);
            b[nj] = __builtin_bit_cast(bf16x8, t);
        }
        #pragma unroll
        for (int mi = 0; mi < 4; ++mi)
            #pragma unroll
            for (int nj = 0; nj < 2; ++nj)
                acc[mi][nj] = __builtin_amdgcn_mfma_f32_16x16x32_bf16(
                    a[mi][ks], b[nj], acc[mi][nj], 0, 0, 0);
    }

    float csum[2] = {0.f, 0.f}, csq[2] = {0.f, 0.f};
    #pragma unroll
    for (int mi = 0; mi < 4; ++mi) {
        #pragma unroll
        for (int nj = 0; nj < 2; ++nj) {
            int col = wn * 32 + nj * 16 + lr;
            float bv = bias[col];
            #pragma unroll
            for (int reg = 0; reg < 4; ++reg) {
                int rw = r0 + wm * 64 + mi * 16 + lk * 4 + reg;
                if (rw < M) {
                    float val = acc[mi][nj][reg] + bv;
                    out[(size_t)rw * 64 + col] = val;
                    csum[nj] += val;
                    csq[nj] += val * val;
                }
            }
        }
    }
    // reduce across lanes sharing (wn, nj, lr): lanes lr, lr+16, lr+32, lr+48
    #pragma unroll
    for (int nj = 0; nj < 2; ++nj) {
        csum[nj] += __shfl_xor(csum[nj], 16);
        csum[nj] += __shfl_xor(csum[nj], 32);
        csq[nj]  += __shfl_xor(csq[nj], 16);
        csq[nj]  += __shfl_xor(csq[nj], 32);
    }
    if (lane < 16) {
        #pragma unroll
        for (int nj = 0; nj < 2; ++nj) {
            int col = wn * 32 + nj * 16 + lr;
            atomicAdd(&fs[col], csum[nj]);
            atomicAdd(&fq[col], csq[nj]);
        }
    }
    __syncthreads();
    if (tid < 64) atomicAdd(&statsOut[tid], fs[tid]);
    else if (tid < 128) atomicAdd(&statsOut[512 + tid - 64], fq[tid - 64]);
}

// ---------------- Fused attention: 4 nodes/wave, unroll 8, bf16 out + fused BN stats ----------------

__global__ __launch_bounds__(256) void attn_kernel(
    const unsigned short* __restrict__ q, const unsigned short* __restrict__ kv,
    const unsigned short* __restrict__ sk,
    const int* __restrict__ rowptr, const int* __restrict__ csrsrc,
    const int* __restrict__ order,
    unsigned short* __restrict__ hnext, float* __restrict__ stats, int N)
{
    __shared__ float ls[128], lq2[128];
    int tid = threadIdx.x;
    if (tid < 128) { ls[tid] = 0.f; lq2[tid] = 0.f; }
    __syncthreads();

    int wave = (blockIdx.x * blockDim.x + tid) >> 6;
    int lane = tid & 63;
    int gl = lane & 15;
    int slot = wave * 4 + (lane >> 4);
    bool nv = slot < N;
    int n = nv ? order[slot] : 0;

    int r0 = rowptr[n], r1 = rowptr[n + 1];
    int deg = nv ? (r1 - r0) : 0;
    int dmax = deg;
    dmax = max(dmax, __shfl_xor(dmax, 16));
    dmax = max(dmax, __shfl_xor(dmax, 32));

    int4 qu = *(const int4*)(q + (size_t)n * 128 + gl * 8);
    float qf[8];
    qf[0] = bfl(qu.x); qf[1] = bfh(qu.x); qf[2] = bfl(qu.y); qf[3] = bfh(qu.y);
    qf[4] = bfl(qu.z); qf[5] = bfh(qu.z); qf[6] = bfl(qu.w); qf[7] = bfh(qu.w);

    float m = -INFINITY, ssum = 0.f;
    float acc[8] = {};

    for (int i = 0; i < dmax; i += 8) {
        int eidx[8];
        bool av[8];
        #pragma unroll
        for (int j = 0; j < 8; ++j) {
            av[j] = (i + j) < deg;
            int e = csrsrc[r0 + i + j];   // csrsrc padded; OOB masked below
            eidx[j] = av[j] ? e : 0;
        }
        int4 K[8], V[8];
        #pragma unroll
        for (int j = 0; j < 8; ++j) {
            const unsigned short* row = kv + (size_t)eidx[j] * 256 + gl * 8;
            K[j] = *(const int4*)(row);
            V[j] = *(const int4*)(row + 128);
        }
        float sc[8];
        #pragma unroll
        for (int j = 0; j < 8; ++j) {
            float p = qf[0] * bfl(K[j].x) + qf[1] * bfh(K[j].x)
                    + qf[2] * bfl(K[j].y) + qf[3] * bfh(K[j].y)
                    + qf[4] * bfl(K[j].z) + qf[5] * bfh(K[j].z)
                    + qf[6] * bfl(K[j].w) + qf[7] * bfh(K[j].w);
            p += __shfl_xor(p, 1);
            p += __shfl_xor(p, 2);
            sc[j] = av[j] ? p * INV_SQRT_C : -INFINITY;
        }
        float mn = m;
        #pragma unroll
        for (int j = 0; j < 8; ++j) mn = fmaxf(mn, sc[j]);
        if (mn > m) {
            float scale = __expf(m - mn);
            ssum *= scale;
            #pragma unroll
            for (int c = 0; c < 8; ++c) acc[c] *= scale;
            m = mn;
        }
        #pragma unroll
        for (int j = 0; j < 8; ++j) {
            float ej = av[j] ? __expf(sc[j] - m) : 0.f;
            ssum += ej;
            acc[0] += ej * bfl(V[j].x); acc[1] += ej * bfh(V[j].x);
            acc[2] += ej * bfl(V[j].y); acc[3] += ej * bfh(V[j].y);
            acc[4] += ej * bfl(V[j].z); acc[5] += ej * bfh(V[j].z);
            acc[6] += ej * bfl(V[j].w); acc[7] += ej * bfh(V[j].w);
        }
    }

    float o[8];
    if (nv) {
        float inv = (ssum > 0.f) ? 1.0f / ssum : 0.f;
        int4 su = *(const int4*)(sk + (size_t)n * 128 + gl * 8);
        o[0] = acc[0] * inv + bfl(su.x); o[1] = acc[1] * inv + bfh(su.x);
        o[2] = acc[2] * inv + bfl(su.y); o[3] = acc[3] * inv + bfh(su.y);
        o[4] = acc[4] * inv + bfl(su.z); o[5] = acc[5] * inv + bfh(su.z);
        o[6] = acc[6] * inv + bfl(su.w); o[7] = acc[7] * inv + bfh(su.w);
        int4 st;
        st.x = (int)packbf(o[0], o[1]); st.y = (int)packbf(o[2], o[3]);
        st.z = (int)packbf(o[4], o[5]); st.w = (int)packbf(o[6], o[7]);
        *(int4*)(hnext + (size_t)n * 128 + gl * 8) = st;
    } else {
        #pragma unroll
        for (int c = 0; c < 8; ++c) o[c] = 0.f;
    }

    // fused BN stats: reduce across the 4 node-slots per wave, then LDS, then global
    float s8[8], q8[8];
    #pragma unroll
    for (int c = 0; c < 8; ++c) { s8[c] = o[c]; q8[c] = o[c] * o[c]; }
    #pragma unroll
    for (int c = 0; c < 8; ++c) {
        s8[c] += __shfl_xor(s8[c], 16); s8[c] += __shfl_xor(s8[c], 32);
        q8[c] += __shfl_xor(q8[c], 16); q8[c] += __shfl_xor(q8[c], 32);
    }
    if (lane < 16) {
        #pragma unroll
        for (int c = 0; c < 8; ++c) {
            atomicAdd(&ls[gl * 8 + c], s8[c]);
            atomicAdd(&lq2[gl * 8 + c], q8[c]);
        }
    }
    __syncthreads();
    if (tid < 128) atomicAdd(&stats[tid], ls[tid]);
    else atomicAdd(&stats[512 + tid - 128], lq2[tid - 128]);
}

// ---------------- final BN apply ----------------

__global__ __launch_bounds__(256) void bn_apply_f32_kernel(
    const float* __restrict__ x, float* __restrict__ y,
    const float* __restrict__ stats, const float* __restrict__ g,
    const float* __restrict__ b, int N, int F)
{
    __shared__ float scale[128], shift[128];
    int tid = threadIdx.x;
    if (tid < F) {
        float invN = 1.0f / (float)N;
        float mu = stats[tid] * invN;
        float var = stats[512 + tid] * invN - mu * mu;
        float sc = rsqrtf(var + BN_EPS) * g[tid];
        scale[tid] = sc;
        shift[tid] = b[tid] - mu * sc;
    }
    __syncthreads();
    size_t total4 = (size_t)N * F >> 2;
    int Fm = F - 1;
    for (size_t t = (size_t)blockIdx.x * blockDim.x + tid; t < total4;
         t += (size_t)gridDim.x * blockDim.x) {
        size_t i = t * 4;
        int f = (int)(i & (size_t)Fm);
        float4 v = *(const float4*)(x + i);
        float4 o;
        o.x = fmaxf(v.x * scale[f + 0] + shift[f + 0], 0.f);
        o.y = fmaxf(v.y * scale[f + 1] + shift[f + 1], 0.f);
        o.z = fmaxf(v.z * scale[f + 2] + shift[f + 2], 0.f);
        o.w = fmaxf(v.w * scale[f + 3] + shift[f + 3], 0.f);
        *(float4*)(y + i) = o;
    }
}

// ---------------- launch ----------------

static inline size_t al16(size_t x) { return (x + 15) & ~(size_t)15; }

extern "C" void kernel_launch(void* const* d_in, const int* in_sizes, int n_in,
                              void* d_out, int out_size, void* d_ws, size_t ws_size,
                              hipStream_t stream) {
    const float* x    = (const float*)d_in[0];
    const int*   edge = (const int*)d_in[1];
    const float* Wq   = (const float*)d_in[2];
    const float* bq   = (const float*)d_in[3];
    const float* Wk   = (const float*)d_in[4];
    const float* bk   = (const float*)d_in[5];
    const float* Wv   = (const float*)d_in[6];
    const float* bv   = (const float*)d_in[7];
    const float* Wsk  = (const float*)d_in[8];
    const float* bsk  = (const float*)d_in[9];
    const float* bng  = (const float*)d_in[10];
    const float* bnb  = (const float*)d_in[11];
    const float* Wo   = (const float*)d_in[12];
    const float* bo   = (const float*)d_in[13];
    const float* bnog = (const float*)d_in[14];
    const float* bnob = (const float*)d_in[15];

    const int N = in_sizes[0] / D_FEAT;
    const int E = in_sizes[1] / 2;
    const int* esrc = edge;
    const int* edst = edge + E;

    const int SB = (N + SORT_NPB - 1) / SORT_NPB;

    char* wsb = (char*)d_ws;
    unsigned short* xb = (unsigned short*)wsb; wsb += al16((size_t)N * 128 * 2);
    unsigned short* kv = (unsigned short*)wsb; wsb += al16((size_t)N * 256 * 2);
    unsigned short* q  = (unsigned short*)wsb; wsb += al16((size_t)N * 128 * 2);
    unsigned short* s  = (unsigned short*)wsb; wsb += al16((size_t)N * 128 * 2);
    unsigned short* hnext = (unsigned short*)wsb; wsb += al16((size_t)N * 128 * 2);
    float* outpre = (float*)wsb; wsb += al16((size_t)N * 64 * 4);
    unsigned short* Wt  = (unsigned short*)wsb; wsb += al16((size_t)NLAYER * 4 * 16384 * 2);
    unsigned short* Wot = (unsigned short*)wsb; wsb += al16((size_t)64 * 128 * 2);
    float* stats  = (float*)wsb; wsb += al16(4096 * 4);   // 4 regions of 1024
    int* rowptr   = (int*)wsb;   wsb += al16((size_t)(N + 1) * 4);
    int* deg      = (int*)wsb;   wsb += al16((size_t)N * 4);
    int* csrsrc   = (int*)wsb;   wsb += al16((size_t)(E + 64) * 4);  // +pad for unroll-8 overread
    int* partials = (int*)wsb;   wsb += al16(256 * 4);
    int* bhist    = (int*)wsb;   wsb += al16((size_t)256 * SB * 4);
    int* binoff   = (int*)wsb;   wsb += al16(256 * 4);
    int* order    = (int*)wsb;   wsb += al16((size_t)N * 4);

    cvt_bf16_kernel<<<2048, 256, 0, stream>>>(x, xb, (size_t)N * 128 / 4);
    prep_weights_kernel<<<256, 256, 0, stream>>>(Wq, Wk, Wv, Wsk, Wo, Wt, Wot);
    hipMemsetAsync(stats, 0, 4096 * 4, stream);

    // CSR build
    const int nb1 = (N + 1023) / 1024;
    hipMemsetAsync(deg, 0, (size_t)N * 4, stream);
    hist_kernel<<<(E + 255) / 256, 256, 0, stream>>>(edst, E, deg);
    scan1_kernel<<<nb1, 256, 0, stream>>>(deg, N, rowptr, partials);
    scan2_kernel<<<1, 64, 0, stream>>>(partials, nb1);
    scan3_kernel<<<nb1, 256, 0, stream>>>(rowptr, N, partials);
    hipMemsetAsync(deg, 0, (size_t)N * 4, stream);
    scatter_kernel<<<(E + 255) / 256, 256, 0, stream>>>(esrc, edst, E, rowptr, deg, csrsrc);

    // degree-binned node order (descending)
    bin_blockhist_kernel<<<SB, 256, 0, stream>>>(rowptr, N, SB, bhist);
    bin_colscan_kernel<<<1, 256, 0, stream>>>(bhist, SB, binoff);
    bin_order_kernel<<<SB, 256, 0, stream>>>(rowptr, N, SB, bhist, binoff, order);

    const int gemm_rb = (N + 127) / 128;
    const int attn_blocks = (N + 15) / 16;
    const unsigned short* hin = xb;
    for (int l = 0; l < NLAYER; ++l) {
        const float* statsIn = (l == 0) ? (const float*)nullptr : stats + (l - 1) * 1024;
        const float* gIn = (l == 0) ? (const float*)nullptr : bng + (l - 1) * 128;
        const float* bIn = (l == 0) ? (const float*)nullptr : bnb + (l - 1) * 128;
        gemm_qkvs_kernel<<<dim3(gemm_rb, 2), 256, 0, stream>>>(
            hin, statsIn, gIn, bIn, (l == 0) ? 0 : 1, N,
            Wt + (size_t)l * 4 * 16384,
            bq + l * 128, bk + l * 128, bv + l * 128, bsk + l * 128,
            q, kv, s);
        attn_kernel<<<attn_blocks, 256, 0, stream>>>(q, kv, s, rowptr, csrsrc, order,
                                                     hnext, stats + l * 1024, N);
        hin = hnext;
    }

    gemm_final_kernel<<<gemm_rb, 256, 0, stream>>>(
        hnext, stats + 2 * 1024, bng + 2 * 128, bnb + 2 * 128, N,
        Wot, bo, outpre, stats + 3 * 1024);
    bn_apply_f32_kernel<<<2048, 256, 0, stream>>>(outpre, (float*)d_out, stats + 3 * 1024,
                                                  bnog, bnob, N, 64);
}

// Round 10
// 491.453 us; speedup vs baseline: 1.5523x; 1.2351x over previous
//
#include <hip/hip_runtime.h>
#include <hip/hip_bf16.h>
#include <math.h>

#define D_FEAT 128
#define NLAYER 3
#define BN_EPS 1e-5f
#define INV_SQRT_C 0.17677669529663687f  // 1/sqrt(32)
#define SORT_NPB 1024                    // nodes per sort block
#define NREP 8                           // stats replicas (atomic decontention)

typedef __bf16 bf16x8 __attribute__((ext_vector_type(8)));
typedef float f32x4 __attribute__((ext_vector_type(4)));

static __device__ __forceinline__ unsigned short f2bf(float f) {
    return __builtin_bit_cast(unsigned short, __float2bfloat16(f));
}
static __device__ __forceinline__ float bfl(unsigned u) { return __uint_as_float(u << 16); }
static __device__ __forceinline__ float bfh(unsigned u) { return __uint_as_float(u & 0xffff0000u); }
static __device__ __forceinline__ unsigned packbf(float a, float b) {
    return (unsigned)f2bf(a) | ((unsigned)f2bf(b) << 16);
}

// ---------------- conversions ----------------

__global__ void cvt_bf16_kernel(const float* __restrict__ src, unsigned short* __restrict__ dst,
                                size_t n4) {
    for (size_t t = (size_t)blockIdx.x * blockDim.x + threadIdx.x; t < n4;
         t += (size_t)gridDim.x * blockDim.x) {
        size_t i = t * 4;
        float4 v = *(const float4*)(src + i);
        ushort4 u;
        u.x = f2bf(v.x); u.y = f2bf(v.y); u.z = f2bf(v.z); u.w = f2bf(v.w);
        *(ushort4*)(dst + i) = u;
    }
}

__global__ void prep_weights_kernel(
    const float* __restrict__ Wq, const float* __restrict__ Wk,
    const float* __restrict__ Wv, const float* __restrict__ Ws,
    const float* __restrict__ Wo,
    unsigned short* __restrict__ Wt, unsigned short* __restrict__ Wot)
{
    const int permat = 16384;
    const int main_total = NLAYER * 4 * permat;
    const int total = main_total + 64 * 128;
    for (int i = blockIdx.x * blockDim.x + threadIdx.x; i < total;
         i += gridDim.x * blockDim.x) {
        if (i < main_total) {
            int l = i / (4 * permat);
            int rem = i - l * (4 * permat);
            int mat = rem / permat;
            int e = rem - mat * permat;
            int nn = e >> 7;
            int kk = e & 127;
            const float* src = (mat == 0) ? Wq : (mat == 1) ? Wk : (mat == 2) ? Wv : Ws;
            Wt[(size_t)l * 4 * permat + mat * permat + nn * 128 + kk] =
                f2bf(src[(size_t)l * permat + kk * 128 + nn]);
        } else {
            int e = i - main_total;
            int nn = e >> 7;
            int kk = e & 127;
            Wot[nn * 128 + kk] = f2bf(Wo[kk * 64 + nn]);
        }
    }
}

// ---------------- CSR build ----------------

__global__ void hist_kernel(const int* __restrict__ dst, int E, int* __restrict__ deg) {
    int e = blockIdx.x * blockDim.x + threadIdx.x;
    if (e < E) atomicAdd(&deg[dst[e]], 1);
}

__global__ __launch_bounds__(256) void scan1_kernel(const int* __restrict__ deg, int n,
                                                    int* __restrict__ rowptr,
                                                    int* __restrict__ partials) {
    int b = blockIdx.x, tid = threadIdx.x;
    int base = b * 1024 + tid * 4;
    int4 d = {0, 0, 0, 0};
    if (base + 3 < n) d = *(const int4*)(deg + base);
    else {
        if (base + 0 < n) d.x = deg[base + 0];
        if (base + 1 < n) d.y = deg[base + 1];
        if (base + 2 < n) d.z = deg[base + 2];
        if (base + 3 < n) d.w = deg[base + 3];
    }
    int p0 = d.x, p1 = p0 + d.y, p2 = p1 + d.z, p3 = p2 + d.w;
    int v = p3;
    int lane = tid & 63;
    #pragma unroll
    for (int off = 1; off < 64; off <<= 1) {
        int t = __shfl_up(v, off);
        if (lane >= off) v += t;
    }
    __shared__ int wsum[4];
    int w = tid >> 6;
    if (lane == 63) wsum[w] = v;
    __syncthreads();
    int woff = 0;
    #pragma unroll
    for (int j = 0; j < 4; ++j) if (j < w) woff += wsum[j];
    int excl = woff + v - p3;
    if (base + 0 < n) rowptr[base + 1] = excl + p0;
    if (base + 1 < n) rowptr[base + 2] = excl + p1;
    if (base + 2 < n) rowptr[base + 3] = excl + p2;
    if (base + 3 < n) rowptr[base + 4] = excl + p3;
    if (tid == 255) partials[b] = excl + p3;
    if (b == 0 && tid == 0) rowptr[0] = 0;
}

__global__ void scan2_kernel(int* __restrict__ partials, int nb) {
    int lane = threadIdx.x;
    int v = (lane < nb) ? partials[lane] : 0;
    #pragma unroll
    for (int off = 1; off < 64; off <<= 1) {
        int t = __shfl_up(v, off);
        if (lane >= off) v += t;
    }
    if (lane < nb) partials[lane] = v;  // inclusive
}

__global__ __launch_bounds__(256) void scan3_kernel(int* __restrict__ rowptr, int n,
                                                    const int* __restrict__ partials) {
    int b = blockIdx.x, tid = threadIdx.x;
    if (b == 0) return;
    int off = partials[b - 1];
    int base = b * 1024 + tid * 4;
    #pragma unroll
    for (int j = 0; j < 4; ++j) {
        int i = base + j;
        if (i < n) rowptr[i + 1] += off;
    }
}

__global__ void scatter_kernel(const int* __restrict__ src, const int* __restrict__ dst, int E,
                               const int* __restrict__ rowptr, int* __restrict__ cursor,
                               int* __restrict__ csrsrc) {
    int e = blockIdx.x * blockDim.x + threadIdx.x;
    if (e < E) {
        int d = dst[e];
        int p = atomicAdd(&cursor[d], 1);
        csrsrc[rowptr[d] + p] = src[e];
    }
}

// ---------------- degree binning: contention-free counting sort (DESCENDING) ----------------

__global__ __launch_bounds__(256) void bin_blockhist_kernel(
    const int* __restrict__ rowptr, int n, int B, int* __restrict__ bhist)
{
    __shared__ int h[256];
    int b = blockIdx.x, tid = threadIdx.x;
    h[tid] = 0;
    __syncthreads();
    #pragma unroll
    for (int j = 0; j < SORT_NPB / 256; ++j) {
        int i = b * SORT_NPB + j * 256 + tid;
        if (i < n) {
            int d = rowptr[i + 1] - rowptr[i];
            if (d > 255) d = 255;
            atomicAdd(&h[255 - d], 1);   // descending: big degrees -> low bins
        }
    }
    __syncthreads();
    bhist[tid * B + b] = h[tid];
}

__global__ __launch_bounds__(256) void bin_colscan_kernel(
    int* __restrict__ bhist, int B, int* __restrict__ binoff)
{
    int d = threadIdx.x;
    int run = 0;
    for (int b = 0; b < B; ++b) {
        int c = bhist[d * B + b];
        bhist[d * B + b] = run;
        run += c;
    }
    __shared__ int sd[256];
    sd[d] = run;
    __syncthreads();
    int v = run;
    for (int s = 1; s < 256; s <<= 1) {
        int t = (d >= s) ? sd[d - s] : 0;
        __syncthreads();
        sd[d] += t;
        __syncthreads();
    }
    binoff[d] = sd[d] - v;  // exclusive
}

__global__ __launch_bounds__(256) void bin_order_kernel(
    const int* __restrict__ rowptr, int n, int B,
    const int* __restrict__ bhist, const int* __restrict__ binoff,
    int* __restrict__ order)
{
    __shared__ int cur[256];
    int b = blockIdx.x, tid = threadIdx.x;
    cur[tid] = binoff[tid] + bhist[tid * B + b];
    __syncthreads();
    #pragma unroll
    for (int j = 0; j < SORT_NPB / 256; ++j) {
        int i = b * SORT_NPB + j * 256 + tid;
        if (i < n) {
            int d = rowptr[i + 1] - rowptr[i];
            if (d > 255) d = 255;
            int pos = atomicAdd(&cur[255 - d], 1);
            order[pos] = i;
        }
    }
}

// ---------------- LDS-free direct-register MFMA GEMM, ct-pairs, inline BN ----------------
// stats: NREP replicas of {sum[128], pad, sumsq at +512}; consumer sums replicas.

__global__ __launch_bounds__(256, 2) void gemm_qkvs_kernel(
    const unsigned short* __restrict__ A,
    const float* __restrict__ stats, const float* __restrict__ g,
    const float* __restrict__ bb, int mode, int M,
    const unsigned short* __restrict__ Wt,
    const float* __restrict__ b0, const float* __restrict__ b1,
    const float* __restrict__ b2, const float* __restrict__ b3,
    unsigned short* __restrict__ q, unsigned short* __restrict__ kv,
    unsigned short* __restrict__ s)
{
    __shared__ float scale[128], shift[128];
    int r0 = blockIdx.x * 128;
    int tid = threadIdx.x;
    int wid = tid >> 6, lane = tid & 63;
    int wm = wid >> 1, wn = wid & 1;
    int lr = lane & 15, lk = lane >> 4;

    if (mode && tid < 128) {
        float ssum = 0.f, qsum = 0.f;
        #pragma unroll
        for (int r = 0; r < NREP; ++r) {
            ssum += stats[r * 1024 + tid];
            qsum += stats[r * 1024 + 512 + tid];
        }
        float invN = 1.0f / (float)M;
        float mu = ssum * invN;
        float var = qsum * invN - mu * mu;
        float sc = rsqrtf(var + BN_EPS) * g[tid];
        scale[tid] = sc;
        shift[tid] = bb[tid] - mu * sc;
    }
    __syncthreads();

    // Load + BN a-frags once
    bf16x8 a[4][4];
    #pragma unroll
    for (int ks = 0; ks < 4; ++ks) {
        int ko = ks * 32 + lk * 8;
        #pragma unroll
        for (int mi = 0; mi < 4; ++mi) {
            int arow = r0 + wm * 64 + mi * 16 + lr;
            int4 t = {0, 0, 0, 0};
            if (arow < M) t = *(const int4*)(A + (size_t)arow * 128 + ko);
            if (mode) {
                float4 sc0 = *(const float4*)&scale[ko];
                float4 sc1 = *(const float4*)&scale[ko + 4];
                float4 sh0 = *(const float4*)&shift[ko];
                float4 sh1 = *(const float4*)&shift[ko + 4];
                float v0 = fmaxf(bfl(t.x) * sc0.x + sh0.x, 0.f);
                float v1 = fmaxf(bfh(t.x) * sc0.y + sh0.y, 0.f);
                float v2 = fmaxf(bfl(t.y) * sc0.z + sh0.z, 0.f);
                float v3 = fmaxf(bfh(t.y) * sc0.w + sh0.w, 0.f);
                float v4 = fmaxf(bfl(t.z) * sc1.x + sh1.x, 0.f);
                float v5 = fmaxf(bfh(t.z) * sc1.y + sh1.y, 0.f);
                float v6 = fmaxf(bfl(t.w) * sc1.z + sh1.z, 0.f);
                float v7 = fmaxf(bfh(t.w) * sc1.w + sh1.w, 0.f);
                t.x = (int)packbf(v0, v1); t.y = (int)packbf(v2, v3);
                t.z = (int)packbf(v4, v5); t.w = (int)packbf(v6, v7);
            }
            a[mi][ks] = __builtin_bit_cast(bf16x8, t);
        }
    }

    #pragma unroll
    for (int cc = 0; cc < 2; ++cc) {
        int ct = blockIdx.y * 2 + cc;
        const unsigned short* W = Wt + (size_t)ct * 16384;

        f32x4 acc[4][4] = {};
        #pragma unroll
        for (int ks = 0; ks < 4; ++ks) {
            int ko = ks * 32 + lk * 8;
            bf16x8 b[4];
            #pragma unroll
            for (int nj = 0; nj < 4; ++nj) {
                int4 t = *(const int4*)(W + (size_t)(wn * 64 + nj * 16 + lr) * 128 + ko);
                b[nj] = __builtin_bit_cast(bf16x8, t);
            }
            #pragma unroll
            for (int mi = 0; mi < 4; ++mi)
                #pragma unroll
                for (int nj = 0; nj < 4; ++nj)
                    acc[mi][nj] = __builtin_amdgcn_mfma_f32_16x16x32_bf16(
                        a[mi][ks], b[nj], acc[mi][nj], 0, 0, 0);
        }

        const float* bias = (ct == 0) ? b0 : (ct == 1) ? b1 : (ct == 2) ? b2 : b3;
        #pragma unroll
        for (int mi = 0; mi < 4; ++mi) {
            #pragma unroll
            for (int nj = 0; nj < 4; ++nj) {
                int col = wn * 64 + nj * 16 + lr;
                float bv = bias[col];
                #pragma unroll
                for (int reg = 0; reg < 4; ++reg) {
                    int rw = r0 + wm * 64 + mi * 16 + lk * 4 + reg;
                    if (rw < M) {
                        unsigned short val = f2bf(acc[mi][nj][reg] + bv);
                        if (ct == 0) q[(size_t)rw * 128 + col] = val;
                        else if (ct == 1) kv[(size_t)rw * 256 + col] = val;
                        else if (ct == 2) kv[(size_t)rw * 256 + 128 + col] = val;
                        else s[(size_t)rw * 128 + col] = val;
                    }
                }
            }
        }
    }
}

// Final: out[M x 64] = BNrelu(A) @ Wo + bo (f32), inline BN from replicated raw stats;
// accumulates output column stats into statsOut (single region, few blocks).
__global__ __launch_bounds__(256, 2) void gemm_final_kernel(
    const unsigned short* __restrict__ A,
    const float* __restrict__ stats, const float* __restrict__ g,
    const float* __restrict__ bb, int M,
    const unsigned short* __restrict__ Wot, const float* __restrict__ bias,
    float* __restrict__ out, float* __restrict__ statsOut)
{
    __shared__ float scale[128], shift[128];
    __shared__ float fs[64], fq[64];
    int r0 = blockIdx.x * 128;
    int tid = threadIdx.x;
    int wid = tid >> 6, lane = tid & 63;
    int wm = wid >> 1, wn = wid & 1;
    int lr = lane & 15, lk = lane >> 4;

    if (tid < 128) {
        float ssum = 0.f, qsum = 0.f;
        #pragma unroll
        for (int r = 0; r < NREP; ++r) {
            ssum += stats[r * 1024 + tid];
            qsum += stats[r * 1024 + 512 + tid];
        }
        float invN = 1.0f / (float)M;
        float mu = ssum * invN;
        float var = qsum * invN - mu * mu;
        float sc = rsqrtf(var + BN_EPS) * g[tid];
        scale[tid] = sc;
        shift[tid] = bb[tid] - mu * sc;
    }
    if (tid < 64) { fs[tid] = 0.f; fq[tid] = 0.f; }
    __syncthreads();

    bf16x8 a[4][4];
    #pragma unroll
    for (int ks = 0; ks < 4; ++ks) {
        int ko = ks * 32 + lk * 8;
        #pragma unroll
        for (int mi = 0; mi < 4; ++mi) {
            int arow = r0 + wm * 64 + mi * 16 + lr;
            int4 t = {0, 0, 0, 0};
            if (arow < M) t = *(const int4*)(A + (size_t)arow * 128 + ko);
            float4 sc0 = *(const float4*)&scale[ko];
            float4 sc1 = *(const float4*)&scale[ko + 4];
            float4 sh0 = *(const float4*)&shift[ko];
            float4 sh1 = *(const float4*)&shift[ko + 4];
            float v0 = fmaxf(bfl(t.x) * sc0.x + sh0.x, 0.f);
            float v1 = fmaxf(bfh(t.x) * sc0.y + sh0.y, 0.f);
            float v2 = fmaxf(bfl(t.y) * sc0.z + sh0.z, 0.f);
            float v3 = fmaxf(bfh(t.y) * sc0.w + sh0.w, 0.f);
            float v4 = fmaxf(bfl(t.z) * sc1.x + sh1.x, 0.f);
            float v5 = fmaxf(bfh(t.z) * sc1.y + sh1.y, 0.f);
            float v6 = fmaxf(bfl(t.w) * sc1.z + sh1.z, 0.f);
            float v7 = fmaxf(bfh(t.w) * sc1.w + sh1.w, 0.f);
            t.x = (int)packbf(v0, v1); t.y = (int)packbf(v2, v3);
            t.z = (int)packbf(v4, v5); t.w = (int)packbf(v6, v7);
            a[mi][ks] = __builtin_bit_cast(bf16x8, t);
        }
    }

    f32x4 acc[4][2] = {};
    #pragma unroll
    for (int ks = 0; ks < 4; ++ks) {
        int ko = ks * 32 + lk * 8;
        bf16x8 b[2];
        #pragma unroll
        for (int nj = 0; nj < 2; ++nj) {
            int4 t = *(const int4*)(Wot + (size_t)(wn * 32 + nj * 16 + lr) * 128 + ko);
            b[nj] = __builtin_bit_cast(bf16x8, t);
        }
        #pragma unroll
        for (int mi = 0; mi < 4; ++mi)
            #pragma unroll
            for (int nj = 0; nj < 2; ++nj)
                acc[mi][nj] = __builtin_amdgcn_mfma_f32_16x16x32_bf16(
                    a[mi][ks], b[nj], acc[mi][nj], 0, 0, 0);
    }

    float csum[2] = {0.f, 0.f}, csq[2] = {0.f, 0.f};
    #pragma unroll
    for (int mi = 0; mi < 4; ++mi) {
        #pragma unroll
        for (int nj = 0; nj < 2; ++nj) {
            int col = wn * 32 + nj * 16 + lr;
            float bv = bias[col];
            #pragma unroll
            for (int reg = 0; reg < 4; ++reg) {
                int rw = r0 + wm * 64 + mi * 16 + lk * 4 + reg;
                if (rw < M) {
                    float val = acc[mi][nj][reg] + bv;
                    out[(size_t)rw * 64 + col] = val;
                    csum[nj] += val;
                    csq[nj] += val * val;
                }
            }
        }
    }
    #pragma unroll
    for (int nj = 0; nj < 2; ++nj) {
        csum[nj] += __shfl_xor(csum[nj], 16);
        csum[nj] += __shfl_xor(csum[nj], 32);
        csq[nj]  += __shfl_xor(csq[nj], 16);
        csq[nj]  += __shfl_xor(csq[nj], 32);
    }
    if (lane < 16) {
        #pragma unroll
        for (int nj = 0; nj < 2; ++nj) {
            int col = wn * 32 + nj * 16 + lr;
            atomicAdd(&fs[col], csum[nj]);
            atomicAdd(&fq[col], csq[nj]);
        }
    }
    __syncthreads();
    if (tid < 64) atomicAdd(&statsOut[tid], fs[tid]);
    else if (tid < 128) atomicAdd(&statsOut[512 + tid - 64], fq[tid - 64]);
}

// ---------------- Fused attention: 4 nodes/wave, unroll 8, bf16 out + replicated BN stats ----------------

__global__ __launch_bounds__(256) void attn_kernel(
    const unsigned short* __restrict__ q, const unsigned short* __restrict__ kv,
    const unsigned short* __restrict__ sk,
    const int* __restrict__ rowptr, const int* __restrict__ csrsrc,
    const int* __restrict__ order,
    unsigned short* __restrict__ hnext, float* __restrict__ stats, int N)
{
    __shared__ float ls[128], lq2[128];
    int tid = threadIdx.x;
    if (tid < 128) { ls[tid] = 0.f; lq2[tid] = 0.f; }
    __syncthreads();

    int wave = (blockIdx.x * blockDim.x + tid) >> 6;
    int lane = tid & 63;
    int gl = lane & 15;
    int slot = wave * 4 + (lane >> 4);
    bool nv = slot < N;
    int n = nv ? order[slot] : 0;

    int r0 = rowptr[n], r1 = rowptr[n + 1];
    int deg = nv ? (r1 - r0) : 0;
    int dmax = deg;
    dmax = max(dmax, __shfl_xor(dmax, 16));
    dmax = max(dmax, __shfl_xor(dmax, 32));

    int4 qu = *(const int4*)(q + (size_t)n * 128 + gl * 8);
    float qf[8];
    qf[0] = bfl(qu.x); qf[1] = bfh(qu.x); qf[2] = bfl(qu.y); qf[3] = bfh(qu.y);
    qf[4] = bfl(qu.z); qf[5] = bfh(qu.z); qf[6] = bfl(qu.w); qf[7] = bfh(qu.w);

    float m = -INFINITY, ssum = 0.f;
    float acc[8] = {};

    for (int i = 0; i < dmax; i += 8) {
        int eidx[8];
        bool av[8];
        #pragma unroll
        for (int j = 0; j < 8; ++j) {
            av[j] = (i + j) < deg;
            int e = csrsrc[r0 + i + j];   // csrsrc padded; OOB masked below
            eidx[j] = av[j] ? e : 0;
        }
        int4 K[8], V[8];
        #pragma unroll
        for (int j = 0; j < 8; ++j) {
            const unsigned short* row = kv + (size_t)eidx[j] * 256 + gl * 8;
            K[j] = *(const int4*)(row);
            V[j] = *(const int4*)(row + 128);
        }
        float sc[8];
        #pragma unroll
        for (int j = 0; j < 8; ++j) {
            float p = qf[0] * bfl(K[j].x) + qf[1] * bfh(K[j].x)
                    + qf[2] * bfl(K[j].y) + qf[3] * bfh(K[j].y)
                    + qf[4] * bfl(K[j].z) + qf[5] * bfh(K[j].z)
                    + qf[6] * bfl(K[j].w) + qf[7] * bfh(K[j].w);
            p += __shfl_xor(p, 1);
            p += __shfl_xor(p, 2);
            sc[j] = av[j] ? p * INV_SQRT_C : -INFINITY;
        }
        float mn = m;
        #pragma unroll
        for (int j = 0; j < 8; ++j) mn = fmaxf(mn, sc[j]);
        if (mn > m) {
            float scale = __expf(m - mn);
            ssum *= scale;
            #pragma unroll
            for (int c = 0; c < 8; ++c) acc[c] *= scale;
            m = mn;
        }
        #pragma unroll
        for (int j = 0; j < 8; ++j) {
            float ej = av[j] ? __expf(sc[j] - m) : 0.f;
            ssum += ej;
            acc[0] += ej * bfl(V[j].x); acc[1] += ej * bfh(V[j].x);
            acc[2] += ej * bfl(V[j].y); acc[3] += ej * bfh(V[j].y);
            acc[4] += ej * bfl(V[j].z); acc[5] += ej * bfh(V[j].z);
            acc[6] += ej * bfl(V[j].w); acc[7] += ej * bfh(V[j].w);
        }
    }

    float o[8];
    if (nv) {
        float inv = (ssum > 0.f) ? 1.0f / ssum : 0.f;
        int4 su = *(const int4*)(sk + (size_t)n * 128 + gl * 8);
        o[0] = acc[0] * inv + bfl(su.x); o[1] = acc[1] * inv + bfh(su.x);
        o[2] = acc[2] * inv + bfl(su.y); o[3] = acc[3] * inv + bfh(su.y);
        o[4] = acc[4] * inv + bfl(su.z); o[5] = acc[5] * inv + bfh(su.z);
        o[6] = acc[6] * inv + bfl(su.w); o[7] = acc[7] * inv + bfh(su.w);
        int4 st;
        st.x = (int)packbf(o[0], o[1]); st.y = (int)packbf(o[2], o[3]);
        st.z = (int)packbf(o[4], o[5]); st.w = (int)packbf(o[6], o[7]);
        *(int4*)(hnext + (size_t)n * 128 + gl * 8) = st;
    } else {
        #pragma unroll
        for (int c = 0; c < 8; ++c) o[c] = 0.f;
    }

    // fused BN stats: wave reduce -> LDS -> one replica of global stats
    float s8[8], q8[8];
    #pragma unroll
    for (int c = 0; c < 8; ++c) { s8[c] = o[c]; q8[c] = o[c] * o[c]; }
    #pragma unroll
    for (int c = 0; c < 8; ++c) {
        s8[c] += __shfl_xor(s8[c], 16); s8[c] += __shfl_xor(s8[c], 32);
        q8[c] += __shfl_xor(q8[c], 16); q8[c] += __shfl_xor(q8[c], 32);
    }
    if (lane < 16) {
        #pragma unroll
        for (int c = 0; c < 8; ++c) {
            atomicAdd(&ls[gl * 8 + c], s8[c]);
            atomicAdd(&lq2[gl * 8 + c], q8[c]);
        }
    }
    __syncthreads();
    float* srep = stats + (blockIdx.x & (NREP - 1)) * 1024;
    if (tid < 128) atomicAdd(&srep[tid], ls[tid]);
    else atomicAdd(&srep[512 + tid - 128], lq2[tid - 128]);
}

// ---------------- final BN apply ----------------

__global__ __launch_bounds__(256) void bn_apply_f32_kernel(
    const float* __restrict__ x, float* __restrict__ y,
    const float* __restrict__ stats, const float* __restrict__ g,
    const float* __restrict__ b, int N, int F)
{
    __shared__ float scale[128], shift[128];
    int tid = threadIdx.x;
    if (tid < F) {
        float invN = 1.0f / (float)N;
        float mu = stats[tid] * invN;
        float var = stats[512 + tid] * invN - mu * mu;
        float sc = rsqrtf(var + BN_EPS) * g[tid];
        scale[tid] = sc;
        shift[tid] = b[tid] - mu * sc;
    }
    __syncthreads();
    size_t total4 = (size_t)N * F >> 2;
    int Fm = F - 1;
    for (size_t t = (size_t)blockIdx.x * blockDim.x + tid; t < total4;
         t += (size_t)gridDim.x * blockDim.x) {
        size_t i = t * 4;
        int f = (int)(i & (size_t)Fm);
        float4 v = *(const float4*)(x + i);
        float4 o;
        o.x = fmaxf(v.x * scale[f + 0] + shift[f + 0], 0.f);
        o.y = fmaxf(v.y * scale[f + 1] + shift[f + 1], 0.f);
        o.z = fmaxf(v.z * scale[f + 2] + shift[f + 2], 0.f);
        o.w = fmaxf(v.w * scale[f + 3] + shift[f + 3], 0.f);
        *(float4*)(y + i) = o;
    }
}

// ---------------- launch ----------------

static inline size_t al16(size_t x) { return (x + 15) & ~(size_t)15; }

extern "C" void kernel_launch(void* const* d_in, const int* in_sizes, int n_in,
                              void* d_out, int out_size, void* d_ws, size_t ws_size,
                              hipStream_t stream) {
    const float* x    = (const float*)d_in[0];
    const int*   edge = (const int*)d_in[1];
    const float* Wq   = (const float*)d_in[2];
    const float* bq   = (const float*)d_in[3];
    const float* Wk   = (const float*)d_in[4];
    const float* bk   = (const float*)d_in[5];
    const float* Wv   = (const float*)d_in[6];
    const float* bv   = (const float*)d_in[7];
    const float* Wsk  = (const float*)d_in[8];
    const float* bsk  = (const float*)d_in[9];
    const float* bng  = (const float*)d_in[10];
    const float* bnb  = (const float*)d_in[11];
    const float* Wo   = (const float*)d_in[12];
    const float* bo   = (const float*)d_in[13];
    const float* bnog = (const float*)d_in[14];
    const float* bnob = (const float*)d_in[15];

    const int N = in_sizes[0] / D_FEAT;
    const int E = in_sizes[1] / 2;
    const int* esrc = edge;
    const int* edst = edge + E;

    const int SB = (N + SORT_NPB - 1) / SORT_NPB;

    char* wsb = (char*)d_ws;
    unsigned short* xb = (unsigned short*)wsb; wsb += al16((size_t)N * 128 * 2);
    unsigned short* kv = (unsigned short*)wsb; wsb += al16((size_t)N * 256 * 2);
    unsigned short* q  = (unsigned short*)wsb; wsb += al16((size_t)N * 128 * 2);
    unsigned short* s  = (unsigned short*)wsb; wsb += al16((size_t)N * 128 * 2);
    unsigned short* hnext = (unsigned short*)wsb; wsb += al16((size_t)N * 128 * 2);
    float* outpre = (float*)wsb; wsb += al16((size_t)N * 64 * 4);
    unsigned short* Wt  = (unsigned short*)wsb; wsb += al16((size_t)NLAYER * 4 * 16384 * 2);
    unsigned short* Wot = (unsigned short*)wsb; wsb += al16((size_t)64 * 128 * 2);
    float* stats  = (float*)wsb; wsb += al16((size_t)(NLAYER * NREP + 1) * 1024 * 4);
    int* rowptr   = (int*)wsb;   wsb += al16((size_t)(N + 1) * 4);
    int* deg      = (int*)wsb;   wsb += al16((size_t)N * 4);
    int* csrsrc   = (int*)wsb;   wsb += al16((size_t)(E + 64) * 4);  // +pad for unroll-8 overread
    int* partials = (int*)wsb;   wsb += al16(256 * 4);
    int* bhist    = (int*)wsb;   wsb += al16((size_t)256 * SB * 4);
    int* binoff   = (int*)wsb;   wsb += al16(256 * 4);
    int* order    = (int*)wsb;   wsb += al16((size_t)N * 4);

    cvt_bf16_kernel<<<2048, 256, 0, stream>>>(x, xb, (size_t)N * 128 / 4);
    prep_weights_kernel<<<256, 256, 0, stream>>>(Wq, Wk, Wv, Wsk, Wo, Wt, Wot);
    hipMemsetAsync(stats, 0, (size_t)(NLAYER * NREP + 1) * 1024 * 4, stream);

    // CSR build
    const int nb1 = (N + 1023) / 1024;
    hipMemsetAsync(deg, 0, (size_t)N * 4, stream);
    hist_kernel<<<(E + 255) / 256, 256, 0, stream>>>(edst, E, deg);
    scan1_kernel<<<nb1, 256, 0, stream>>>(deg, N, rowptr, partials);
    scan2_kernel<<<1, 64, 0, stream>>>(partials, nb1);
    scan3_kernel<<<nb1, 256, 0, stream>>>(rowptr, N, partials);
    hipMemsetAsync(deg, 0, (size_t)N * 4, stream);
    scatter_kernel<<<(E + 255) / 256, 256, 0, stream>>>(esrc, edst, E, rowptr, deg, csrsrc);

    // degree-binned node order (descending)
    bin_blockhist_kernel<<<SB, 256, 0, stream>>>(rowptr, N, SB, bhist);
    bin_colscan_kernel<<<1, 256, 0, stream>>>(bhist, SB, binoff);
    bin_order_kernel<<<SB, 256, 0, stream>>>(rowptr, N, SB, bhist, binoff, order);

    const int gemm_rb = (N + 127) / 128;
    const int attn_blocks = (N + 15) / 16;
    const unsigned short* hin = xb;
    for (int l = 0; l < NLAYER; ++l) {
        const float* statsIn = (l == 0) ? (const float*)nullptr
                                        : stats + (size_t)(l - 1) * NREP * 1024;
        const float* gIn = (l == 0) ? (const float*)nullptr : bng + (l - 1) * 128;
        const float* bIn = (l == 0) ? (const float*)nullptr : bnb + (l - 1) * 128;
        gemm_qkvs_kernel<<<dim3(gemm_rb, 2), 256, 0, stream>>>(
            hin, statsIn, gIn, bIn, (l == 0) ? 0 : 1, N,
            Wt + (size_t)l * 4 * 16384,
            bq + l * 128, bk + l * 128, bv + l * 128, bsk + l * 128,
            q, kv, s);
        attn_kernel<<<attn_blocks, 256, 0, stream>>>(q, kv, s, rowptr, csrsrc, order,
                                                     hnext, stats + (size_t)l * NREP * 1024, N);
        hin = hnext;
    }

    float* fstats = stats + (size_t)NLAYER * NREP * 1024;
    gemm_final_kernel<<<gemm_rb, 256, 0, stream>>>(
        hnext, stats + (size_t)2 * NREP * 1024, bng + 2 * 128, bnb + 2 * 128, N,
        Wot, bo, outpre, fstats);
    bn_apply_f32_kernel<<<2048, 256, 0, stream>>>(outpre, (float*)d_out, fstats,
                                                  bnog, bnob, N, 64);
}

// Round 11
// 446.801 us; speedup vs baseline: 1.7075x; 1.0999x over previous
//
#include <hip/hip_runtime.h>
#include <hip/hip_bf16.h>
#include <math.h>

#define D_FEAT 128
#define NLAYER 3
#define BN_EPS 1e-5f
#define INV_SQRT_C 0.17677669529663687f  // 1/sqrt(32)
#define SORT_NPB 1024                    // nodes per sort block
#define NREP 8                           // stats replicas (atomic decontention)
#define TP 136                           // gemm LDS tile pitch (shorts): 272B rows, 16B-aligned

typedef __bf16 bf16x8 __attribute__((ext_vector_type(8)));
typedef float f32x4 __attribute__((ext_vector_type(4)));

static __device__ __forceinline__ unsigned short f2bf(float f) {
    return __builtin_bit_cast(unsigned short, __float2bfloat16(f));
}
static __device__ __forceinline__ float bfl(unsigned u) { return __uint_as_float(u << 16); }
static __device__ __forceinline__ float bfh(unsigned u) { return __uint_as_float(u & 0xffff0000u); }
static __device__ __forceinline__ unsigned packbf(float a, float b) {
    return (unsigned)f2bf(a) | ((unsigned)f2bf(b) << 16);
}

// ---------------- fused prep: x->bf16 cvt (blocks <1792) + weight transp/cvt ----------------

__global__ void prep_kernel(const float* __restrict__ x, unsigned short* __restrict__ xb,
                            size_t n4,
                            const float* __restrict__ Wq, const float* __restrict__ Wk,
                            const float* __restrict__ Wv, const float* __restrict__ Ws,
                            const float* __restrict__ Wo,
                            unsigned short* __restrict__ Wt, unsigned short* __restrict__ Wot)
{
    const int CVTB = 1792;
    int b = blockIdx.x;
    if (b < CVTB) {
        for (size_t t = (size_t)b * blockDim.x + threadIdx.x; t < n4;
             t += (size_t)CVTB * blockDim.x) {
            size_t i = t * 4;
            float4 v = *(const float4*)(x + i);
            ushort4 u;
            u.x = f2bf(v.x); u.y = f2bf(v.y); u.z = f2bf(v.z); u.w = f2bf(v.w);
            *(ushort4*)(xb + i) = u;
        }
    } else {
        const int permat = 16384;
        const int main_total = NLAYER * 4 * permat;
        const int total = main_total + 64 * 128;
        const int WB = gridDim.x - CVTB;
        for (int i = (b - CVTB) * blockDim.x + threadIdx.x; i < total;
             i += WB * blockDim.x) {
            if (i < main_total) {
                int l = i / (4 * permat);
                int rem = i - l * (4 * permat);
                int mat = rem / permat;
                int e = rem - mat * permat;
                int nn = e >> 7;
                int kk = e & 127;
                const float* src = (mat == 0) ? Wq : (mat == 1) ? Wk : (mat == 2) ? Wv : Ws;
                Wt[(size_t)l * 4 * permat + mat * permat + nn * 128 + kk] =
                    f2bf(src[(size_t)l * permat + kk * 128 + nn]);
            } else {
                int e = i - main_total;
                int nn = e >> 7;
                int kk = e & 127;
                Wot[nn * 128 + kk] = f2bf(Wo[kk * 64 + nn]);
            }
        }
    }
}

// ---------------- CSR build ----------------

__global__ void hist_kernel(const int* __restrict__ dst, int E, int* __restrict__ deg) {
    int e = blockIdx.x * blockDim.x + threadIdx.x;
    if (e < E) atomicAdd(&deg[dst[e]], 1);
}

__global__ __launch_bounds__(256) void scan1_kernel(const int* __restrict__ deg, int n,
                                                    int* __restrict__ rowptr,
                                                    int* __restrict__ partials) {
    int b = blockIdx.x, tid = threadIdx.x;
    int base = b * 1024 + tid * 4;
    int4 d = {0, 0, 0, 0};
    if (base + 3 < n) d = *(const int4*)(deg + base);
    else {
        if (base + 0 < n) d.x = deg[base + 0];
        if (base + 1 < n) d.y = deg[base + 1];
        if (base + 2 < n) d.z = deg[base + 2];
        if (base + 3 < n) d.w = deg[base + 3];
    }
    int p0 = d.x, p1 = p0 + d.y, p2 = p1 + d.z, p3 = p2 + d.w;
    int v = p3;
    int lane = tid & 63;
    #pragma unroll
    for (int off = 1; off < 64; off <<= 1) {
        int t = __shfl_up(v, off);
        if (lane >= off) v += t;
    }
    __shared__ int wsum[4];
    int w = tid >> 6;
    if (lane == 63) wsum[w] = v;
    __syncthreads();
    int woff = 0;
    #pragma unroll
    for (int j = 0; j < 4; ++j) if (j < w) woff += wsum[j];
    int excl = woff + v - p3;
    if (base + 0 < n) rowptr[base + 1] = excl + p0;
    if (base + 1 < n) rowptr[base + 2] = excl + p1;
    if (base + 2 < n) rowptr[base + 3] = excl + p2;
    if (base + 3 < n) rowptr[base + 4] = excl + p3;
    if (tid == 255) partials[b] = excl + p3;
    if (b == 0 && tid == 0) rowptr[0] = 0;
}

__global__ void scan2_kernel(int* __restrict__ partials, int nb) {
    int lane = threadIdx.x;
    int v = (lane < nb) ? partials[lane] : 0;
    #pragma unroll
    for (int off = 1; off < 64; off <<= 1) {
        int t = __shfl_up(v, off);
        if (lane >= off) v += t;
    }
    if (lane < nb) partials[lane] = v;  // inclusive
}

// Fused: finalize rowptr (add block offset) AND build per-block degree histogram
// (descending bins). Degrees are derived from OLD (block-local) rowptr values, so
// there is no cross-block dependency: deg[i] = old[i+1]-old[i] (i>base), old[base+1] (i==base).
__global__ __launch_bounds__(256) void scan3_hist_kernel(
    int* __restrict__ rowptr, int n, const int* __restrict__ partials,
    int B, int* __restrict__ bhist)
{
    __shared__ int h[256];
    __shared__ int oldv[SORT_NPB];
    int b = blockIdx.x, tid = threadIdx.x;
    h[tid] = 0;
    int off = (b == 0) ? 0 : partials[b - 1];
    #pragma unroll
    for (int j = 0; j < SORT_NPB / 256; ++j) {
        int loc = j * 256 + tid;
        int i = b * SORT_NPB + loc;
        oldv[loc] = (i < n) ? rowptr[i + 1] : 0;
    }
    __syncthreads();
    #pragma unroll
    for (int j = 0; j < SORT_NPB / 256; ++j) {
        int loc = j * 256 + tid;
        int i = b * SORT_NPB + loc;
        if (i < n) {
            int d = (loc == 0) ? oldv[0] : (oldv[loc] - oldv[loc - 1]);
            if (d > 255) d = 255;
            atomicAdd(&h[255 - d], 1);        // descending
            rowptr[i + 1] = oldv[loc] + off;  // finalize
        }
    }
    __syncthreads();
    bhist[tid * B + b] = h[tid];
}

__global__ void scatter_kernel(const int* __restrict__ src, const int* __restrict__ dst, int E,
                               const int* __restrict__ rowptr, int* __restrict__ cursor,
                               int* __restrict__ csrsrc) {
    int e = blockIdx.x * blockDim.x + threadIdx.x;
    if (e < E) {
        int d = dst[e];
        int p = atomicAdd(&cursor[d], 1);
        csrsrc[rowptr[d] + p] = src[e];
    }
}

__global__ __launch_bounds__(256) void bin_colscan_kernel(
    int* __restrict__ bhist, int B, int* __restrict__ binoff)
{
    int d = threadIdx.x;
    int run = 0;
    for (int b = 0; b < B; ++b) {
        int c = bhist[d * B + b];
        bhist[d * B + b] = run;
        run += c;
    }
    __shared__ int sd[256];
    sd[d] = run;
    __syncthreads();
    int v = run;
    for (int s = 1; s < 256; s <<= 1) {
        int t = (d >= s) ? sd[d - s] : 0;
        __syncthreads();
        sd[d] += t;
        __syncthreads();
    }
    binoff[d] = sd[d] - v;  // exclusive
}

__global__ __launch_bounds__(256) void bin_order_kernel(
    const int* __restrict__ rowptr, int n, int B,
    const int* __restrict__ bhist, const int* __restrict__ binoff,
    int* __restrict__ order)
{
    __shared__ int cur[256];
    int b = blockIdx.x, tid = threadIdx.x;
    cur[tid] = binoff[tid] + bhist[tid * B + b];
    __syncthreads();
    #pragma unroll
    for (int j = 0; j < SORT_NPB / 256; ++j) {
        int i = b * SORT_NPB + j * 256 + tid;
        if (i < n) {
            int d = rowptr[i + 1] - rowptr[i];
            if (d > 255) d = 255;
            int pos = atomicAdd(&cur[255 - d], 1);
            order[pos] = i;
        }
    }
}

// ---------------- LDS-free direct-register MFMA GEMM, ct-pairs, inline BN,
// LDS-transposed coalesced epilogue ----------------

__global__ __launch_bounds__(256, 2) void gemm_qkvs_kernel(
    const unsigned short* __restrict__ A,
    const float* __restrict__ stats, const float* __restrict__ g,
    const float* __restrict__ bb, int mode, int M,
    const unsigned short* __restrict__ Wt,
    const float* __restrict__ b0, const float* __restrict__ b1,
    const float* __restrict__ b2, const float* __restrict__ b3,
    unsigned short* __restrict__ q, unsigned short* __restrict__ kv,
    unsigned short* __restrict__ s)
{
    __shared__ float scale[128], shift[128];
    __shared__ unsigned short tile[128 * TP];
    int r0 = blockIdx.x * 128;
    int tid = threadIdx.x;
    int wid = tid >> 6, lane = tid & 63;
    int wm = wid >> 1, wn = wid & 1;
    int lr = lane & 15, lk = lane >> 4;

    if (mode && tid < 128) {
        float ssum = 0.f, qsum = 0.f;
        #pragma unroll
        for (int r = 0; r < NREP; ++r) {
            ssum += stats[r * 1024 + tid];
            qsum += stats[r * 1024 + 512 + tid];
        }
        float invN = 1.0f / (float)M;
        float mu = ssum * invN;
        float var = qsum * invN - mu * mu;
        float sc = rsqrtf(var + BN_EPS) * g[tid];
        scale[tid] = sc;
        shift[tid] = bb[tid] - mu * sc;
    }
    __syncthreads();

    // Load + BN a-frags once
    bf16x8 a[4][4];
    #pragma unroll
    for (int ks = 0; ks < 4; ++ks) {
        int ko = ks * 32 + lk * 8;
        #pragma unroll
        for (int mi = 0; mi < 4; ++mi) {
            int arow = r0 + wm * 64 + mi * 16 + lr;
            int4 t = {0, 0, 0, 0};
            if (arow < M) t = *(const int4*)(A + (size_t)arow * 128 + ko);
            if (mode) {
                float4 sc0 = *(const float4*)&scale[ko];
                float4 sc1 = *(const float4*)&scale[ko + 4];
                float4 sh0 = *(const float4*)&shift[ko];
                float4 sh1 = *(const float4*)&shift[ko + 4];
                float v0 = fmaxf(bfl(t.x) * sc0.x + sh0.x, 0.f);
                float v1 = fmaxf(bfh(t.x) * sc0.y + sh0.y, 0.f);
                float v2 = fmaxf(bfl(t.y) * sc0.z + sh0.z, 0.f);
                float v3 = fmaxf(bfh(t.y) * sc0.w + sh0.w, 0.f);
                float v4 = fmaxf(bfl(t.z) * sc1.x + sh1.x, 0.f);
                float v5 = fmaxf(bfh(t.z) * sc1.y + sh1.y, 0.f);
                float v6 = fmaxf(bfl(t.w) * sc1.z + sh1.z, 0.f);
                float v7 = fmaxf(bfh(t.w) * sc1.w + sh1.w, 0.f);
                t.x = (int)packbf(v0, v1); t.y = (int)packbf(v2, v3);
                t.z = (int)packbf(v4, v5); t.w = (int)packbf(v6, v7);
            }
            a[mi][ks] = __builtin_bit_cast(bf16x8, t);
        }
    }

    #pragma unroll
    for (int cc = 0; cc < 2; ++cc) {
        int ct = blockIdx.y * 2 + cc;
        const unsigned short* W = Wt + (size_t)ct * 16384;

        f32x4 acc[4][4] = {};
        #pragma unroll
        for (int ks = 0; ks < 4; ++ks) {
            int ko = ks * 32 + lk * 8;
            bf16x8 b[4];
            #pragma unroll
            for (int nj = 0; nj < 4; ++nj) {
                int4 t = *(const int4*)(W + (size_t)(wn * 64 + nj * 16 + lr) * 128 + ko);
                b[nj] = __builtin_bit_cast(bf16x8, t);
            }
            #pragma unroll
            for (int mi = 0; mi < 4; ++mi)
                #pragma unroll
                for (int nj = 0; nj < 4; ++nj)
                    acc[mi][nj] = __builtin_amdgcn_mfma_f32_16x16x32_bf16(
                        a[mi][ks], b[nj], acc[mi][nj], 0, 0, 0);
        }

        const float* bias = (ct == 0) ? b0 : (ct == 1) ? b1 : (ct == 2) ? b2 : b3;
        __syncthreads();   // previous cc's tile readers done
        #pragma unroll
        for (int mi = 0; mi < 4; ++mi) {
            #pragma unroll
            for (int nj = 0; nj < 4; ++nj) {
                int col = wn * 64 + nj * 16 + lr;
                float bv = bias[col];
                #pragma unroll
                for (int reg = 0; reg < 4; ++reg) {
                    int rloc = wm * 64 + mi * 16 + lk * 4 + reg;
                    tile[rloc * TP + col] = f2bf(acc[mi][nj][reg] + bv);
                }
            }
        }
        __syncthreads();
        // coalesced readback: 8 int4 per thread
        #pragma unroll
        for (int it = 0; it < 8; ++it) {
            int flat = (it * 256 + tid) * 8;
            int row = flat >> 7, col = flat & 127;
            int rw = r0 + row;
            if (rw < M) {
                int4 v = *(const int4*)&tile[row * TP + col];
                if (ct == 0) *(int4*)(q + (size_t)rw * 128 + col) = v;
                else if (ct == 1) *(int4*)(kv + (size_t)rw * 256 + col) = v;
                else if (ct == 2) *(int4*)(kv + (size_t)rw * 256 + 128 + col) = v;
                else *(int4*)(s + (size_t)rw * 128 + col) = v;
            }
        }
    }
}

// Final: out[M x 64] = BNrelu(A) @ Wo + bo (f32), inline BN from replicated raw stats;
// accumulates output column stats into statsOut.
__global__ __launch_bounds__(256, 2) void gemm_final_kernel(
    const unsigned short* __restrict__ A,
    const float* __restrict__ stats, const float* __restrict__ g,
    const float* __restrict__ bb, int M,
    const unsigned short* __restrict__ Wot, const float* __restrict__ bias,
    float* __restrict__ out, float* __restrict__ statsOut)
{
    __shared__ float scale[128], shift[128];
    __shared__ float fs[64], fq[64];
    int r0 = blockIdx.x * 128;
    int tid = threadIdx.x;
    int wid = tid >> 6, lane = tid & 63;
    int wm = wid >> 1, wn = wid & 1;
    int lr = lane & 15, lk = lane >> 4;

    if (tid < 128) {
        float ssum = 0.f, qsum = 0.f;
        #pragma unroll
        for (int r = 0; r < NREP; ++r) {
            ssum += stats[r * 1024 + tid];
            qsum += stats[r * 1024 + 512 + tid];
        }
        float invN = 1.0f / (float)M;
        float mu = ssum * invN;
        float var = qsum * invN - mu * mu;
        float sc = rsqrtf(var + BN_EPS) * g[tid];
        scale[tid] = sc;
        shift[tid] = bb[tid] - mu * sc;
    }
    if (tid < 64) { fs[tid] = 0.f; fq[tid] = 0.f; }
    __syncthreads();

    bf16x8 a[4][4];
    #pragma unroll
    for (int ks = 0; ks < 4; ++ks) {
        int ko = ks * 32 + lk * 8;
        #pragma unroll
        for (int mi = 0; mi < 4; ++mi) {
            int arow = r0 + wm * 64 + mi * 16 + lr;
            int4 t = {0, 0, 0, 0};
            if (arow < M) t = *(const int4*)(A + (size_t)arow * 128 + ko);
            float4 sc0 = *(const float4*)&scale[ko];
            float4 sc1 = *(const float4*)&scale[ko + 4];
            float4 sh0 = *(const float4*)&shift[ko];
            float4 sh1 = *(const float4*)&shift[ko + 4];
            float v0 = fmaxf(bfl(t.x) * sc0.x + sh0.x, 0.f);
            float v1 = fmaxf(bfh(t.x) * sc0.y + sh0.y, 0.f);
            float v2 = fmaxf(bfl(t.y) * sc0.z + sh0.z, 0.f);
            float v3 = fmaxf(bfh(t.y) * sc0.w + sh0.w, 0.f);
            float v4 = fmaxf(bfl(t.z) * sc1.x + sh1.x, 0.f);
            float v5 = fmaxf(bfh(t.z) * sc1.y + sh1.y, 0.f);
            float v6 = fmaxf(bfl(t.w) * sc1.z + sh1.z, 0.f);
            float v7 = fmaxf(bfh(t.w) * sc1.w + sh1.w, 0.f);
            t.x = (int)packbf(v0, v1); t.y = (int)packbf(v2, v3);
            t.z = (int)packbf(v4, v5); t.w = (int)packbf(v6, v7);
            a[mi][ks] = __builtin_bit_cast(bf16x8, t);
        }
    }

    f32x4 acc[4][2] = {};
    #pragma unroll
    for (int ks = 0; ks < 4; ++ks) {
        int ko = ks * 32 + lk * 8;
        bf16x8 b[2];
        #pragma unroll
        for (int nj = 0; nj < 2; ++nj) {
            int4 t = *(const int4*)(Wot + (size_t)(wn * 32 + nj * 16 + lr) * 128 + ko);
            b[nj] = __builtin_bit_cast(bf16x8, t);
        }
        #pragma unroll
        for (int mi = 0; mi < 4; ++mi)
            #pragma unroll
            for (int nj = 0; nj < 2; ++nj)
                acc[mi][nj] = __builtin_amdgcn_mfma_f32_16x16x32_bf16(
                    a[mi][ks], b[nj], acc[mi][nj], 0, 0, 0);
    }

    float csum[2] = {0.f, 0.f}, csq[2] = {0.f, 0.f};
    #pragma unroll
    for (int mi = 0; mi < 4; ++mi) {
        #pragma unroll
        for (int nj = 0; nj < 2; ++nj) {
            int col = wn * 32 + nj * 16 + lr;
            float bv = bias[col];
            #pragma unroll
            for (int reg = 0; reg < 4; ++reg) {
                int rw = r0 + wm * 64 + mi * 16 + lk * 4 + reg;
                if (rw < M) {
                    float val = acc[mi][nj][reg] + bv;
                    out[(size_t)rw * 64 + col] = val;
                    csum[nj] += val;
                    csq[nj] += val * val;
                }
            }
        }
    }
    #pragma unroll
    for (int nj = 0; nj < 2; ++nj) {
        csum[nj] += __shfl_xor(csum[nj], 16);
        csum[nj] += __shfl_xor(csum[nj], 32);
        csq[nj]  += __shfl_xor(csq[nj], 16);
        csq[nj]  += __shfl_xor(csq[nj], 32);
    }
    if (lane < 16) {
        #pragma unroll
        for (int nj = 0; nj < 2; ++nj) {
            int col = wn * 32 + nj * 16 + lr;
            atomicAdd(&fs[col], csum[nj]);
            atomicAdd(&fq[col], csq[nj]);
        }
    }
    __syncthreads();
    if (tid < 64) atomicAdd(&statsOut[tid], fs[tid]);
    else if (tid < 128) atomicAdd(&statsOut[512 + tid - 64], fq[tid - 64]);
}

// ---------------- Fused attention: 4 nodes/wave, unroll 8, bf16 out + replicated BN stats ----------------

__global__ __launch_bounds__(256) void attn_kernel(
    const unsigned short* __restrict__ q, const unsigned short* __restrict__ kv,
    const unsigned short* __restrict__ sk,
    const int* __restrict__ rowptr, const int* __restrict__ csrsrc,
    const int* __restrict__ order,
    unsigned short* __restrict__ hnext, float* __restrict__ stats, int N)
{
    __shared__ float ls[128], lq2[128];
    int tid = threadIdx.x;
    if (tid < 128) { ls[tid] = 0.f; lq2[tid] = 0.f; }
    __syncthreads();

    int wave = (blockIdx.x * blockDim.x + tid) >> 6;
    int lane = tid & 63;
    int gl = lane & 15;
    int slot = wave * 4 + (lane >> 4);
    bool nv = slot < N;
    int n = nv ? order[slot] : 0;

    int r0 = rowptr[n], r1 = rowptr[n + 1];
    int deg = nv ? (r1 - r0) : 0;
    int dmax = deg;
    dmax = max(dmax, __shfl_xor(dmax, 16));
    dmax = max(dmax, __shfl_xor(dmax, 32));

    int4 qu = *(const int4*)(q + (size_t)n * 128 + gl * 8);
    float qf[8];
    qf[0] = bfl(qu.x); qf[1] = bfh(qu.x); qf[2] = bfl(qu.y); qf[3] = bfh(qu.y);
    qf[4] = bfl(qu.z); qf[5] = bfh(qu.z); qf[6] = bfl(qu.w); qf[7] = bfh(qu.w);

    float m = -INFINITY, ssum = 0.f;
    float acc[8] = {};

    for (int i = 0; i < dmax; i += 8) {
        int eidx[8];
        bool av[8];
        #pragma unroll
        for (int j = 0; j < 8; ++j) {
            av[j] = (i + j) < deg;
            int e = csrsrc[r0 + i + j];   // csrsrc padded; OOB masked below
            eidx[j] = av[j] ? e : 0;
        }
        int4 K[8], V[8];
        #pragma unroll
        for (int j = 0; j < 8; ++j) {
            const unsigned short* row = kv + (size_t)eidx[j] * 256 + gl * 8;
            K[j] = *(const int4*)(row);
            V[j] = *(const int4*)(row + 128);
        }
        float sc[8];
        #pragma unroll
        for (int j = 0; j < 8; ++j) {
            float p = qf[0] * bfl(K[j].x) + qf[1] * bfh(K[j].x)
                    + qf[2] * bfl(K[j].y) + qf[3] * bfh(K[j].y)
                    + qf[4] * bfl(K[j].z) + qf[5] * bfh(K[j].z)
                    + qf[6] * bfl(K[j].w) + qf[7] * bfh(K[j].w);
            p += __shfl_xor(p, 1);
            p += __shfl_xor(p, 2);
            sc[j] = av[j] ? p * INV_SQRT_C : -INFINITY;
        }
        float mn = m;
        #pragma unroll
        for (int j = 0; j < 8; ++j) mn = fmaxf(mn, sc[j]);
        if (mn > m) {
            float scale = __expf(m - mn);
            ssum *= scale;
            #pragma unroll
            for (int c = 0; c < 8; ++c) acc[c] *= scale;
            m = mn;
        }
        #pragma unroll
        for (int j = 0; j < 8; ++j) {
            float ej = av[j] ? __expf(sc[j] - m) : 0.f;
            ssum += ej;
            acc[0] += ej * bfl(V[j].x); acc[1] += ej * bfh(V[j].x);
            acc[2] += ej * bfl(V[j].y); acc[3] += ej * bfh(V[j].y);
            acc[4] += ej * bfl(V[j].z); acc[5] += ej * bfh(V[j].z);
            acc[6] += ej * bfl(V[j].w); acc[7] += ej * bfh(V[j].w);
        }
    }

    float o[8];
    if (nv) {
        float inv = (ssum > 0.f) ? 1.0f / ssum : 0.f;
        int4 su = *(const int4*)(sk + (size_t)n * 128 + gl * 8);
        o[0] = acc[0] * inv + bfl(su.x); o[1] = acc[1] * inv + bfh(su.x);
        o[2] = acc[2] * inv + bfl(su.y); o[3] = acc[3] * inv + bfh(su.y);
        o[4] = acc[4] * inv + bfl(su.z); o[5] = acc[5] * inv + bfh(su.z);
        o[6] = acc[6] * inv + bfl(su.w); o[7] = acc[7] * inv + bfh(su.w);
        int4 st;
        st.x = (int)packbf(o[0], o[1]); st.y = (int)packbf(o[2], o[3]);
        st.z = (int)packbf(o[4], o[5]); st.w = (int)packbf(o[6], o[7]);
        *(int4*)(hnext + (size_t)n * 128 + gl * 8) = st;
    } else {
        #pragma unroll
        for (int c = 0; c < 8; ++c) o[c] = 0.f;
    }

    // fused BN stats: wave reduce -> LDS -> one replica of global stats
    float s8[8], q8[8];
    #pragma unroll
    for (int c = 0; c < 8; ++c) { s8[c] = o[c]; q8[c] = o[c] * o[c]; }
    #pragma unroll
    for (int c = 0; c < 8; ++c) {
        s8[c] += __shfl_xor(s8[c], 16); s8[c] += __shfl_xor(s8[c], 32);
        q8[c] += __shfl_xor(q8[c], 16); q8[c] += __shfl_xor(q8[c], 32);
    }
    if (lane < 16) {
        #pragma unroll
        for (int c = 0; c < 8; ++c) {
            atomicAdd(&ls[gl * 8 + c], s8[c]);
            atomicAdd(&lq2[gl * 8 + c], q8[c]);
        }
    }
    __syncthreads();
    float* srep = stats + (blockIdx.x & (NREP - 1)) * 1024;
    if (tid < 128) atomicAdd(&srep[tid], ls[tid]);
    else atomicAdd(&srep[512 + tid - 128], lq2[tid - 128]);
}

// ---------------- final BN apply ----------------

__global__ __launch_bounds__(256) void bn_apply_f32_kernel(
    const float* __restrict__ x, float* __restrict__ y,
    const float* __restrict__ stats, const float* __restrict__ g,
    const float* __restrict__ b, int N, int F)
{
    __shared__ float scale[128], shift[128];
    int tid = threadIdx.x;
    if (tid < F) {
        float invN = 1.0f / (float)N;
        float mu = stats[tid] * invN;
        float var = stats[512 + tid] * invN - mu * mu;
        float sc = rsqrtf(var + BN_EPS) * g[tid];
        scale[tid] = sc;
        shift[tid] = b[tid] - mu * sc;
    }
    __syncthreads();
    size_t total4 = (size_t)N * F >> 2;
    int Fm = F - 1;
    for (size_t t = (size_t)blockIdx.x * blockDim.x + tid; t < total4;
         t += (size_t)gridDim.x * blockDim.x) {
        size_t i = t * 4;
        int f = (int)(i & (size_t)Fm);
        float4 v = *(const float4*)(x + i);
        float4 o;
        o.x = fmaxf(v.x * scale[f + 0] + shift[f + 0], 0.f);
        o.y = fmaxf(v.y * scale[f + 1] + shift[f + 1], 0.f);
        o.z = fmaxf(v.z * scale[f + 2] + shift[f + 2], 0.f);
        o.w = fmaxf(v.w * scale[f + 3] + shift[f + 3], 0.f);
        *(float4*)(y + i) = o;
    }
}

// ---------------- launch ----------------

static inline size_t al16(size_t x) { return (x + 15) & ~(size_t)15; }

extern "C" void kernel_launch(void* const* d_in, const int* in_sizes, int n_in,
                              void* d_out, int out_size, void* d_ws, size_t ws_size,
                              hipStream_t stream) {
    const float* x    = (const float*)d_in[0];
    const int*   edge = (const int*)d_in[1];
    const float* Wq   = (const float*)d_in[2];
    const float* bq   = (const float*)d_in[3];
    const float* Wk   = (const float*)d_in[4];
    const float* bk   = (const float*)d_in[5];
    const float* Wv   = (const float*)d_in[6];
    const float* bv   = (const float*)d_in[7];
    const float* Wsk  = (const float*)d_in[8];
    const float* bsk  = (const float*)d_in[9];
    const float* bng  = (const float*)d_in[10];
    const float* bnb  = (const float*)d_in[11];
    const float* Wo   = (const float*)d_in[12];
    const float* bo   = (const float*)d_in[13];
    const float* bnog = (const float*)d_in[14];
    const float* bnob = (const float*)d_in[15];

    const int N = in_sizes[0] / D_FEAT;
    const int E = in_sizes[1] / 2;
    const int* esrc = edge;
    const int* edst = edge + E;

    const int SB = (N + SORT_NPB - 1) / SORT_NPB;
    const size_t STATS_F = (size_t)(NLAYER * NREP + 1) * 1024;

    char* wsb = (char*)d_ws;
    unsigned short* xb = (unsigned short*)wsb; wsb += al16((size_t)N * 128 * 2);
    unsigned short* kv = (unsigned short*)wsb; wsb += al16((size_t)N * 256 * 2);
    unsigned short* q  = (unsigned short*)wsb; wsb += al16((size_t)N * 128 * 2);
    unsigned short* s  = (unsigned short*)wsb; wsb += al16((size_t)N * 128 * 2);
    unsigned short* hnext = (unsigned short*)wsb; wsb += al16((size_t)N * 128 * 2);
    float* outpre = (float*)wsb; wsb += al16((size_t)N * 64 * 4);
    unsigned short* Wt  = (unsigned short*)wsb; wsb += al16((size_t)NLAYER * 4 * 16384 * 2);
    unsigned short* Wot = (unsigned short*)wsb; wsb += al16((size_t)64 * 128 * 2);
    // zero-region: stats | deg | cursor (one memset)
    float* stats  = (float*)wsb; wsb += al16(STATS_F * 4);
    int* deg      = (int*)wsb;   wsb += al16((size_t)N * 4);
    int* cursor   = (int*)wsb;   wsb += al16((size_t)N * 4);
    size_t zero_bytes = (char*)wsb - (char*)stats;
    int* rowptr   = (int*)wsb;   wsb += al16((size_t)(N + 1) * 4);
    int* csrsrc   = (int*)wsb;   wsb += al16((size_t)(E + 64) * 4);  // +pad for unroll-8 overread
    int* partials = (int*)wsb;   wsb += al16(256 * 4);
    int* bhist    = (int*)wsb;   wsb += al16((size_t)256 * SB * 4);
    int* binoff   = (int*)wsb;   wsb += al16(256 * 4);
    int* order    = (int*)wsb;   wsb += al16((size_t)N * 4);

    prep_kernel<<<2048, 256, 0, stream>>>(x, xb, (size_t)N * 128 / 4,
                                          Wq, Wk, Wv, Wsk, Wo, Wt, Wot);
    hipMemsetAsync(stats, 0, zero_bytes, stream);

    // CSR build + degree sort
    const int nb1 = (N + 1023) / 1024;
    hist_kernel<<<(E + 255) / 256, 256, 0, stream>>>(edst, E, deg);
    scan1_kernel<<<nb1, 256, 0, stream>>>(deg, N, rowptr, partials);
    scan2_kernel<<<1, 64, 0, stream>>>(partials, nb1);
    scan3_hist_kernel<<<SB, 256, 0, stream>>>(rowptr, N, partials, SB, bhist);
    scatter_kernel<<<(E + 255) / 256, 256, 0, stream>>>(esrc, edst, E, rowptr, cursor, csrsrc);
    bin_colscan_kernel<<<1, 256, 0, stream>>>(bhist, SB, binoff);
    bin_order_kernel<<<SB, 256, 0, stream>>>(rowptr, N, SB, bhist, binoff, order);

    const int gemm_rb = (N + 127) / 128;
    const int attn_blocks = (N + 15) / 16;
    const unsigned short* hin = xb;
    for (int l = 0; l < NLAYER; ++l) {
        const float* statsIn = (l == 0) ? (const float*)nullptr
                                        : stats + (size_t)(l - 1) * NREP * 1024;
        const float* gIn = (l == 0) ? (const float*)nullptr : bng + (l - 1) * 128;
        const float* bIn = (l == 0) ? (const float*)nullptr : bnb + (l - 1) * 128;
        gemm_qkvs_kernel<<<dim3(gemm_rb, 2), 256, 0, stream>>>(
            hin, statsIn, gIn, bIn, (l == 0) ? 0 : 1, N,
            Wt + (size_t)l * 4 * 16384,
            bq + l * 128, bk + l * 128, bv + l * 128, bsk + l * 128,
            q, kv, s);
        attn_kernel<<<attn_blocks, 256, 0, stream>>>(q, kv, s, rowptr, csrsrc, order,
                                                     hnext, stats + (size_t)l * NREP * 1024, N);
        hin = hnext;
    }

    float* fstats = stats + (size_t)NLAYER * NREP * 1024;
    gemm_final_kernel<<<gemm_rb, 256, 0, stream>>>(
        hnext, stats + (size_t)2 * NREP * 1024, bng + 2 * 128, bnb + 2 * 128, N,
        Wot, bo, outpre, fstats);
    bn_apply_f32_kernel<<<2048, 256, 0, stream>>>(outpre, (float*)d_out, fstats,
                                                  bnog, bnob, N, 64);
}